// Round 3
// baseline (6948.019 us; speedup 1.0000x reference)
//
#include <hip/hip_runtime.h>
#include <hip/hip_bf16.h>

typedef __hip_bfloat16 bf16;
typedef short v8s __attribute__((ext_vector_type(8)));
typedef float v4f __attribute__((ext_vector_type(4)));

__device__ __forceinline__ float cvt(bf16 v) { return __bfloat162float(v); }

__device__ __forceinline__ float ldg_any(const void* p, size_t i, bool bf) {
    return bf ? cvt(((const bf16*)p)[i]) : ((const float*)p)[i];
}
__device__ __forceinline__ void stg_any(void* p, size_t i, float v, bool bf) {
    if (bf) ((bf16*)p)[i] = __float2bfloat16(v);
    else    ((float*)p)[i] = v;
}
__device__ __forceinline__ bool bfmode(int mode, const int* flags) {
    return mode == 2 ? (flags[0] != 0) : (mode != 0);
}
__device__ __forceinline__ unsigned short f2b(float f) {
    bf16 h = __float2bfloat16(f); return *(unsigned short*)&h;
}
__device__ __forceinline__ void b2f2(unsigned u, float& a, float& b) {
    a = __uint_as_float(u << 16);
    b = __uint_as_float(u & 0xffff0000u);
}

union U16x8 { uint4 u; unsigned short s[8]; };

// ---------------------------------------------------------------------------
// dtype probe on f3 (N(0,1) data): fp32 never has exponent >= 200.
// ---------------------------------------------------------------------------
__global__ void detect_k(const unsigned int* __restrict__ x, int* __restrict__ flags)
{
    unsigned int u = x[threadIdx.x];
    int e = (u >> 23) & 0xFF;
    unsigned long long m = __ballot(e >= 200);
    if (threadIdx.x == 0) flags[0] = (m != 0ULL) ? 1 : 0;
}

// ---------------------------------------------------------------------------
// weight repack: OIHW (+element offset) -> [tap][co(pad)][ci] bf16
// ---------------------------------------------------------------------------
__global__ void repack_off_k(const void* __restrict__ w, size_t w_off,
                             const int* __restrict__ flags, bf16* __restrict__ dst,
                             int Cout, int Cpad, int Cin, int total)
{
    const bool fw = flags[0] != 0;
    int i = blockIdx.x * 256 + threadIdx.x;
    if (i >= total) return;
    int ci = i % Cin; int r = i / Cin; int co = r % Cpad; int tap = r / Cpad;
    float v = 0.f;
    if (co < Cout) v = ldg_any(w, w_off + ((size_t)co * Cin + ci) * 9 + tap, fw);
    dst[i] = __float2bfloat16(v);
}

// ---------------------------------------------------------------------------
// pad + transpose: NCHW (fp32/bf16) -> NHWC padded bf16 [n][Hp][Wq][C].
// Padded (py,px) maps to source (py-1, px-1); everything else zero.
// ---------------------------------------------------------------------------
__global__ void padT_k(const void* __restrict__ src, const int* __restrict__ flags,
                       bf16* __restrict__ dst, int C, int H, int W, int Wq, int Hp,
                       int PIX, long total)
{
    const bool fb = flags[0] != 0;
    long v = (long)blockIdx.x * 256 + threadIdx.x;
    if (v >= total) return;
    const int C8 = C >> 3;
    int oct = (int)(v & (C8 - 1));
    long rest = v >> (C == 256 ? 5 : 4);
    int px = (int)(rest % Wq);
    long r2 = rest / Wq;
    int py = (int)(r2 % Hp);
    int n  = (int)(r2 / Hp);
    U16x8 o;
    if (py == 0 || py > H || px == 0 || px > W) {
        o.u = uint4{0, 0, 0, 0};
    } else {
        const int HW = H * W;
        size_t sb = ((size_t)n * C + oct * 8) * HW + (size_t)(py - 1) * W + (px - 1);
#pragma unroll
        for (int e = 0; e < 8; ++e) o.s[e] = f2b(ldg_any(src, sb + (size_t)e * HW, fb));
    }
    *(uint4*)(dst + v * 8) = o.u;
}

// ---------------------------------------------------------------------------
// MFMA implicit-GEMM 3x3 SAME conv, NHWC padded input.
// Block: 128 co x (4 rows x 32 cols); 4 waves, wave wv owns row wv.
// K loop: Cin chunks of 32; per chunk: ~3.2 aligned uint4 loads/thread ->
// conflict-free swizzled ds_write_b128; taps unrolled with register
// double-buffered weight fragments (batch-8 loads hidden under MFMAs).
// One barrier per chunk (write targets opposite LDS buffer).
// ---------------------------------------------------------------------------
__global__ __launch_bounds__(256, 2) void conv3x3_mfma_k(
    const bf16* __restrict__ in,      // NHWC padded
    const bf16* __restrict__ wrep,    // [tap][co pad][ci]
    const float* __restrict__ gstat, const void* __restrict__ gamma,
    const void* __restrict__ beta, size_t gb_off, int cpg, int Gn, float inv_pg,
    const void* __restrict__ bias, const void* __restrict__ scale, int sidx,
    void* __restrict__ out, int outm, size_t out_off, int out_C,
    const int* __restrict__ flags,
    int Cin, int H, int W, int Wq, int PIX, int Cout, int Cpad, int co_blocks)
{
    const bool fw   = flags[0] != 0;
    const bool fout = bfmode(outm, flags);

    const int t    = threadIdx.x;
    const int lane = t & 63;
    const int wv   = t >> 6;
    const int c    = lane & 15;
    const int quad = lane >> 4;
    const int x0   = blockIdx.x * 32;
    const int y0   = blockIdx.y * 4;
    const int n    = blockIdx.z / co_blocks;
    const int cb   = blockIdx.z % co_blocks;

    __shared__ __align__(16) bf16 s_img[2 * 204 * 32];   // [buf][pos][32ci swizzled]
    __shared__ float s_scale[256], s_shift[256];

    const bool donorm = (gstat != nullptr);

    v4f acc[8][2];
#pragma unroll
    for (int i = 0; i < 8; ++i) {
        acc[i][0] = v4f{0.f, 0.f, 0.f, 0.f};
        acc[i][1] = v4f{0.f, 0.f, 0.f, 0.f};
    }

    const bf16* inb = in + (size_t)n * PIX * Cin;

    // static staging map: flat = t + 256*it over 816 = 204 pos x 4 octets
    int goff[4], loff[4], okm[4], octv[4];
#pragma unroll
    for (int it = 0; it < 4; ++it) {
        int flat = t + 256 * it;
        int pos = flat >> 2, oct = flat & 3;
        int r = (pos * 241) >> 13;          // pos / 34 (exact for pos < 204)
        int cc = pos - r * 34;
        int py = y0 + r, px = x0 + cc;
        bool valid = flat < 816;
        goff[it] = (py * Wq + px) * Cin + oct * 8;
        loff[it] = valid ? (pos * 64 + (((oct + (pos >> 1)) & 3) << 4)) : -1;
        okm[it]  = (py >= 1 && py <= H && px >= 1 && px <= W) ? 1 : 0;
        octv[it] = oct * 8;
    }

    uint4 L[4];

    auto STAGE_LOAD = [&](int ci0_) {
#pragma unroll
        for (int it = 0; it < 4; ++it)
            if (loff[it] >= 0)
                L[it] = *(const uint4*)(inb + goff[it] + ci0_);
    };

    auto STAGE_WRITE = [&](int ci0_, int b_) {
        char* db = (char*)s_img + b_ * 13056;
#pragma unroll
        for (int it = 0; it < 4; ++it) {
            if (loff[it] < 0) continue;
            uint4 q = L[it];
            if (donorm) {
                U16x8 u; u.u = q;
                U16x8 o;
                if (okm[it]) {
                    int cib = ci0_ + octv[it];
#pragma unroll
                    for (int e = 0; e < 8; ++e) {
                        float v = __uint_as_float((unsigned)u.s[e] << 16);
                        v = fmaxf(fmaf(v, s_scale[cib + e], s_shift[cib + e]), 0.f);
                        o.s[e] = f2b(v);
                    }
                } else {
                    o.u = uint4{0, 0, 0, 0};
                }
                q = o.u;
            }
            *(uint4*)(db + loff[it]) = q;
        }
    };

#define LOADAF(dst, tap_) { \
    const bf16* wt_ = wtap + (size_t)(tap_) * tapstride; \
    _Pragma("unroll") for (int mf = 0; mf < 8; ++mf) \
        dst[mf] = *(const v8s*)(wt_ + (size_t)mf * 16 * Cin); }

#define TAPBODY(cur, nxt, tap_, pre_) { \
    const int ky_ = (tap_) / 3, kx_ = (tap_) - 3 * ky_; \
    int pb_ = (wv + ky_) * 34 + kx_ + c; \
    int p1_ = pb_ + 16; \
    v8s b0_ = *(const v8s*)(sb + pb_ * 64 + (((quad + (pb_ >> 1)) & 3) << 4)); \
    v8s b1_ = *(const v8s*)(sb + p1_ * 64 + (((quad + (p1_ >> 1)) & 3) << 4)); \
    if (pre_) { LOADAF(nxt, (tap_) + 1); } \
    _Pragma("unroll") for (int mf = 0; mf < 8; ++mf) { \
        acc[mf][0] = __builtin_amdgcn_mfma_f32_16x16x32_bf16(cur[mf], b0_, acc[mf][0], 0, 0, 0); \
        acc[mf][1] = __builtin_amdgcn_mfma_f32_16x16x32_bf16(cur[mf], b1_, acc[mf][1], 0, 0, 0); } }

    // prologue
    STAGE_LOAD(0);
    if (donorm) {
        for (int ch = t; ch < Cin; ch += 256) {
            int gl = n * Gn + ch / cpg;
            float mu  = gstat[2 * gl] * inv_pg;
            float var = fmaxf(gstat[2 * gl + 1] * inv_pg - mu * mu, 0.f);
            float iv  = rsqrtf(var + 1e-5f);
            float ga  = ldg_any(gamma, gb_off + ch, fw);
            float be  = ldg_any(beta,  gb_off + ch, fw);
            s_scale[ch] = iv * ga;
            s_shift[ch] = be - mu * iv * ga;
        }
    }
    __syncthreads();
    STAGE_WRITE(0, 0);
    __syncthreads();

    const size_t tapstride = (size_t)Cpad * Cin;
    for (int ci0 = 0; ci0 < Cin; ci0 += 32) {
        const int buf = (ci0 >> 5) & 1;
        const bool more = (ci0 + 32 < Cin);
        if (more) STAGE_LOAD(ci0 + 32);
        {
            const char* sb = (const char*)s_img + buf * 13056;
            const bf16* wtap = wrep + (size_t)(cb * 128 + c) * Cin + (size_t)quad * 8 + ci0;
            v8s afA[8], afB[8];
            LOADAF(afA, 0);
            TAPBODY(afA, afB, 0, true);
            TAPBODY(afB, afA, 1, true);
            TAPBODY(afA, afB, 2, true);
            TAPBODY(afB, afA, 3, true);
            TAPBODY(afA, afB, 4, true);
            TAPBODY(afB, afA, 5, true);
            TAPBODY(afA, afB, 6, true);
            TAPBODY(afB, afA, 7, true);
            TAPBODY(afA, afB, 8, false);
        }
        if (more) STAGE_WRITE(ci0 + 32, buf ^ 1);
        __syncthreads();
    }
#undef TAPBODY
#undef LOADAF

    // epilogue: C/D layout col(lane&15)=pixel x, row(quad*4+reg)=co
    const int y = y0 + wv;
    if (outm == 0) {
        if (y < H) {
            bf16* ob = (bf16*)out + ((size_t)n * PIX + (size_t)(y + 1) * Wq + 1) * out_C;
#pragma unroll
            for (int mf = 0; mf < 8; ++mf) {
                int co = cb * 128 + mf * 16 + quad * 4;
#pragma unroll
                for (int nf = 0; nf < 2; ++nf) {
                    int x = x0 + nf * 16 + c;
                    if (x < W) {
                        uint2 o;
                        o.x = f2b(acc[mf][nf][0]) | ((unsigned)f2b(acc[mf][nf][1]) << 16);
                        o.y = f2b(acc[mf][nf][2]) | ((unsigned)f2b(acc[mf][nf][3]) << 16);
                        *(uint2*)(ob + (size_t)x * out_C + co) = o;
                    }
                }
            }
        }
    } else {
        const float al = scale ? ldg_any(scale, sidx, fw) : 1.f;
        const int HW = H * W;
        if (y < H) {
#pragma unroll
            for (int mf = 0; mf < 8; ++mf) {
                int cobase = cb * 128 + mf * 16 + quad * 4;
#pragma unroll
                for (int reg = 0; reg < 4; ++reg) {
                    int co = cobase + reg;
                    if (co >= Cout) continue;
                    float bv = bias ? ldg_any(bias, co, fw) : 0.f;
                    size_t obase = out_off + ((size_t)n * Cout + co) * HW + (size_t)y * W;
#pragma unroll
                    for (int nf = 0; nf < 2; ++nf) {
                        int x = x0 + nf * 16 + c;
                        if (x < W)
                            stg_any(out, obase + x, fmaf(al, acc[mf][nf][reg], bv), fout);
                    }
                }
            }
        }
    }
}

// ---------------------------------------------------------------------------
// GroupNorm stats over NHWC padded buffer (borders are zero -> harmless).
// Each lane owns a fixed channel-octet; xor-shuffle reduce; atomics per group.
// ---------------------------------------------------------------------------
__global__ __launch_bounds__(256) void gn_stats_nhwc(const bf16* __restrict__ x,
                                                     float* __restrict__ stats,
                                                     int C8, int cpg8, int Gn,
                                                     long nvec, int planeC)
{
    const int n = blockIdx.z;
    const bf16* xp = x + (size_t)n * planeC;
    const int t = threadIdx.x;
    const int oct = t & (C8 - 1);
    float s = 0.f, ss = 0.f;
    const long stride = 256L * gridDim.x;
    for (long v = (long)blockIdx.x * 256 + t; v < nvec; v += stride) {
        uint4 u = *(const uint4*)(xp + v * 8);
        float f0,f1,f2,f3,f4,f5,f6,f7;
        b2f2(u.x, f0, f1); b2f2(u.y, f2, f3); b2f2(u.z, f4, f5); b2f2(u.w, f6, f7);
        s += ((f0+f1)+(f2+f3)) + ((f4+f5)+(f6+f7));
        ss = fmaf(f0,f0,ss); ss = fmaf(f1,f1,ss); ss = fmaf(f2,f2,ss); ss = fmaf(f3,f3,ss);
        ss = fmaf(f4,f4,ss); ss = fmaf(f5,f5,ss); ss = fmaf(f6,f6,ss); ss = fmaf(f7,f7,ss);
    }
    for (int off = C8; off < 64; off <<= 1) {
        s  += __shfl_xor(s,  off, 64);
        ss += __shfl_xor(ss, off, 64);
    }
    if ((t & 63) < C8) {
        int gl = n * Gn + oct / cpg8;
        atomicAdd(&stats[2 * gl],     s);
        atomicAdd(&stats[2 * gl + 1], ss);
    }
}

// GroupNorm apply + relu on NHWC padded interior (borders stay zero).
__global__ void gn_apply_nhwc(bf16* __restrict__ x, const float* __restrict__ stats,
                              const void* __restrict__ gamma, const void* __restrict__ beta,
                              size_t gb_off, const int* __restrict__ flags,
                              int C, int cpg, int Gn, int H, int W, int Wq, int PIX,
                              float inv_len, long total)
{
    const bool fw = flags[0] != 0;
    long v = (long)blockIdx.x * 256 + threadIdx.x;
    if (v >= total) return;
    const int C8 = C >> 3;
    int oct = (int)(v & (C8 - 1));
    long rest = v / C8;
    int x2 = (int)(rest % W);
    long r2 = rest / W;
    int y = (int)(r2 % H);
    int n = (int)(r2 / H);
    int ch0 = oct * 8;
    int gl = n * Gn + ch0 / cpg;
    float mu  = stats[2 * gl] * inv_len;
    float var = fmaxf(stats[2 * gl + 1] * inv_len - mu * mu, 0.f);
    float iv  = rsqrtf(var + 1e-5f);
    size_t base = ((size_t)n * PIX + (size_t)(y + 1) * Wq + (x2 + 1)) * C + ch0;
    U16x8 u; u.u = *(const uint4*)(x + base);
    U16x8 o;
#pragma unroll
    for (int e = 0; e < 8; ++e) {
        float ga = ldg_any(gamma, gb_off + ch0 + e, fw);
        float be = ldg_any(beta,  gb_off + ch0 + e, fw);
        float f = __uint_as_float((unsigned)u.s[e] << 16);
        f = fmaxf(fmaf(f, iv * ga, be - mu * iv * ga), 0.f);
        o.s[e] = f2b(f);
    }
    *(uint4*)(x + base) = o.u;
}

// ---------------------------------------------------------------------------
__global__ void extract_params_k(const void* __restrict__ pred3, const int* __restrict__ flags,
                                 float* __restrict__ prm, int HW)
{
    const bool bf = flags[0] != 0;
    int tid = blockIdx.x * blockDim.x + threadIdx.x;
    if (tid >= 200 * 169) return;
    int p = tid / 169, c = tid - p * 169;
    int b = p / 100, i = p - b * 100;
    prm[tid] = ldg_any(pred3, ((size_t)b * 254 + 85 + c) * HW + i, bf);
}

// bilinear upsample (align corners), NHWC padded src -> add into NHWC padded dst
__global__ void upsample_add_nhwc(const bf16* __restrict__ src, bf16* __restrict__ dst,
                                  int h, int w, int sWq, int sPIX,
                                  int OH, int OW, int dWq, int dPIX, long total)
{
    long i = (long)blockIdx.x * 256 + threadIdx.x;
    if (i >= total) return;
    const int C = 128, C8 = 16;
    int oct = (int)(i & (C8 - 1));
    long rest = i >> 4;
    int ox = (int)(rest % OW);
    long r = rest / OW;
    int oy = (int)(r % OH);
    int n  = (int)(r / OH);
    float sy = oy * ((h - 1.f) / (OH - 1.f));
    float sx = ox * ((w - 1.f) / (OW - 1.f));
    int y0 = (int)sy; int y1 = min(y0 + 1, h - 1); float wy = sy - y0;
    int x0 = (int)sx; int x1 = min(x0 + 1, w - 1); float wx = sx - x0;
    const bf16* sp = src + (size_t)n * sPIX * C + oct * 8;
    U16x8 q00, q01, q10, q11;
    q00.u = *(const uint4*)(sp + ((size_t)(y0 + 1) * sWq + (x0 + 1)) * C);
    q01.u = *(const uint4*)(sp + ((size_t)(y0 + 1) * sWq + (x1 + 1)) * C);
    q10.u = *(const uint4*)(sp + ((size_t)(y1 + 1) * sWq + (x0 + 1)) * C);
    q11.u = *(const uint4*)(sp + ((size_t)(y1 + 1) * sWq + (x1 + 1)) * C);
    bf16* dp = dst + ((size_t)n * dPIX + (size_t)(oy + 1) * dWq + (ox + 1)) * C + oct * 8;
    U16x8 d; d.u = *(const uint4*)dp;
    U16x8 o;
#pragma unroll
    for (int e = 0; e < 8; ++e) {
        float a00 = __uint_as_float((unsigned)q00.s[e] << 16);
        float a01 = __uint_as_float((unsigned)q01.s[e] << 16);
        float a10 = __uint_as_float((unsigned)q10.s[e] << 16);
        float a11 = __uint_as_float((unsigned)q11.s[e] << 16);
        float t0 = a00 * (1.f - wy) + a10 * wy;
        float t1 = a01 * (1.f - wy) + a11 * wy;
        float dv = __uint_as_float((unsigned)d.s[e] << 16);
        o.s[e] = f2b(dv + t0 * (1.f - wx) + t1 * wx);
    }
    *(uint4*)dp = o.u;
}

__global__ void resize_out_k(const float* __restrict__ src, void* __restrict__ dst,
                             size_t dst_off, const int* __restrict__ flags,
                             int h, int w, int OH, int OW, long total)
{
    const bool bf = flags[0] != 0;
    long i = (long)blockIdx.x * blockDim.x + threadIdx.x;
    if (i >= total) return;
    int ox = (int)(i % OW);
    long r = i / OW;
    int oy = (int)(r % OH);
    int nc = (int)(r / OH);
    float sy = oy * ((h - 1.f) / (OH - 1.f));
    float sx = ox * ((w - 1.f) / (OW - 1.f));
    int y0 = (int)sy; int y1 = min(y0 + 1, h - 1); float wy = sy - y0;
    int x0 = (int)sx; int x1 = min(x0 + 1, w - 1); float wx = sx - x0;
    const float* sp = src + (size_t)nc * h * w;
    float t0 = sp[y0 * w + x0] * (1.f - wy) + sp[y1 * w + x0] * wy;
    float t1 = sp[y0 * w + x1] * (1.f - wy) + sp[y1 * w + x1] * wy;
    stg_any(dst, dst_off + (size_t)i, t0 * (1.f - wx) + t1 * wx, bf);
}

__global__ void cast_out_k(const bf16* __restrict__ src, void* __restrict__ dst,
                           size_t dst_off, const int* __restrict__ flags, long n)
{
    const bool bf = flags[0] != 0;
    long i = (long)blockIdx.x * blockDim.x + threadIdx.x;
    if (i < n) stg_any(dst, dst_off + (size_t)i, cvt(src[i]), bf);
}

// 1x1 conv: NHWC padded (C=128) -> flat NCHW bf16 (8 ch)
__global__ __launch_bounds__(256) void conv1x1_nhwc(const bf16* __restrict__ in,
                                                    const void* __restrict__ w,
                                                    const int* __restrict__ flags,
                                                    bf16* __restrict__ out,
                                                    int H, int W, int Wq, int PIX)
{
    const bool fw = flags[0] != 0;
    __shared__ float sw[8 * 128];
    for (int i = threadIdx.x; i < 1024; i += 256) sw[i] = ldg_any(w, i, fw);
    __syncthreads();
    const int HW = H * W;
    int idx = blockIdx.x * 256 + threadIdx.x;
    if (idx >= 2 * HW) return;
    int pix = idx % HW, n = idx / HW;
    int y = pix / W, x = pix - y * W;
    const bf16* ip = in + ((size_t)n * PIX + (size_t)(y + 1) * Wq + (x + 1)) * 128;
    float a[8];
#pragma unroll
    for (int o = 0; o < 8; ++o) a[o] = 0.f;
    for (int oc = 0; oc < 16; ++oc) {
        U16x8 q; q.u = *(const uint4*)(ip + oc * 8);
#pragma unroll
        for (int e = 0; e < 8; ++e) {
            float f = __uint_as_float((unsigned)q.s[e] << 16);
#pragma unroll
            for (int o = 0; o < 8; ++o) a[o] = fmaf(sw[o * 128 + oc * 8 + e], f, a[o]);
        }
    }
#pragma unroll
    for (int o = 0; o < 8; ++o)
        out[((size_t)n * 8 + o) * HW + pix] = __float2bfloat16(a[o]);
}

// GroupNorm stats/apply on FLAT planar bf16 (mfeat)
__global__ __launch_bounds__(256) void gn_stats_v(const bf16* __restrict__ x,
                                                  float* __restrict__ stats, int per_group)
{
    const int g = blockIdx.x;
    const uint4* xp = (const uint4*)(x + (size_t)g * per_group);
    const int nvec = per_group >> 3;
    float s = 0.f, ss = 0.f;
    const int stride = 256 * gridDim.y;
    for (int i = blockIdx.y * 256 + threadIdx.x; i < nvec; i += stride) {
        uint4 u = xp[i];
        float f0,f1,f2,f3,f4,f5,f6,f7;
        b2f2(u.x, f0, f1); b2f2(u.y, f2, f3); b2f2(u.z, f4, f5); b2f2(u.w, f6, f7);
        s += ((f0+f1)+(f2+f3)) + ((f4+f5)+(f6+f7));
        ss = fmaf(f0,f0,ss); ss = fmaf(f1,f1,ss); ss = fmaf(f2,f2,ss); ss = fmaf(f3,f3,ss);
        ss = fmaf(f4,f4,ss); ss = fmaf(f5,f5,ss); ss = fmaf(f6,f6,ss); ss = fmaf(f7,f7,ss);
    }
#pragma unroll
    for (int off = 32; off > 0; off >>= 1) {
        s  += __shfl_down(s,  off, 64);
        ss += __shfl_down(ss, off, 64);
    }
    __shared__ float sh[8];
    const int wv = threadIdx.x >> 6;
    if ((threadIdx.x & 63) == 0) { sh[wv * 2] = s; sh[wv * 2 + 1] = ss; }
    __syncthreads();
    if (threadIdx.x == 0) {
        s  = sh[0] + sh[2] + sh[4] + sh[6];
        ss = sh[1] + sh[3] + sh[5] + sh[7];
        atomicAdd(&stats[2 * g],     s);
        atomicAdd(&stats[2 * g + 1], ss);
    }
}

__global__ void gn_apply_v(bf16* __restrict__ x, const float* __restrict__ stats,
                           const void* __restrict__ gamma, const void* __restrict__ beta,
                           size_t gb_off, const int* __restrict__ flags,
                           int HW, int C, int per_group, float inv_len, long nvec)
{
    const bool fw = flags[0] != 0;
    long v = (long)blockIdx.x * blockDim.x + threadIdx.x;
    if (v >= nvec) return;
    long i0 = v * 8;
    int gl = (int)(i0 / per_group);
    float mu  = stats[2 * gl] * inv_len;
    float var = fmaxf(stats[2 * gl + 1] * inv_len - mu * mu, 0.f);
    float iv  = rsqrtf(var + 1e-5f);
    int cc = (int)((i0 / HW) % C);
    float ga = ldg_any(gamma, gb_off + cc, fw);
    float be = ldg_any(beta,  gb_off + cc, fw);
    float sc = iv * ga, sf = be - mu * iv * ga;
    uint4 u = *(const uint4*)(x + i0);
    float f[8];
    b2f2(u.x, f[0], f[1]); b2f2(u.y, f[2], f[3]);
    b2f2(u.z, f[4], f[5]); b2f2(u.w, f[6], f[7]);
#pragma unroll
    for (int j = 0; j < 8; ++j) f[j] = fmaxf(fmaf(f[j], sc, sf), 0.f);
    uint4 o;
    o.x = f2b(f[0]) | ((unsigned)f2b(f[1]) << 16);
    o.y = f2b(f[2]) | ((unsigned)f2b(f[3]) << 16);
    o.z = f2b(f[4]) | ((unsigned)f2b(f[5]) << 16);
    o.w = f2b(f[6]) | ((unsigned)f2b(f[7]) << 16);
    *(uint4*)(x + i0) = o;
}

__global__ __launch_bounds__(256) void dyn_conv_k(const bf16* __restrict__ mf,
                                                  const float* __restrict__ prm,
                                                  float* __restrict__ out, int H, int W)
{
    const int inst = blockIdx.y;
    __shared__ float p[169];
    if (threadIdx.x < 169) p[threadIdx.x] = prm[inst * 169 + threadIdx.x];
    __syncthreads();
    const int HW = H * W;
    const int pix = blockIdx.x * 256 + threadIdx.x;
    if (pix >= HW) return;
    const int b = inst / 100;
    float xin[10];
#pragma unroll
    for (int c = 0; c < 8; ++c) xin[c] = cvt(mf[((size_t)(b * 8 + c)) * HW + pix]);
    int yy = pix / W, xx = pix - yy * W;
    xin[8] = -1.f + 2.f * xx / (W - 1);
    xin[9] = -1.f + 2.f * yy / (H - 1);
    float h1[8];
#pragma unroll
    for (int o = 0; o < 8; ++o) {
        float s = p[152 + o];
#pragma unroll
        for (int c = 0; c < 10; ++c) s = fmaf(p[o * 10 + c], xin[c], s);
        h1[o] = fmaxf(s, 0.f);
    }
    float h2[8];
#pragma unroll
    for (int o = 0; o < 8; ++o) {
        float s = p[160 + o];
#pragma unroll
        for (int c = 0; c < 8; ++c) s = fmaf(p[80 + o * 8 + c], h1[c], s);
        h2[o] = fmaxf(s, 0.f);
    }
    float s = p[168];
#pragma unroll
    for (int c = 0; c < 8; ++c) s = fmaf(p[144 + c], h2[c], s);
    out[(size_t)inst * HW + pix] = s;
}

// ---------------------------------------------------------------------------
// host helpers
// ---------------------------------------------------------------------------
struct Norm { const float* st; const void* g; const void* b; size_t off; int cpg; int Gn; float inv; };
struct Geo  { int H, W, Wq, Hp, PIX; };

static inline Geo mkgeo(int H, int W) {
    int xb = (W + 31) / 32, yb = (H + 3) / 4;
    Geo g; g.H = H; g.W = W; g.Wq = (xb - 1) * 32 + 34; g.Hp = (yb - 1) * 4 + 6;
    g.PIX = g.Hp * g.Wq;
    return g;
}

static inline void mconv(const bf16* in, const bf16* wrep, const Norm* nm,
                         const void* bias, const void* scale, int sidx,
                         void* out, int outm, size_t out_off, int out_C,
                         const int* flags, int N, int Cin, Geo g, int Cout, hipStream_t s)
{
    int cob = (Cout + 127) / 128, Cpad = cob * 128;
    dim3 gr((g.W + 31) / 32, (g.H + 3) / 4, N * cob);
    conv3x3_mfma_k<<<gr, 256, 0, s>>>(
        in, wrep,
        nm ? nm->st : nullptr, nm ? nm->g : nullptr, nm ? nm->b : nullptr,
        nm ? nm->off : 0, nm ? nm->cpg : 1, nm ? nm->Gn : 1, nm ? nm->inv : 1.f,
        bias, scale, sidx, out, outm, out_off, out_C,
        flags, Cin, g.H, g.W, g.Wq, g.PIX, Cout, Cpad, cob);
}

static inline void run_padT(const void* src, const int* flags, bf16* dst,
                            int N, int C, Geo g, hipStream_t s)
{
    long total = (long)N * g.PIX * (C >> 3);
    padT_k<<<(int)((total + 255) / 256), 256, 0, s>>>(src, flags, dst, C, g.H, g.W,
                                                      g.Wq, g.Hp, g.PIX, total);
}

static inline void run_stats_nhwc(const bf16* x, float* st, int N, int C, int cpg, int Gn,
                                  Geo g, hipStream_t s)
{
    int C8 = C >> 3;
    long nvec = (long)g.PIX * C8;
    int chunks = (int)((nvec + 2047) / 2048);
    if (chunks > 256) chunks = 256; if (chunks < 1) chunks = 1;
    gn_stats_nhwc<<<dim3(chunks, 1, N), 256, 0, s>>>(x, st, C8, cpg >> 3, Gn,
                                                     nvec, g.PIX * C);
}

static inline void run_apply_nhwc(bf16* x, const float* st, const void* gm, const void* bt,
                                  size_t off, const int* flags, int N, int C, int cpg, int Gn,
                                  Geo g, hipStream_t s)
{
    long total = (long)N * g.H * g.W * (C >> 3);
    gn_apply_nhwc<<<(int)((total + 255) / 256), 256, 0, s>>>(
        x, st, gm, bt, off, flags, C, cpg, Gn, g.H, g.W, g.Wq, g.PIX,
        1.f / ((float)cpg * g.H * g.W), total);
}

extern "C" void kernel_launch(void* const* d_in, const int* in_sizes, int n_in,
                              void* d_out, int out_size, void* d_ws, size_t ws_size,
                              hipStream_t stream)
{
    const void* f[5] = {d_in[0], d_in[1], d_in[2], d_in[3], d_in[4]};
    static const int Hs[5] = {96, 48, 24, 12, 6};
    static const int Wd[5] = {160, 80, 40, 20, 10};
    const void* head_w     = d_in[5];
    const void* head_gn_g  = d_in[6];
    const void* head_gn_b  = d_in[7];
    const void* head_out_w = d_in[8];
    const void* head_out_b = d_in[9];
    const void* scales     = d_in[10];
    const void* ref_w      = d_in[11];
    const void* ref_gn_g   = d_in[12];
    const void* ref_gn_b   = d_in[13];
    const void* tow_w      = d_in[14];
    const void* tow_gn_g   = d_in[15];
    const void* tow_gn_b   = d_in[16];
    const void* out_w      = d_in[17];
    const void* out_gn_g   = d_in[18];
    const void* out_gn_b   = d_in[19];

    Geo G[5];
    for (int l = 0; l < 5; ++l) G[l] = mkgeo(Hs[l], Wd[l]);
    // PIX: 15876, 4900, 1716, 476, 340

    size_t po[5]; size_t off = 0;
    for (int l = 0; l < 5; ++l) { po[l] = off; off += (size_t)2 * 254 * Hs[l] * Wd[l]; }
    size_t mf_off = off; off += 245760;
    size_t ml_off = off;

    // ---- workspace (~42 MB) ----
    const size_t ACAP = (size_t)2 * 256 * G[0].PIX;       // 8,128,512 elems
    bf16*  A     = (bf16*)d_ws;
    bf16*  B     = A + ACAP;
    bf16*  B2    = B + ACAP;                              // 2*128*4900 = 1,254,400
    bf16*  mfeat = B2 + 1254400;
    float* prm   = (float*)(mfeat + 245760);              // 33,800 f32
    float* stats = prm + 33800;                           // 4,096 f32
    int*   flags = (int*)(stats + 4096);                  // 16 int
    bf16*  wrep  = (bf16*)(flags + 16);                   // 2,949,120 bf16
    float* dyn   = (float*)A;                             // aliases A after last read

    bf16* wrepH  = wrep;                        // 4 x 589824 (head layers)
    bf16* wrepHO = wrep + 4 * 589824;           // 589824 (head_out, Cpad 256)
    bf16* wrepR  = wrep;                        // mask phase reuses region
    bf16* wrepT  = wrep + 3 * 294912;

    hipMemsetAsync(stats, 0, 4096 * sizeof(float), stream);
    detect_k<<<1, 64, 0, stream>>>((const unsigned int*)d_in[0], flags);

    float* sp = stats;

    // repack head weights
    for (int l = 0; l < 4; ++l) {
        int total = 9 * 256 * 256;
        repack_off_k<<<(total + 255) / 256, 256, 0, stream>>>(
            head_w, (size_t)l * 589824, flags, wrepH + (size_t)l * 589824, 256, 256, 256, total);
    }
    {
        int total = 9 * 256 * 256;
        repack_off_k<<<(total + 255) / 256, 256, 0, stream>>>(
            head_out_w, 0, flags, wrepHO, 254, 256, 256, total);
    }

    // ---------------- head branches ----------------
    for (int lvl = 0; lvl < 5; ++lvl) {
        Geo g = G[lvl];
        int HW = g.H * g.W;
        float inv_pg = 1.f / (8 * HW);
        run_padT(f[lvl], flags, B, 2, 256, g, stream);
        hipMemsetAsync(A, 0, (size_t)2 * 256 * g.PIX * sizeof(bf16), stream);
        mconv(B, wrepH, nullptr, nullptr, nullptr, 0, A, 0, 0, 256,
              flags, 2, 256, g, 256, stream);
        float* s_prev = sp; sp += 128;
        run_stats_nhwc(A, s_prev, 2, 256, 8, 32, g, stream);
        bf16* a = A; bf16* bb = B;
        for (int l = 1; l < 4; ++l) {
            Norm nm{s_prev, head_gn_g, head_gn_b, (size_t)(l - 1) * 256, 8, 32, inv_pg};
            mconv(a, wrepH + (size_t)l * 589824, &nm, nullptr, nullptr, 0,
                  bb, 0, 0, 256, flags, 2, 256, g, 256, stream);
            s_prev = sp; sp += 128;
            run_stats_nhwc(bb, s_prev, 2, 256, 8, 32, g, stream);
            bf16* tmp = a; a = bb; bb = tmp;
        }
        Norm nm{s_prev, head_gn_g, head_gn_b, (size_t)3 * 256, 8, 32, inv_pg};
        mconv(a, wrepHO, &nm, head_out_b, scales, lvl, d_out, 2, po[lvl], 0,
              flags, 2, 256, g, 254, stream);
        if (lvl == 0)
            extract_params_k<<<(200 * 169 + 255) / 256, 256, 0, stream>>>(d_out, flags, prm, HW);
    }

    // repack mask weights (enqueued after all head convs; stream order protects)
    for (int i = 0; i < 3; ++i) {
        int total = 9 * 128 * 256;
        repack_off_k<<<(total + 255) / 256, 256, 0, stream>>>(
            ref_w, (size_t)i * 294912, flags, wrepR + (size_t)i * 294912, 128, 128, 256, total);
    }
    for (int l = 0; l < 4; ++l) {
        int total = 9 * 128 * 128;
        repack_off_k<<<(total + 255) / 256, 256, 0, stream>>>(
            tow_w, (size_t)l * 147456, flags, wrepT + (size_t)l * 147456, 128, 128, 128, total);
    }

    // ---------------- mask branch ----------------
    {
        Geo g0 = G[0];
        const int HW = 96 * 160;

        // refine 0
        run_padT(f[0], flags, B, 2, 256, g0, stream);
        hipMemsetAsync(A, 0, (size_t)2 * 128 * g0.PIX * sizeof(bf16), stream);
        mconv(B, wrepR, nullptr, nullptr, nullptr, 0, A, 0, 0, 128,
              flags, 2, 256, g0, 128, stream);
        float* s0 = sp; sp += 4;
        run_stats_nhwc(A, s0, 2, 128, 128, 1, g0, stream);
        run_apply_nhwc(A, s0, ref_gn_g, ref_gn_b, 0, flags, 2, 128, 128, 1, g0, stream);

        // refines 1,2 + upsample-add into A
        for (int i = 1; i < 3; ++i) {
            Geo gi = G[i];
            run_padT(f[i], flags, B, 2, 256, gi, stream);
            hipMemsetAsync(B2, 0, (size_t)2 * 128 * gi.PIX * sizeof(bf16), stream);
            mconv(B, wrepR + (size_t)i * 294912, nullptr, nullptr, nullptr, 0,
                  B2, 0, 0, 128, flags, 2, 256, gi, 128, stream);
            float* si = sp; sp += 4;
            run_stats_nhwc(B2, si, 2, 128, 128, 1, gi, stream);
            run_apply_nhwc(B2, si, ref_gn_g, ref_gn_b, (size_t)i * 128, flags,
                           2, 128, 128, 1, gi, stream);
            long tot = (long)2 * 96 * 160 * 16;
            upsample_add_nhwc<<<(int)((tot + 255) / 256), 256, 0, stream>>>(
                B2, A, gi.H, gi.W, gi.Wq, gi.PIX, 96, 160, g0.Wq, g0.PIX, tot);
        }

        // tower
        float inv_pg = 1.f / (128 * HW);
        hipMemsetAsync(B, 0, (size_t)2 * 128 * g0.PIX * sizeof(bf16), stream);
        mconv(A, wrepT, nullptr, nullptr, nullptr, 0, B, 0, 0, 128,
              flags, 2, 128, g0, 128, stream);
        float* sT = sp; sp += 4;
        run_stats_nhwc(B, sT, 2, 128, 128, 1, g0, stream);
        bf16* a = B; bf16* bb = A;
        for (int l = 1; l < 4; ++l) {
            Norm nm{sT, tow_gn_g, tow_gn_b, (size_t)(l - 1) * 128, 128, 1, inv_pg};
            mconv(a, wrepT + (size_t)l * 147456, &nm, nullptr, nullptr, 0,
                  bb, 0, 0, 128, flags, 2, 128, g0, 128, stream);
            sT = sp; sp += 4;
            run_stats_nhwc(bb, sT, 2, 128, 128, 1, g0, stream);
            bf16* tmp = a; a = bb; bb = tmp;
        }
        // final tower raw in a (= A), stats sT
        run_apply_nhwc(a, sT, tow_gn_g, tow_gn_b, (size_t)3 * 128, flags, 2, 128, 128, 1, g0, stream);
        conv1x1_nhwc<<<(2 * HW + 255) / 256, 256, 0, stream>>>(
            a, out_w, flags, mfeat, 96, 160, g0.Wq, g0.PIX);
        float* sM = sp; sp += 4;
        {
            int chunks = (8 * HW) / 8192; if (chunks < 1) chunks = 1;
            gn_stats_v<<<dim3(2, chunks), 256, 0, stream>>>(mfeat, sM, 8 * HW);
            long nvec = ((long)2 * 8 * HW) >> 3;
            gn_apply_v<<<(int)((nvec + 255) / 256), 256, 0, stream>>>(
                mfeat, sM, out_gn_g, out_gn_b, 0, flags, HW, 8, 8 * HW, 1.f / (8 * HW), nvec);
        }
        cast_out_k<<<(2 * 8 * HW + 255) / 256, 256, 0, stream>>>(
            mfeat, d_out, mf_off, flags, (long)2 * 8 * HW);
        dyn_conv_k<<<dim3((HW + 255) / 256, 200), 256, 0, stream>>>(mfeat, prm, dyn, 96, 160);
        long nt = (long)200 * 192 * 320;
        resize_out_k<<<(int)((nt + 255) / 256), 256, 0, stream>>>(
            dyn, d_out, ml_off, flags, 96, 160, 192, 320, nt);
    }
}

// Round 4
// 4804.950 us; speedup vs baseline: 1.4460x; 1.4460x over previous
//
#include <hip/hip_runtime.h>
#include <hip/hip_bf16.h>

typedef __hip_bfloat16 bf16;
typedef short v8s __attribute__((ext_vector_type(8)));
typedef float v4f __attribute__((ext_vector_type(4)));

__device__ __forceinline__ float cvt(bf16 v) { return __bfloat162float(v); }

__device__ __forceinline__ float ldg_any(const void* p, size_t i, bool bf) {
    return bf ? cvt(((const bf16*)p)[i]) : ((const float*)p)[i];
}
__device__ __forceinline__ void stg_any(void* p, size_t i, float v, bool bf) {
    if (bf) ((bf16*)p)[i] = __float2bfloat16(v);
    else    ((float*)p)[i] = v;
}
__device__ __forceinline__ bool bfmode(int mode, const int* flags) {
    return mode == 2 ? (flags[0] != 0) : (mode != 0);
}
__device__ __forceinline__ unsigned short f2b(float f) {
    bf16 h = __float2bfloat16(f); return *(unsigned short*)&h;
}
__device__ __forceinline__ void b2f2(unsigned u, float& a, float& b) {
    a = __uint_as_float(u << 16);
    b = __uint_as_float(u & 0xffff0000u);
}

union U16x8 { uint4 u; unsigned short s[8]; };

// ---------------------------------------------------------------------------
// dtype probe on f3 (N(0,1) data): fp32 never has exponent >= 200.
// ---------------------------------------------------------------------------
__global__ void detect_k(const unsigned int* __restrict__ x, int* __restrict__ flags)
{
    unsigned int u = x[threadIdx.x];
    int e = (u >> 23) & 0xFF;
    unsigned long long m = __ballot(e >= 200);
    if (threadIdx.x == 0) flags[0] = (m != 0ULL) ? 1 : 0;
}

// ---------------------------------------------------------------------------
// weight repack: OIHW (+element offset) -> [tap][co(pad)][ci] bf16
// ---------------------------------------------------------------------------
__global__ void repack_off_k(const void* __restrict__ w, size_t w_off,
                             const int* __restrict__ flags, bf16* __restrict__ dst,
                             int Cout, int Cpad, int Cin, int total)
{
    const bool fw = flags[0] != 0;
    int i = blockIdx.x * 256 + threadIdx.x;
    if (i >= total) return;
    int ci = i % Cin; int r = i / Cin; int co = r % Cpad; int tap = r / Cpad;
    float v = 0.f;
    if (co < Cout) v = ldg_any(w, w_off + ((size_t)co * Cin + ci) * 9 + tap, fw);
    dst[i] = __float2bfloat16(v);
}

// ---------------------------------------------------------------------------
// pad + transpose: NCHW (fp32/bf16) -> NHWC padded bf16 [n][Hp][Wq][C].
// Padded (py,px) maps to source (py-1, px-1); everything else zero.
// ---------------------------------------------------------------------------
__global__ void padT_k(const void* __restrict__ src, const int* __restrict__ flags,
                       bf16* __restrict__ dst, int C, int H, int W, int Wq, int Hp,
                       int PIX, long total)
{
    const bool fb = flags[0] != 0;
    long v = (long)blockIdx.x * 256 + threadIdx.x;
    if (v >= total) return;
    const int C8 = C >> 3;
    int oct = (int)(v & (C8 - 1));
    long rest = v >> (C == 256 ? 5 : 4);
    int px = (int)(rest % Wq);
    long r2 = rest / Wq;
    int py = (int)(r2 % Hp);
    int n  = (int)(r2 / Hp);
    U16x8 o;
    if (py == 0 || py > H || px == 0 || px > W) {
        o.u = uint4{0, 0, 0, 0};
    } else {
        const int HW = H * W;
        size_t sb = ((size_t)n * C + oct * 8) * HW + (size_t)(py - 1) * W + (px - 1);
#pragma unroll
        for (int e = 0; e < 8; ++e) o.s[e] = f2b(ldg_any(src, sb + (size_t)e * HW, fb));
    }
    *(uint4*)(dst + v * 8) = o.u;
}

// ---------------------------------------------------------------------------
// MFMA implicit-GEMM 3x3 SAME conv, NHWC padded input.
// Block: 128 co x (4 rows x 32 cols); 4 waves, wave wv owns row wv.
// K loop: Cin chunks of 32; per chunk: ~3.2 aligned uint4 loads/thread ->
// conflict-free swizzled ds_write_b128; taps unrolled with register
// double-buffered weight fragments (batch-8 loads hidden under MFMAs).
// One barrier per chunk (write targets opposite LDS buffer).
// ---------------------------------------------------------------------------
__global__ __launch_bounds__(256, 2) void conv3x3_mfma_k(
    const bf16* __restrict__ in,      // NHWC padded
    const bf16* __restrict__ wrep,    // [tap][co pad][ci]
    const float* __restrict__ gstat, const void* __restrict__ gamma,
    const void* __restrict__ beta, size_t gb_off, int cpg, int Gn, float inv_pg,
    const void* __restrict__ bias, const void* __restrict__ scale, int sidx,
    void* __restrict__ out, int outm, size_t out_off, int out_C,
    const int* __restrict__ flags,
    int Cin, int H, int W, int Wq, int PIX, int Cout, int Cpad, int co_blocks)
{
    const bool fw   = flags[0] != 0;
    const bool fout = bfmode(outm, flags);

    const int t    = threadIdx.x;
    const int lane = t & 63;
    const int wv   = t >> 6;
    const int c    = lane & 15;
    const int quad = lane >> 4;
    const int x0   = blockIdx.x * 32;
    const int y0   = blockIdx.y * 4;
    const int n    = blockIdx.z / co_blocks;
    const int cb   = blockIdx.z % co_blocks;

    __shared__ __align__(16) bf16 s_img[2 * 204 * 32];   // [buf][pos][32ci swizzled]
    __shared__ float s_scale[256], s_shift[256];

    const bool donorm = (gstat != nullptr);

    v4f acc[8][2];
#pragma unroll
    for (int i = 0; i < 8; ++i) {
        acc[i][0] = v4f{0.f, 0.f, 0.f, 0.f};
        acc[i][1] = v4f{0.f, 0.f, 0.f, 0.f};
    }

    const bf16* inb = in + (size_t)n * PIX * Cin;

    // static staging map: flat = t + 256*it over 816 = 204 pos x 4 octets
    int goff[4], loff[4], okm[4], octv[4];
#pragma unroll
    for (int it = 0; it < 4; ++it) {
        int flat = t + 256 * it;
        int pos = flat >> 2, oct = flat & 3;
        int r = (pos * 241) >> 13;          // pos / 34 (exact for pos < 204)
        int cc = pos - r * 34;
        int py = y0 + r, px = x0 + cc;
        bool valid = flat < 816;
        goff[it] = (py * Wq + px) * Cin + oct * 8;
        loff[it] = valid ? (pos * 64 + (((oct + (pos >> 1)) & 3) << 4)) : -1;
        okm[it]  = (py >= 1 && py <= H && px >= 1 && px <= W) ? 1 : 0;
        octv[it] = oct * 8;
    }

    uint4 L[4];

    auto STAGE_LOAD = [&](int ci0_) {
#pragma unroll
        for (int it = 0; it < 4; ++it)
            if (loff[it] >= 0)
                L[it] = *(const uint4*)(inb + goff[it] + ci0_);
    };

    auto STAGE_WRITE = [&](int ci0_, int b_) {
        char* db = (char*)s_img + b_ * 13056;
#pragma unroll
        for (int it = 0; it < 4; ++it) {
            if (loff[it] < 0) continue;
            uint4 q = L[it];
            if (donorm) {
                U16x8 u; u.u = q;
                U16x8 o;
                if (okm[it]) {
                    int cib = ci0_ + octv[it];
#pragma unroll
                    for (int e = 0; e < 8; ++e) {
                        float v = __uint_as_float((unsigned)u.s[e] << 16);
                        v = fmaxf(fmaf(v, s_scale[cib + e], s_shift[cib + e]), 0.f);
                        o.s[e] = f2b(v);
                    }
                } else {
                    o.u = uint4{0, 0, 0, 0};
                }
                q = o.u;
            }
            *(uint4*)(db + loff[it]) = q;
        }
    };

#define LOADAF(dst, tap_) { \
    const bf16* wt_ = wtap + (size_t)(tap_) * tapstride; \
    _Pragma("unroll") for (int mf = 0; mf < 8; ++mf) \
        dst[mf] = *(const v8s*)(wt_ + (size_t)mf * 16 * Cin); }

#define TAPBODY(cur, nxt, tap_, pre_) { \
    const int ky_ = (tap_) / 3, kx_ = (tap_) - 3 * ky_; \
    int pb_ = (wv + ky_) * 34 + kx_ + c; \
    int p1_ = pb_ + 16; \
    v8s b0_ = *(const v8s*)(sb + pb_ * 64 + (((quad + (pb_ >> 1)) & 3) << 4)); \
    v8s b1_ = *(const v8s*)(sb + p1_ * 64 + (((quad + (p1_ >> 1)) & 3) << 4)); \
    if (pre_) { LOADAF(nxt, (tap_) + 1); } \
    _Pragma("unroll") for (int mf = 0; mf < 8; ++mf) { \
        acc[mf][0] = __builtin_amdgcn_mfma_f32_16x16x32_bf16(cur[mf], b0_, acc[mf][0], 0, 0, 0); \
        acc[mf][1] = __builtin_amdgcn_mfma_f32_16x16x32_bf16(cur[mf], b1_, acc[mf][1], 0, 0, 0); } }

    // prologue
    STAGE_LOAD(0);
    if (donorm) {
        for (int ch = t; ch < Cin; ch += 256) {
            int gl = n * Gn + ch / cpg;
            float mu  = gstat[2 * gl] * inv_pg;
            float var = fmaxf(gstat[2 * gl + 1] * inv_pg - mu * mu, 0.f);
            float iv  = rsqrtf(var + 1e-5f);
            float ga  = ldg_any(gamma, gb_off + ch, fw);
            float be  = ldg_any(beta,  gb_off + ch, fw);
            s_scale[ch] = iv * ga;
            s_shift[ch] = be - mu * iv * ga;
        }
    }
    __syncthreads();
    STAGE_WRITE(0, 0);
    __syncthreads();

    const size_t tapstride = (size_t)Cpad * Cin;
    for (int ci0 = 0; ci0 < Cin; ci0 += 32) {
        const int buf = (ci0 >> 5) & 1;
        const bool more = (ci0 + 32 < Cin);
        if (more) STAGE_LOAD(ci0 + 32);
        {
            const char* sb = (const char*)s_img + buf * 13056;
            const bf16* wtap = wrep + (size_t)(cb * 128 + c) * Cin + (size_t)quad * 8 + ci0;
            v8s afA[8], afB[8];
            LOADAF(afA, 0);
            TAPBODY(afA, afB, 0, true);
            TAPBODY(afB, afA, 1, true);
            TAPBODY(afA, afB, 2, true);
            TAPBODY(afB, afA, 3, true);
            TAPBODY(afA, afB, 4, true);
            TAPBODY(afB, afA, 5, true);
            TAPBODY(afA, afB, 6, true);
            TAPBODY(afB, afA, 7, true);
            TAPBODY(afA, afB, 8, false);
        }
        if (more) STAGE_WRITE(ci0 + 32, buf ^ 1);
        __syncthreads();
    }
#undef TAPBODY
#undef LOADAF

    // epilogue: C/D layout col(lane&15)=pixel x, row(quad*4+reg)=co
    const int y = y0 + wv;
    if (outm == 0) {
        if (y < H) {
            bf16* ob = (bf16*)out + ((size_t)n * PIX + (size_t)(y + 1) * Wq + 1) * out_C;
#pragma unroll
            for (int mf = 0; mf < 8; ++mf) {
                int co = cb * 128 + mf * 16 + quad * 4;
#pragma unroll
                for (int nf = 0; nf < 2; ++nf) {
                    int x = x0 + nf * 16 + c;
                    if (x < W) {
                        uint2 o;
                        o.x = f2b(acc[mf][nf][0]) | ((unsigned)f2b(acc[mf][nf][1]) << 16);
                        o.y = f2b(acc[mf][nf][2]) | ((unsigned)f2b(acc[mf][nf][3]) << 16);
                        *(uint2*)(ob + (size_t)x * out_C + co) = o;
                    }
                }
            }
        }
    } else {
        const float al = scale ? ldg_any(scale, sidx, fw) : 1.f;
        const int HW = H * W;
        if (y < H) {
#pragma unroll
            for (int mf = 0; mf < 8; ++mf) {
                int cobase = cb * 128 + mf * 16 + quad * 4;
#pragma unroll
                for (int reg = 0; reg < 4; ++reg) {
                    int co = cobase + reg;
                    if (co >= Cout) continue;
                    float bv = bias ? ldg_any(bias, co, fw) : 0.f;
                    size_t obase = out_off + ((size_t)n * Cout + co) * HW + (size_t)y * W;
#pragma unroll
                    for (int nf = 0; nf < 2; ++nf) {
                        int x = x0 + nf * 16 + c;
                        if (x < W)
                            stg_any(out, obase + x, fmaf(al, acc[mf][nf][reg], bv), fout);
                    }
                }
            }
        }
    }
}

// ---------------------------------------------------------------------------
// GroupNorm stats over NHWC padded buffer (borders zero -> harmless).
// Hierarchical: per-wave xor-shuffle -> cross-wave LDS -> octet->group
// segmented shuffle -> ONE atomicAdd per (group,stat) per block.
// (Old version did per-lane atomics: ~8K same-address fp32 RMWs = 400 us.)
// ---------------------------------------------------------------------------
__global__ __launch_bounds__(256) void gn_stats_nhwc(const bf16* __restrict__ x,
                                                     float* __restrict__ stats,
                                                     int C8, int cpg8, int Gn,
                                                     long nvec, int planeC)
{
    const int n = blockIdx.z;
    const bf16* xp = x + (size_t)n * planeC;
    const int t = threadIdx.x;
    const int oct = t & (C8 - 1);
    float s = 0.f, ss = 0.f;
    const long stride = 256L * gridDim.x;
    for (long v = (long)blockIdx.x * 256 + t; v < nvec; v += stride) {
        uint4 u = *(const uint4*)(xp + v * 8);
        float f0,f1,f2,f3,f4,f5,f6,f7;
        b2f2(u.x, f0, f1); b2f2(u.y, f2, f3); b2f2(u.z, f4, f5); b2f2(u.w, f6, f7);
        s += ((f0+f1)+(f2+f3)) + ((f4+f5)+(f6+f7));
        ss = fmaf(f0,f0,ss); ss = fmaf(f1,f1,ss); ss = fmaf(f2,f2,ss); ss = fmaf(f3,f3,ss);
        ss = fmaf(f4,f4,ss); ss = fmaf(f5,f5,ss); ss = fmaf(f6,f6,ss); ss = fmaf(f7,f7,ss);
    }
    // fold lanes sharing the same octet within the wave
    for (int off = C8; off < 64; off <<= 1) {
        s  += __shfl_xor(s,  off, 64);
        ss += __shfl_xor(ss, off, 64);
    }
    __shared__ float red[4][32][2];
    const int wvi = t >> 6;
    if ((t & 63) < C8) { red[wvi][oct][0] = s; red[wvi][oct][1] = ss; }
    __syncthreads();
    if (t < C8) {
        s  = red[0][t][0] + red[1][t][0] + red[2][t][0] + red[3][t][0];
        ss = red[0][t][1] + red[1][t][1] + red[2][t][1] + red[3][t][1];
        // reduce octets within a group (cpg8 consecutive octets, pow2)
        for (int off = cpg8 >> 1; off >= 1; off >>= 1) {
            s  += __shfl_down(s,  off, 64);
            ss += __shfl_down(ss, off, 64);
        }
        if ((t & (cpg8 - 1)) == 0) {
            int gl = n * Gn + t / cpg8;
            atomicAdd(&stats[2 * gl],     s);
            atomicAdd(&stats[2 * gl + 1], ss);
        }
    }
}

// GroupNorm apply + relu on NHWC padded interior (borders stay zero).
__global__ void gn_apply_nhwc(bf16* __restrict__ x, const float* __restrict__ stats,
                              const void* __restrict__ gamma, const void* __restrict__ beta,
                              size_t gb_off, const int* __restrict__ flags,
                              int C, int cpg, int Gn, int H, int W, int Wq, int PIX,
                              float inv_len, long total)
{
    const bool fw = flags[0] != 0;
    long v = (long)blockIdx.x * 256 + threadIdx.x;
    if (v >= total) return;
    const int C8 = C >> 3;
    int oct = (int)(v & (C8 - 1));
    long rest = v / C8;
    int x2 = (int)(rest % W);
    long r2 = rest / W;
    int y = (int)(r2 % H);
    int n = (int)(r2 / H);
    int ch0 = oct * 8;
    int gl = n * Gn + ch0 / cpg;
    float mu  = stats[2 * gl] * inv_len;
    float var = fmaxf(stats[2 * gl + 1] * inv_len - mu * mu, 0.f);
    float iv  = rsqrtf(var + 1e-5f);
    size_t base = ((size_t)n * PIX + (size_t)(y + 1) * Wq + (x2 + 1)) * C + ch0;
    U16x8 u; u.u = *(const uint4*)(x + base);
    U16x8 o;
#pragma unroll
    for (int e = 0; e < 8; ++e) {
        float ga = ldg_any(gamma, gb_off + ch0 + e, fw);
        float be = ldg_any(beta,  gb_off + ch0 + e, fw);
        float f = __uint_as_float((unsigned)u.s[e] << 16);
        f = fmaxf(fmaf(f, iv * ga, be - mu * iv * ga), 0.f);
        o.s[e] = f2b(f);
    }
    *(uint4*)(x + base) = o.u;
}

// ---------------------------------------------------------------------------
__global__ void extract_params_k(const void* __restrict__ pred3, const int* __restrict__ flags,
                                 float* __restrict__ prm, int HW)
{
    const bool bf = flags[0] != 0;
    int tid = blockIdx.x * blockDim.x + threadIdx.x;
    if (tid >= 200 * 169) return;
    int p = tid / 169, c = tid - p * 169;
    int b = p / 100, i = p - b * 100;
    prm[tid] = ldg_any(pred3, ((size_t)b * 254 + 85 + c) * HW + i, bf);
}

// bilinear upsample (align corners), NHWC padded src -> add into NHWC padded dst
__global__ void upsample_add_nhwc(const bf16* __restrict__ src, bf16* __restrict__ dst,
                                  int h, int w, int sWq, int sPIX,
                                  int OH, int OW, int dWq, int dPIX, long total)
{
    long i = (long)blockIdx.x * 256 + threadIdx.x;
    if (i >= total) return;
    const int C = 128, C8 = 16;
    int oct = (int)(i & (C8 - 1));
    long rest = i >> 4;
    int ox = (int)(rest % OW);
    long r = rest / OW;
    int oy = (int)(r % OH);
    int n  = (int)(r / OH);
    float sy = oy * ((h - 1.f) / (OH - 1.f));
    float sx = ox * ((w - 1.f) / (OW - 1.f));
    int y0 = (int)sy; int y1 = min(y0 + 1, h - 1); float wy = sy - y0;
    int x0 = (int)sx; int x1 = min(x0 + 1, w - 1); float wx = sx - x0;
    const bf16* sp = src + (size_t)n * sPIX * C + oct * 8;
    U16x8 q00, q01, q10, q11;
    q00.u = *(const uint4*)(sp + ((size_t)(y0 + 1) * sWq + (x0 + 1)) * C);
    q01.u = *(const uint4*)(sp + ((size_t)(y0 + 1) * sWq + (x1 + 1)) * C);
    q10.u = *(const uint4*)(sp + ((size_t)(y1 + 1) * sWq + (x0 + 1)) * C);
    q11.u = *(const uint4*)(sp + ((size_t)(y1 + 1) * sWq + (x1 + 1)) * C);
    bf16* dp = dst + ((size_t)n * dPIX + (size_t)(oy + 1) * dWq + (ox + 1)) * C + oct * 8;
    U16x8 d; d.u = *(const uint4*)dp;
    U16x8 o;
#pragma unroll
    for (int e = 0; e < 8; ++e) {
        float a00 = __uint_as_float((unsigned)q00.s[e] << 16);
        float a01 = __uint_as_float((unsigned)q01.s[e] << 16);
        float a10 = __uint_as_float((unsigned)q10.s[e] << 16);
        float a11 = __uint_as_float((unsigned)q11.s[e] << 16);
        float t0 = a00 * (1.f - wy) + a10 * wy;
        float t1 = a01 * (1.f - wy) + a11 * wy;
        float dv = __uint_as_float((unsigned)d.s[e] << 16);
        o.s[e] = f2b(dv + t0 * (1.f - wx) + t1 * wx);
    }
    *(uint4*)dp = o.u;
}

__global__ void resize_out_k(const float* __restrict__ src, void* __restrict__ dst,
                             size_t dst_off, const int* __restrict__ flags,
                             int h, int w, int OH, int OW, long total)
{
    const bool bf = flags[0] != 0;
    long i = (long)blockIdx.x * blockDim.x + threadIdx.x;
    if (i >= total) return;
    int ox = (int)(i % OW);
    long r = i / OW;
    int oy = (int)(r % OH);
    int nc = (int)(r / OH);
    float sy = oy * ((h - 1.f) / (OH - 1.f));
    float sx = ox * ((w - 1.f) / (OW - 1.f));
    int y0 = (int)sy; int y1 = min(y0 + 1, h - 1); float wy = sy - y0;
    int x0 = (int)sx; int x1 = min(x0 + 1, w - 1); float wx = sx - x0;
    const float* sp = src + (size_t)nc * h * w;
    float t0 = sp[y0 * w + x0] * (1.f - wy) + sp[y1 * w + x0] * wy;
    float t1 = sp[y0 * w + x1] * (1.f - wy) + sp[y1 * w + x1] * wy;
    stg_any(dst, dst_off + (size_t)i, t0 * (1.f - wx) + t1 * wx, bf);
}

__global__ void cast_out_k(const bf16* __restrict__ src, void* __restrict__ dst,
                           size_t dst_off, const int* __restrict__ flags, long n)
{
    const bool bf = flags[0] != 0;
    long i = (long)blockIdx.x * blockDim.x + threadIdx.x;
    if (i < n) stg_any(dst, dst_off + (size_t)i, cvt(src[i]), bf);
}

// 1x1 conv: NHWC padded (C=128) -> flat NCHW bf16 (8 ch)
__global__ __launch_bounds__(256) void conv1x1_nhwc(const bf16* __restrict__ in,
                                                    const void* __restrict__ w,
                                                    const int* __restrict__ flags,
                                                    bf16* __restrict__ out,
                                                    int H, int W, int Wq, int PIX)
{
    const bool fw = flags[0] != 0;
    __shared__ float sw[8 * 128];
    for (int i = threadIdx.x; i < 1024; i += 256) sw[i] = ldg_any(w, i, fw);
    __syncthreads();
    const int HW = H * W;
    int idx = blockIdx.x * 256 + threadIdx.x;
    if (idx >= 2 * HW) return;
    int pix = idx % HW, n = idx / HW;
    int y = pix / W, x = pix - y * W;
    const bf16* ip = in + ((size_t)n * PIX + (size_t)(y + 1) * Wq + (x + 1)) * 128;
    float a[8];
#pragma unroll
    for (int o = 0; o < 8; ++o) a[o] = 0.f;
    for (int oc = 0; oc < 16; ++oc) {
        U16x8 q; q.u = *(const uint4*)(ip + oc * 8);
#pragma unroll
        for (int e = 0; e < 8; ++e) {
            float f = __uint_as_float((unsigned)q.s[e] << 16);
#pragma unroll
            for (int o = 0; o < 8; ++o) a[o] = fmaf(sw[o * 128 + oc * 8 + e], f, a[o]);
        }
    }
#pragma unroll
    for (int o = 0; o < 8; ++o)
        out[((size_t)n * 8 + o) * HW + pix] = __float2bfloat16(a[o]);
}

// GroupNorm stats/apply on FLAT planar bf16 (mfeat)
__global__ __launch_bounds__(256) void gn_stats_v(const bf16* __restrict__ x,
                                                  float* __restrict__ stats, int per_group)
{
    const int g = blockIdx.x;
    const uint4* xp = (const uint4*)(x + (size_t)g * per_group);
    const int nvec = per_group >> 3;
    float s = 0.f, ss = 0.f;
    const int stride = 256 * gridDim.y;
    for (int i = blockIdx.y * 256 + threadIdx.x; i < nvec; i += stride) {
        uint4 u = xp[i];
        float f0,f1,f2,f3,f4,f5,f6,f7;
        b2f2(u.x, f0, f1); b2f2(u.y, f2, f3); b2f2(u.z, f4, f5); b2f2(u.w, f6, f7);
        s += ((f0+f1)+(f2+f3)) + ((f4+f5)+(f6+f7));
        ss = fmaf(f0,f0,ss); ss = fmaf(f1,f1,ss); ss = fmaf(f2,f2,ss); ss = fmaf(f3,f3,ss);
        ss = fmaf(f4,f4,ss); ss = fmaf(f5,f5,ss); ss = fmaf(f6,f6,ss); ss = fmaf(f7,f7,ss);
    }
#pragma unroll
    for (int off = 32; off > 0; off >>= 1) {
        s  += __shfl_down(s,  off, 64);
        ss += __shfl_down(ss, off, 64);
    }
    __shared__ float sh[8];
    const int wv = threadIdx.x >> 6;
    if ((threadIdx.x & 63) == 0) { sh[wv * 2] = s; sh[wv * 2 + 1] = ss; }
    __syncthreads();
    if (threadIdx.x == 0) {
        s  = sh[0] + sh[2] + sh[4] + sh[6];
        ss = sh[1] + sh[3] + sh[5] + sh[7];
        atomicAdd(&stats[2 * g],     s);
        atomicAdd(&stats[2 * g + 1], ss);
    }
}

__global__ void gn_apply_v(bf16* __restrict__ x, const float* __restrict__ stats,
                           const void* __restrict__ gamma, const void* __restrict__ beta,
                           size_t gb_off, const int* __restrict__ flags,
                           int HW, int C, int per_group, float inv_len, long nvec)
{
    const bool fw = flags[0] != 0;
    long v = (long)blockIdx.x * blockDim.x + threadIdx.x;
    if (v >= nvec) return;
    long i0 = v * 8;
    int gl = (int)(i0 / per_group);
    float mu  = stats[2 * gl] * inv_len;
    float var = fmaxf(stats[2 * gl + 1] * inv_len - mu * mu, 0.f);
    float iv  = rsqrtf(var + 1e-5f);
    int cc = (int)((i0 / HW) % C);
    float ga = ldg_any(gamma, gb_off + cc, fw);
    float be = ldg_any(beta,  gb_off + cc, fw);
    float sc = iv * ga, sf = be - mu * iv * ga;
    uint4 u = *(const uint4*)(x + i0);
    float f[8];
    b2f2(u.x, f[0], f[1]); b2f2(u.y, f[2], f[3]);
    b2f2(u.z, f[4], f[5]); b2f2(u.w, f[6], f[7]);
#pragma unroll
    for (int j = 0; j < 8; ++j) f[j] = fmaxf(fmaf(f[j], sc, sf), 0.f);
    uint4 o;
    o.x = f2b(f[0]) | ((unsigned)f2b(f[1]) << 16);
    o.y = f2b(f[2]) | ((unsigned)f2b(f[3]) << 16);
    o.z = f2b(f[4]) | ((unsigned)f2b(f[5]) << 16);
    o.w = f2b(f[6]) | ((unsigned)f2b(f[7]) << 16);
    *(uint4*)(x + i0) = o;
}

__global__ __launch_bounds__(256) void dyn_conv_k(const bf16* __restrict__ mf,
                                                  const float* __restrict__ prm,
                                                  float* __restrict__ out, int H, int W)
{
    const int inst = blockIdx.y;
    __shared__ float p[169];
    if (threadIdx.x < 169) p[threadIdx.x] = prm[inst * 169 + threadIdx.x];
    __syncthreads();
    const int HW = H * W;
    const int pix = blockIdx.x * 256 + threadIdx.x;
    if (pix >= HW) return;
    const int b = inst / 100;
    float xin[10];
#pragma unroll
    for (int c = 0; c < 8; ++c) xin[c] = cvt(mf[((size_t)(b * 8 + c)) * HW + pix]);
    int yy = pix / W, xx = pix - yy * W;
    xin[8] = -1.f + 2.f * xx / (W - 1);
    xin[9] = -1.f + 2.f * yy / (H - 1);
    float h1[8];
#pragma unroll
    for (int o = 0; o < 8; ++o) {
        float s = p[152 + o];
#pragma unroll
        for (int c = 0; c < 10; ++c) s = fmaf(p[o * 10 + c], xin[c], s);
        h1[o] = fmaxf(s, 0.f);
    }
    float h2[8];
#pragma unroll
    for (int o = 0; o < 8; ++o) {
        float s = p[160 + o];
#pragma unroll
        for (int c = 0; c < 8; ++c) s = fmaf(p[80 + o * 8 + c], h1[c], s);
        h2[o] = fmaxf(s, 0.f);
    }
    float s = p[168];
#pragma unroll
    for (int c = 0; c < 8; ++c) s = fmaf(p[144 + c], h2[c], s);
    out[(size_t)inst * HW + pix] = s;
}

// ---------------------------------------------------------------------------
// host helpers
// ---------------------------------------------------------------------------
struct Norm { const float* st; const void* g; const void* b; size_t off; int cpg; int Gn; float inv; };
struct Geo  { int H, W, Wq, Hp, PIX; };

static inline Geo mkgeo(int H, int W) {
    int xb = (W + 31) / 32, yb = (H + 3) / 4;
    Geo g; g.H = H; g.W = W; g.Wq = (xb - 1) * 32 + 34; g.Hp = (yb - 1) * 4 + 6;
    g.PIX = g.Hp * g.Wq;
    return g;
}

static inline void mconv(const bf16* in, const bf16* wrep, const Norm* nm,
                         const void* bias, const void* scale, int sidx,
                         void* out, int outm, size_t out_off, int out_C,
                         const int* flags, int N, int Cin, Geo g, int Cout, hipStream_t s)
{
    int cob = (Cout + 127) / 128, Cpad = cob * 128;
    dim3 gr((g.W + 31) / 32, (g.H + 3) / 4, N * cob);
    conv3x3_mfma_k<<<gr, 256, 0, s>>>(
        in, wrep,
        nm ? nm->st : nullptr, nm ? nm->g : nullptr, nm ? nm->b : nullptr,
        nm ? nm->off : 0, nm ? nm->cpg : 1, nm ? nm->Gn : 1, nm ? nm->inv : 1.f,
        bias, scale, sidx, out, outm, out_off, out_C,
        flags, Cin, g.H, g.W, g.Wq, g.PIX, Cout, Cpad, cob);
}

static inline void run_padT(const void* src, const int* flags, bf16* dst,
                            int N, int C, Geo g, hipStream_t s)
{
    long total = (long)N * g.PIX * (C >> 3);
    padT_k<<<(int)((total + 255) / 256), 256, 0, s>>>(src, flags, dst, C, g.H, g.W,
                                                      g.Wq, g.Hp, g.PIX, total);
}

static inline void run_stats_nhwc(const bf16* x, float* st, int N, int C, int cpg, int Gn,
                                  Geo g, hipStream_t s)
{
    int C8 = C >> 3;
    long nvec = (long)g.PIX * C8;
    int chunks = (int)((nvec + 16383) / 16384);
    if (chunks > 32) chunks = 32; if (chunks < 1) chunks = 1;
    gn_stats_nhwc<<<dim3(chunks, 1, N), 256, 0, s>>>(x, st, C8, cpg >> 3, Gn,
                                                     nvec, g.PIX * C);
}

static inline void run_apply_nhwc(bf16* x, const float* st, const void* gm, const void* bt,
                                  size_t off, const int* flags, int N, int C, int cpg, int Gn,
                                  Geo g, hipStream_t s)
{
    long total = (long)N * g.H * g.W * (C >> 3);
    gn_apply_nhwc<<<(int)((total + 255) / 256), 256, 0, s>>>(
        x, st, gm, bt, off, flags, C, cpg, Gn, g.H, g.W, g.Wq, g.PIX,
        1.f / ((float)cpg * g.H * g.W), total);
}

extern "C" void kernel_launch(void* const* d_in, const int* in_sizes, int n_in,
                              void* d_out, int out_size, void* d_ws, size_t ws_size,
                              hipStream_t stream)
{
    const void* f[5] = {d_in[0], d_in[1], d_in[2], d_in[3], d_in[4]};
    static const int Hs[5] = {96, 48, 24, 12, 6};
    static const int Wd[5] = {160, 80, 40, 20, 10};
    const void* head_w     = d_in[5];
    const void* head_gn_g  = d_in[6];
    const void* head_gn_b  = d_in[7];
    const void* head_out_w = d_in[8];
    const void* head_out_b = d_in[9];
    const void* scales     = d_in[10];
    const void* ref_w      = d_in[11];
    const void* ref_gn_g   = d_in[12];
    const void* ref_gn_b   = d_in[13];
    const void* tow_w      = d_in[14];
    const void* tow_gn_g   = d_in[15];
    const void* tow_gn_b   = d_in[16];
    const void* out_w      = d_in[17];
    const void* out_gn_g   = d_in[18];
    const void* out_gn_b   = d_in[19];

    Geo G[5];
    for (int l = 0; l < 5; ++l) G[l] = mkgeo(Hs[l], Wd[l]);
    // PIX: 15876, 4900, 1716, 476, 340

    size_t po[5]; size_t off = 0;
    for (int l = 0; l < 5; ++l) { po[l] = off; off += (size_t)2 * 254 * Hs[l] * Wd[l]; }
    size_t mf_off = off; off += 245760;
    size_t ml_off = off;

    // ---- workspace (~42 MB) ----
    const size_t ACAP = (size_t)2 * 256 * G[0].PIX;       // 8,128,512 elems
    bf16*  A     = (bf16*)d_ws;
    bf16*  B     = A + ACAP;
    bf16*  B2    = B + ACAP;                              // 2*128*4900 = 1,254,400
    bf16*  mfeat = B2 + 1254400;
    float* prm   = (float*)(mfeat + 245760);              // 33,800 f32
    float* stats = prm + 33800;                           // 4,096 f32
    int*   flags = (int*)(stats + 4096);                  // 16 int
    bf16*  wrep  = (bf16*)(flags + 16);                   // 2,949,120 bf16
    float* dyn   = (float*)A;                             // aliases A after last read

    bf16* wrepH  = wrep;                        // 4 x 589824 (head layers)
    bf16* wrepHO = wrep + 4 * 589824;           // 589824 (head_out, Cpad 256)
    bf16* wrepR  = wrep;                        // mask phase reuses region
    bf16* wrepT  = wrep + 3 * 294912;

    hipMemsetAsync(stats, 0, 4096 * sizeof(float), stream);
    detect_k<<<1, 64, 0, stream>>>((const unsigned int*)d_in[0], flags);

    float* sp = stats;

    // repack head weights
    for (int l = 0; l < 4; ++l) {
        int total = 9 * 256 * 256;
        repack_off_k<<<(total + 255) / 256, 256, 0, stream>>>(
            head_w, (size_t)l * 589824, flags, wrepH + (size_t)l * 589824, 256, 256, 256, total);
    }
    {
        int total = 9 * 256 * 256;
        repack_off_k<<<(total + 255) / 256, 256, 0, stream>>>(
            head_out_w, 0, flags, wrepHO, 254, 256, 256, total);
    }

    // ---------------- head branches ----------------
    for (int lvl = 0; lvl < 5; ++lvl) {
        Geo g = G[lvl];
        int HW = g.H * g.W;
        float inv_pg = 1.f / (8 * HW);
        run_padT(f[lvl], flags, B, 2, 256, g, stream);
        hipMemsetAsync(A, 0, (size_t)2 * 256 * g.PIX * sizeof(bf16), stream);
        mconv(B, wrepH, nullptr, nullptr, nullptr, 0, A, 0, 0, 256,
              flags, 2, 256, g, 256, stream);
        float* s_prev = sp; sp += 128;
        run_stats_nhwc(A, s_prev, 2, 256, 8, 32, g, stream);
        bf16* a = A; bf16* bb = B;
        for (int l = 1; l < 4; ++l) {
            Norm nm{s_prev, head_gn_g, head_gn_b, (size_t)(l - 1) * 256, 8, 32, inv_pg};
            mconv(a, wrepH + (size_t)l * 589824, &nm, nullptr, nullptr, 0,
                  bb, 0, 0, 256, flags, 2, 256, g, 256, stream);
            s_prev = sp; sp += 128;
            run_stats_nhwc(bb, s_prev, 2, 256, 8, 32, g, stream);
            bf16* tmp = a; a = bb; bb = tmp;
        }
        Norm nm{s_prev, head_gn_g, head_gn_b, (size_t)3 * 256, 8, 32, inv_pg};
        mconv(a, wrepHO, &nm, head_out_b, scales, lvl, d_out, 2, po[lvl], 0,
              flags, 2, 256, g, 254, stream);
        if (lvl == 0)
            extract_params_k<<<(200 * 169 + 255) / 256, 256, 0, stream>>>(d_out, flags, prm, HW);
    }

    // repack mask weights (enqueued after all head convs; stream order protects)
    for (int i = 0; i < 3; ++i) {
        int total = 9 * 128 * 256;
        repack_off_k<<<(total + 255) / 256, 256, 0, stream>>>(
            ref_w, (size_t)i * 294912, flags, wrepR + (size_t)i * 294912, 128, 128, 256, total);
    }
    for (int l = 0; l < 4; ++l) {
        int total = 9 * 128 * 128;
        repack_off_k<<<(total + 255) / 256, 256, 0, stream>>>(
            tow_w, (size_t)l * 147456, flags, wrepT + (size_t)l * 147456, 128, 128, 128, total);
    }

    // ---------------- mask branch ----------------
    {
        Geo g0 = G[0];
        const int HW = 96 * 160;

        // refine 0
        run_padT(f[0], flags, B, 2, 256, g0, stream);
        hipMemsetAsync(A, 0, (size_t)2 * 128 * g0.PIX * sizeof(bf16), stream);
        mconv(B, wrepR, nullptr, nullptr, nullptr, 0, A, 0, 0, 128,
              flags, 2, 256, g0, 128, stream);
        float* s0 = sp; sp += 4;
        run_stats_nhwc(A, s0, 2, 128, 128, 1, g0, stream);
        run_apply_nhwc(A, s0, ref_gn_g, ref_gn_b, 0, flags, 2, 128, 128, 1, g0, stream);

        // refines 1,2 + upsample-add into A
        for (int i = 1; i < 3; ++i) {
            Geo gi = G[i];
            run_padT(f[i], flags, B, 2, 256, gi, stream);
            hipMemsetAsync(B2, 0, (size_t)2 * 128 * gi.PIX * sizeof(bf16), stream);
            mconv(B, wrepR + (size_t)i * 294912, nullptr, nullptr, nullptr, 0,
                  B2, 0, 0, 128, flags, 2, 256, gi, 128, stream);
            float* si = sp; sp += 4;
            run_stats_nhwc(B2, si, 2, 128, 128, 1, gi, stream);
            run_apply_nhwc(B2, si, ref_gn_g, ref_gn_b, (size_t)i * 128, flags,
                           2, 128, 128, 1, gi, stream);
            long tot = (long)2 * 96 * 160 * 16;
            upsample_add_nhwc<<<(int)((tot + 255) / 256), 256, 0, stream>>>(
                B2, A, gi.H, gi.W, gi.Wq, gi.PIX, 96, 160, g0.Wq, g0.PIX, tot);
        }

        // tower
        float inv_pg = 1.f / (128 * HW);
        hipMemsetAsync(B, 0, (size_t)2 * 128 * g0.PIX * sizeof(bf16), stream);
        mconv(A, wrepT, nullptr, nullptr, nullptr, 0, B, 0, 0, 128,
              flags, 2, 128, g0, 128, stream);
        float* sT = sp; sp += 4;
        run_stats_nhwc(B, sT, 2, 128, 128, 1, g0, stream);
        bf16* a = B; bf16* bb = A;
        for (int l = 1; l < 4; ++l) {
            Norm nm{sT, tow_gn_g, tow_gn_b, (size_t)(l - 1) * 128, 128, 1, inv_pg};
            mconv(a, wrepT + (size_t)l * 147456, &nm, nullptr, nullptr, 0,
                  bb, 0, 0, 128, flags, 2, 128, g0, 128, stream);
            sT = sp; sp += 4;
            run_stats_nhwc(bb, sT, 2, 128, 128, 1, g0, stream);
            bf16* tmp = a; a = bb; bb = tmp;
        }
        // final tower raw in a (= A), stats sT
        run_apply_nhwc(a, sT, tow_gn_g, tow_gn_b, (size_t)3 * 128, flags, 2, 128, 128, 1, g0, stream);
        conv1x1_nhwc<<<(2 * HW + 255) / 256, 256, 0, stream>>>(
            a, out_w, flags, mfeat, 96, 160, g0.Wq, g0.PIX);
        float* sM = sp; sp += 4;
        {
            int chunks = (8 * HW) / 8192; if (chunks < 1) chunks = 1;
            gn_stats_v<<<dim3(2, chunks), 256, 0, stream>>>(mfeat, sM, 8 * HW);
            long nvec = ((long)2 * 8 * HW) >> 3;
            gn_apply_v<<<(int)((nvec + 255) / 256), 256, 0, stream>>>(
                mfeat, sM, out_gn_g, out_gn_b, 0, flags, HW, 8, 8 * HW, 1.f / (8 * HW), nvec);
        }
        cast_out_k<<<(2 * 8 * HW + 255) / 256, 256, 0, stream>>>(
            mfeat, d_out, mf_off, flags, (long)2 * 8 * HW);
        dyn_conv_k<<<dim3((HW + 255) / 256, 200), 256, 0, stream>>>(mfeat, prm, dyn, 96, 160);
        long nt = (long)200 * 192 * 320;
        resize_out_k<<<(int)((nt + 255) / 256), 256, 0, stream>>>(
            dyn, d_out, ml_off, flags, 96, 160, 192, 320, nt);
    }
}

// Round 5
// 2772.129 us; speedup vs baseline: 2.5064x; 1.7333x over previous
//
#include <hip/hip_runtime.h>
#include <hip/hip_bf16.h>

typedef __hip_bfloat16 bf16;
typedef short v8s __attribute__((ext_vector_type(8)));
typedef float v4f __attribute__((ext_vector_type(4)));

__device__ __forceinline__ float cvt(bf16 v) { return __bfloat162float(v); }

__device__ __forceinline__ float ldg_any(const void* p, size_t i, bool bf) {
    return bf ? cvt(((const bf16*)p)[i]) : ((const float*)p)[i];
}
__device__ __forceinline__ void stg_any(void* p, size_t i, float v, bool bf) {
    if (bf) ((bf16*)p)[i] = __float2bfloat16(v);
    else    ((float*)p)[i] = v;
}
__device__ __forceinline__ bool bfmode(int mode, const int* flags) {
    return mode == 2 ? (flags[0] != 0) : (mode != 0);
}
__device__ __forceinline__ unsigned short f2b(float f) {
    bf16 h = __float2bfloat16(f); return *(unsigned short*)&h;
}
__device__ __forceinline__ void b2f2(unsigned u, float& a, float& b) {
    a = __uint_as_float(u << 16);
    b = __uint_as_float(u & 0xffff0000u);
}

union U16x8 { uint4 u; unsigned short s[8]; };

// ---------------------------------------------------------------------------
// dtype probe on f3 (N(0,1) data): fp32 never has exponent >= 200.
// ---------------------------------------------------------------------------
__global__ void detect_k(const unsigned int* __restrict__ x, int* __restrict__ flags)
{
    unsigned int u = x[threadIdx.x];
    int e = (u >> 23) & 0xFF;
    unsigned long long m = __ballot(e >= 200);
    if (threadIdx.x == 0) flags[0] = (m != 0ULL) ? 1 : 0;
}

// ---------------------------------------------------------------------------
// weight repack: OIHW (+element offset) -> [tap][co(pad)][ci] bf16
// ---------------------------------------------------------------------------
__global__ void repack_off_k(const void* __restrict__ w, size_t w_off,
                             const int* __restrict__ flags, bf16* __restrict__ dst,
                             int Cout, int Cpad, int Cin, int total)
{
    const bool fw = flags[0] != 0;
    int i = blockIdx.x * 256 + threadIdx.x;
    if (i >= total) return;
    int ci = i % Cin; int r = i / Cin; int co = r % Cpad; int tap = r / Cpad;
    float v = 0.f;
    if (co < Cout) v = ldg_any(w, w_off + ((size_t)co * Cin + ci) * 9 + tap, fw);
    dst[i] = __float2bfloat16(v);
}

// ---------------------------------------------------------------------------
// pad + transpose: NCHW (fp32/bf16) -> NHWC padded bf16 [n][Hp][Wq][C].
// ---------------------------------------------------------------------------
__global__ void padT_k(const void* __restrict__ src, const int* __restrict__ flags,
                       bf16* __restrict__ dst, int C, int H, int W, int Wq, int Hp,
                       int PIX, long total)
{
    const bool fb = flags[0] != 0;
    long v = (long)blockIdx.x * 256 + threadIdx.x;
    if (v >= total) return;
    const int C8 = C >> 3;
    int oct = (int)(v & (C8 - 1));
    long rest = v >> (C == 256 ? 5 : 4);
    int px = (int)(rest % Wq);
    long r2 = rest / Wq;
    int py = (int)(r2 % Hp);
    int n  = (int)(r2 / Hp);
    U16x8 o;
    if (py == 0 || py > H || px == 0 || px > W) {
        o.u = uint4{0, 0, 0, 0};
    } else {
        const int HW = H * W;
        size_t sb = ((size_t)n * C + oct * 8) * HW + (size_t)(py - 1) * W + (px - 1);
#pragma unroll
        for (int e = 0; e < 8; ++e) o.s[e] = f2b(ldg_any(src, sb + (size_t)e * HW, fb));
    }
    *(uint4*)(dst + v * 8) = o.u;
}

// ---------------------------------------------------------------------------
// MFMA implicit-GEMM 3x3 SAME conv, NHWC padded input, LDS-staged WEIGHTS.
// Block: 128 co x (4 rows x 32 cols); 4 waves tiled 2(co-slice) x 2(row-pair):
// each wave computes 64co x (2 rows x 32 cols) = acc[4][4].
// K loop: Cin chunks of 32, each chunk split into 3 phases (kernel row ky):
// per phase all 256 threads cooperatively stage 3taps x 128co x 32ci weights
// (24KB) into a double-buffered LDS slab (coalesced uint4), while MFMAs read
// the previous slab via conflict-free ds_read_b128. One barrier per phase.
// Image chunk staged per chunk (as before, swizzled, double-buffered).
// ---------------------------------------------------------------------------
__global__ __launch_bounds__(256, 2) void conv3x3_mfma_k(
    const bf16* __restrict__ in,      // NHWC padded
    const bf16* __restrict__ wrep,    // [tap][co pad][ci]
    const float* __restrict__ gstat, const void* __restrict__ gamma,
    const void* __restrict__ beta, size_t gb_off, int cpg, int Gn, float inv_pg,
    const void* __restrict__ bias, const void* __restrict__ scale, int sidx,
    void* __restrict__ out, int outm, size_t out_off, int out_C,
    const int* __restrict__ flags,
    int Cin, int H, int W, int Wq, int PIX, int Cout, int Cpad, int co_blocks)
{
    const bool fw   = flags[0] != 0;
    const bool fout = bfmode(outm, flags);

    const int t    = threadIdx.x;
    const int lane = t & 63;
    const int wv   = t >> 6;
    const int c    = lane & 15;
    const int quad = lane >> 4;
    const int wr   = wv >> 1;     // wave row-pair (0,1)
    const int wc   = wv & 1;      // wave co-slice (0,1)
    const int x0   = blockIdx.x * 32;
    const int y0   = blockIdx.y * 4;
    const int n    = blockIdx.z / co_blocks;
    const int cb   = blockIdx.z % co_blocks;

    __shared__ __align__(16) bf16 s_img[2][204 * 32];   // [buf][pos][32ci swizzled]
    __shared__ __align__(16) bf16 s_w[2][3 * 128 * 32]; // [buf][kx][co][32ci]
    __shared__ float s_scale[256], s_shift[256];

    const bool donorm = (gstat != nullptr);

    v4f acc[4][4];
#pragma unroll
    for (int i = 0; i < 4; ++i)
#pragma unroll
        for (int j = 0; j < 4; ++j) acc[i][j] = v4f{0.f, 0.f, 0.f, 0.f};

    const bf16* inb = in + (size_t)n * PIX * Cin;

    // static image staging map: flat = t + 256*it over 816 = 204 pos x 4 octets
    int goff[4], loff[4], okm[4], octv[4];
#pragma unroll
    for (int it = 0; it < 4; ++it) {
        int flat = t + 256 * it;
        int pos = flat >> 2, oct = flat & 3;
        int r = (pos * 241) >> 13;          // pos / 34 (exact for pos < 204)
        int cc = pos - r * 34;
        int py = y0 + r, px = x0 + cc;
        bool valid = flat < 816;
        goff[it] = (py * Wq + px) * Cin + oct * 8;
        loff[it] = valid ? (pos * 64 + (((oct + (pos >> 1)) & 3) << 4)) : -1;
        okm[it]  = (py >= 1 && py <= H && px >= 1 && px <= W) ? 1 : 0;
        octv[it] = oct * 8;
    }

    uint4 L[4];
    uint4 wrg[6];

#define STAGE_LOAD(ci0_) { \
    _Pragma("unroll") for (int it = 0; it < 4; ++it) \
        if (loff[it] >= 0) L[it] = *(const uint4*)(inb + goff[it] + (ci0_)); }

#define STAGE_WRITE(ci0_, b_) { \
    char* db = (char*)&s_img[b_][0]; \
    _Pragma("unroll") for (int it = 0; it < 4; ++it) { \
        if (loff[it] < 0) continue; \
        uint4 q = L[it]; \
        if (donorm) { \
            U16x8 u_; u_.u = q; U16x8 o_; \
            if (okm[it]) { \
                int cib = (ci0_) + octv[it]; \
                _Pragma("unroll") for (int e = 0; e < 8; ++e) { \
                    float v_ = __uint_as_float((unsigned)u_.s[e] << 16); \
                    v_ = fmaxf(fmaf(v_, s_scale[cib + e], s_shift[cib + e]), 0.f); \
                    o_.s[e] = f2b(v_); } \
            } else { o_.u = uint4{0, 0, 0, 0}; } \
            q = o_.u; } \
        *(uint4*)(db + loff[it]) = q; } }

// cooperative coalesced weight stage: phase (ky=g_) of chunk ci0_, 24KB
#define WLOAD(ci0_, g_) { \
    _Pragma("unroll") for (int j = 0; j < 6; ++j) { \
        int f_ = t + 256 * j; int tapl_ = f_ >> 9; int rem_ = f_ & 511; \
        wrg[j] = *(const uint4*)(wrep + ((size_t)(3 * (g_) + tapl_) * Cpad \
                 + cb * 128 + (rem_ >> 2)) * (size_t)Cin + (ci0_) + (rem_ & 3) * 8); } }

#define WSTORE(b_) { \
    _Pragma("unroll") for (int j = 0; j < 6; ++j) { \
        int f_ = t + 256 * j; int tapl_ = f_ >> 9; int rem_ = f_ & 511; \
        *(uint4*)(&s_w[b_][tapl_ * 4096 + (rem_ >> 2) * 32 + (rem_ & 3) * 8]) = wrg[j]; } }

// MFMA phase: kernel row g_, 3 kx taps, 48 MFMAs/wave
#define MPHASE(ib_, wb_, g_) { \
    const char* sb_ = (const char*)&s_img[ib_][0]; \
    const bf16* wp_ = &s_w[wb_][0]; \
    _Pragma("unroll") for (int kx = 0; kx < 3; ++kx) { \
        v8s bfr[4]; \
        _Pragma("unroll") for (int nf = 0; nf < 4; ++nf) { \
            int pos = (2 * wr + (nf >> 1) + (g_)) * 34 + kx + c + (nf & 1) * 16; \
            bfr[nf] = *(const v8s*)(sb_ + pos * 64 + (((quad + (pos >> 1)) & 3) << 4)); } \
        _Pragma("unroll") for (int mf = 0; mf < 4; ++mf) { \
            v8s af = *(const v8s*)(wp_ + kx * 4096 + (wc * 64 + mf * 16 + c) * 32 + quad * 8); \
            _Pragma("unroll") for (int nf = 0; nf < 4; ++nf) \
                acc[mf][nf] = __builtin_amdgcn_mfma_f32_16x16x32_bf16( \
                    af, bfr[nf], acc[mf][nf], 0, 0, 0); } } }

    // prologue: stage img chunk 0 and weight phase (0, ky=0)
    STAGE_LOAD(0);
    WLOAD(0, 0);
    if (donorm) {
        for (int ch = t; ch < Cin; ch += 256) {
            int gl = n * Gn + ch / cpg;
            float mu  = gstat[2 * gl] * inv_pg;
            float var = fmaxf(gstat[2 * gl + 1] * inv_pg - mu * mu, 0.f);
            float iv  = rsqrtf(var + 1e-5f);
            float ga  = ldg_any(gamma, gb_off + ch, fw);
            float be  = ldg_any(beta,  gb_off + ch, fw);
            s_scale[ch] = iv * ga;
            s_shift[ch] = be - mu * iv * ga;
        }
    }
    __syncthreads();
    STAGE_WRITE(0, 0);
    WSTORE(0);
    __syncthreads();

    // main loop: two 32-ci chunks per iteration (6 phases), static buffers
    for (int ci0 = 0; ci0 < Cin; ci0 += 64) {
        const bool moreB = (ci0 + 64 < Cin);
        // P0: chunk A, ky=0, img0, w0
        STAGE_LOAD(ci0 + 32);
        WLOAD(ci0, 1);
        MPHASE(0, 0, 0);
        WSTORE(1);
        __syncthreads();
        // P1: A, ky=1, w1
        WLOAD(ci0, 2);
        MPHASE(0, 1, 1);
        WSTORE(0);
        __syncthreads();
        // P2: A, ky=2, w0; write img chunk B
        WLOAD(ci0 + 32, 0);
        MPHASE(0, 0, 2);
        STAGE_WRITE(ci0 + 32, 1);
        WSTORE(1);
        __syncthreads();
        // P3: chunk B, ky=0, img1, w1
        if (moreB) STAGE_LOAD(ci0 + 64);
        WLOAD(ci0 + 32, 1);
        MPHASE(1, 1, 0);
        WSTORE(0);
        __syncthreads();
        // P4: B, ky=1, w0
        WLOAD(ci0 + 32, 2);
        MPHASE(1, 0, 1);
        WSTORE(1);
        __syncthreads();
        // P5: B, ky=2, w1; prefetch next iteration
        if (moreB) { WLOAD(ci0 + 64, 0); }
        MPHASE(1, 1, 2);
        if (moreB) { STAGE_WRITE(ci0 + 64, 0); WSTORE(0); }
        __syncthreads();
    }
#undef MPHASE
#undef WSTORE
#undef WLOAD
#undef STAGE_WRITE
#undef STAGE_LOAD

    // epilogue: C/D layout col(lane&15)=pixel x, row(quad*4+reg)=co
    const int ybase = y0 + 2 * wr;
    if (outm == 0) {
        bf16* ob = (bf16*)out + (size_t)n * PIX * out_C;
#pragma unroll
        for (int mf = 0; mf < 4; ++mf) {
            int co = cb * 128 + wc * 64 + mf * 16 + quad * 4;
#pragma unroll
            for (int nf = 0; nf < 4; ++nf) {
                int y = ybase + (nf >> 1);
                int x = x0 + (nf & 1) * 16 + c;
                if (y < H && x < W) {
                    uint2 o;
                    o.x = f2b(acc[mf][nf][0]) | ((unsigned)f2b(acc[mf][nf][1]) << 16);
                    o.y = f2b(acc[mf][nf][2]) | ((unsigned)f2b(acc[mf][nf][3]) << 16);
                    *(uint2*)(ob + ((size_t)(y + 1) * Wq + (x + 1)) * out_C + co) = o;
                }
            }
        }
    } else {
        const float al = scale ? ldg_any(scale, sidx, fw) : 1.f;
        const int HW = H * W;
#pragma unroll
        for (int mf = 0; mf < 4; ++mf) {
            int cobase = cb * 128 + wc * 64 + mf * 16 + quad * 4;
#pragma unroll
            for (int reg = 0; reg < 4; ++reg) {
                int co = cobase + reg;
                if (co >= Cout) continue;
                float bv = bias ? ldg_any(bias, co, fw) : 0.f;
                size_t obase = out_off + ((size_t)n * Cout + co) * HW;
#pragma unroll
                for (int nf = 0; nf < 4; ++nf) {
                    int y = ybase + (nf >> 1);
                    int x = x0 + (nf & 1) * 16 + c;
                    if (y < H && x < W)
                        stg_any(out, obase + (size_t)y * W + x,
                                fmaf(al, acc[mf][nf][reg], bv), fout);
                }
            }
        }
    }
}

// ---------------------------------------------------------------------------
// GroupNorm stats over NHWC padded buffer (borders zero -> harmless).
// Hierarchical: per-wave xor-shuffle -> cross-wave LDS -> octet->group
// segmented shuffle -> ONE atomicAdd per (group,stat) per block.
// ---------------------------------------------------------------------------
__global__ __launch_bounds__(256) void gn_stats_nhwc(const bf16* __restrict__ x,
                                                     float* __restrict__ stats,
                                                     int C8, int cpg8, int Gn,
                                                     long nvec, int planeC)
{
    const int n = blockIdx.z;
    const bf16* xp = x + (size_t)n * planeC;
    const int t = threadIdx.x;
    const int oct = t & (C8 - 1);
    float s = 0.f, ss = 0.f;
    const long stride = 256L * gridDim.x;
    for (long v = (long)blockIdx.x * 256 + t; v < nvec; v += stride) {
        uint4 u = *(const uint4*)(xp + v * 8);
        float f0,f1,f2,f3,f4,f5,f6,f7;
        b2f2(u.x, f0, f1); b2f2(u.y, f2, f3); b2f2(u.z, f4, f5); b2f2(u.w, f6, f7);
        s += ((f0+f1)+(f2+f3)) + ((f4+f5)+(f6+f7));
        ss = fmaf(f0,f0,ss); ss = fmaf(f1,f1,ss); ss = fmaf(f2,f2,ss); ss = fmaf(f3,f3,ss);
        ss = fmaf(f4,f4,ss); ss = fmaf(f5,f5,ss); ss = fmaf(f6,f6,ss); ss = fmaf(f7,f7,ss);
    }
    for (int off = C8; off < 64; off <<= 1) {
        s  += __shfl_xor(s,  off, 64);
        ss += __shfl_xor(ss, off, 64);
    }
    __shared__ float red[4][32][2];
    const int wvi = t >> 6;
    if ((t & 63) < C8) { red[wvi][oct][0] = s; red[wvi][oct][1] = ss; }
    __syncthreads();
    if (t < C8) {
        s  = red[0][t][0] + red[1][t][0] + red[2][t][0] + red[3][t][0];
        ss = red[0][t][1] + red[1][t][1] + red[2][t][1] + red[3][t][1];
        for (int off = cpg8 >> 1; off >= 1; off >>= 1) {
            s  += __shfl_down(s,  off, 64);
            ss += __shfl_down(ss, off, 64);
        }
        if ((t & (cpg8 - 1)) == 0) {
            int gl = n * Gn + t / cpg8;
            atomicAdd(&stats[2 * gl],     s);
            atomicAdd(&stats[2 * gl + 1], ss);
        }
    }
}

// GroupNorm apply + relu on NHWC padded interior (borders stay zero).
__global__ void gn_apply_nhwc(bf16* __restrict__ x, const float* __restrict__ stats,
                              const void* __restrict__ gamma, const void* __restrict__ beta,
                              size_t gb_off, const int* __restrict__ flags,
                              int C, int cpg, int Gn, int H, int W, int Wq, int PIX,
                              float inv_len, long total)
{
    const bool fw = flags[0] != 0;
    long v = (long)blockIdx.x * 256 + threadIdx.x;
    if (v >= total) return;
    const int C8 = C >> 3;
    int oct = (int)(v & (C8 - 1));
    long rest = v / C8;
    int x2 = (int)(rest % W);
    long r2 = rest / W;
    int y = (int)(r2 % H);
    int n = (int)(r2 / H);
    int ch0 = oct * 8;
    int gl = n * Gn + ch0 / cpg;
    float mu  = stats[2 * gl] * inv_len;
    float var = fmaxf(stats[2 * gl + 1] * inv_len - mu * mu, 0.f);
    float iv  = rsqrtf(var + 1e-5f);
    size_t base = ((size_t)n * PIX + (size_t)(y + 1) * Wq + (x2 + 1)) * C + ch0;
    U16x8 u; u.u = *(const uint4*)(x + base);
    U16x8 o;
#pragma unroll
    for (int e = 0; e < 8; ++e) {
        float ga = ldg_any(gamma, gb_off + ch0 + e, fw);
        float be = ldg_any(beta,  gb_off + ch0 + e, fw);
        float f = __uint_as_float((unsigned)u.s[e] << 16);
        f = fmaxf(fmaf(f, iv * ga, be - mu * iv * ga), 0.f);
        o.s[e] = f2b(f);
    }
    *(uint4*)(x + base) = o.u;
}

// ---------------------------------------------------------------------------
__global__ void extract_params_k(const void* __restrict__ pred3, const int* __restrict__ flags,
                                 float* __restrict__ prm, int HW)
{
    const bool bf = flags[0] != 0;
    int tid = blockIdx.x * blockDim.x + threadIdx.x;
    if (tid >= 200 * 169) return;
    int p = tid / 169, c = tid - p * 169;
    int b = p / 100, i = p - b * 100;
    prm[tid] = ldg_any(pred3, ((size_t)b * 254 + 85 + c) * HW + i, bf);
}

// bilinear upsample (align corners), NHWC padded src -> add into NHWC padded dst
__global__ void upsample_add_nhwc(const bf16* __restrict__ src, bf16* __restrict__ dst,
                                  int h, int w, int sWq, int sPIX,
                                  int OH, int OW, int dWq, int dPIX, long total)
{
    long i = (long)blockIdx.x * 256 + threadIdx.x;
    if (i >= total) return;
    const int C = 128, C8 = 16;
    int oct = (int)(i & (C8 - 1));
    long rest = i >> 4;
    int ox = (int)(rest % OW);
    long r = rest / OW;
    int oy = (int)(r % OH);
    int n  = (int)(r / OH);
    float sy = oy * ((h - 1.f) / (OH - 1.f));
    float sx = ox * ((w - 1.f) / (OW - 1.f));
    int y0 = (int)sy; int y1 = min(y0 + 1, h - 1); float wy = sy - y0;
    int x0 = (int)sx; int x1 = min(x0 + 1, w - 1); float wx = sx - x0;
    const bf16* sp = src + (size_t)n * sPIX * C + oct * 8;
    U16x8 q00, q01, q10, q11;
    q00.u = *(const uint4*)(sp + ((size_t)(y0 + 1) * sWq + (x0 + 1)) * C);
    q01.u = *(const uint4*)(sp + ((size_t)(y0 + 1) * sWq + (x1 + 1)) * C);
    q10.u = *(const uint4*)(sp + ((size_t)(y1 + 1) * sWq + (x0 + 1)) * C);
    q11.u = *(const uint4*)(sp + ((size_t)(y1 + 1) * sWq + (x1 + 1)) * C);
    bf16* dp = dst + ((size_t)n * dPIX + (size_t)(oy + 1) * dWq + (ox + 1)) * C + oct * 8;
    U16x8 d; d.u = *(const uint4*)dp;
    U16x8 o;
#pragma unroll
    for (int e = 0; e < 8; ++e) {
        float a00 = __uint_as_float((unsigned)q00.s[e] << 16);
        float a01 = __uint_as_float((unsigned)q01.s[e] << 16);
        float a10 = __uint_as_float((unsigned)q10.s[e] << 16);
        float a11 = __uint_as_float((unsigned)q11.s[e] << 16);
        float t0 = a00 * (1.f - wy) + a10 * wy;
        float t1 = a01 * (1.f - wy) + a11 * wy;
        float dv = __uint_as_float((unsigned)d.s[e] << 16);
        o.s[e] = f2b(dv + t0 * (1.f - wx) + t1 * wx);
    }
    *(uint4*)dp = o.u;
}

__global__ void resize_out_k(const float* __restrict__ src, void* __restrict__ dst,
                             size_t dst_off, const int* __restrict__ flags,
                             int h, int w, int OH, int OW, long total)
{
    const bool bf = flags[0] != 0;
    long i = (long)blockIdx.x * blockDim.x + threadIdx.x;
    if (i >= total) return;
    int ox = (int)(i % OW);
    long r = i / OW;
    int oy = (int)(r % OH);
    int nc = (int)(r / OH);
    float sy = oy * ((h - 1.f) / (OH - 1.f));
    float sx = ox * ((w - 1.f) / (OW - 1.f));
    int y0 = (int)sy; int y1 = min(y0 + 1, h - 1); float wy = sy - y0;
    int x0 = (int)sx; int x1 = min(x0 + 1, w - 1); float wx = sx - x0;
    const float* sp = src + (size_t)nc * h * w;
    float t0 = sp[y0 * w + x0] * (1.f - wy) + sp[y1 * w + x0] * wy;
    float t1 = sp[y0 * w + x1] * (1.f - wy) + sp[y1 * w + x1] * wy;
    stg_any(dst, dst_off + (size_t)i, t0 * (1.f - wx) + t1 * wx, bf);
}

__global__ void cast_out_k(const bf16* __restrict__ src, void* __restrict__ dst,
                           size_t dst_off, const int* __restrict__ flags, long n)
{
    const bool bf = flags[0] != 0;
    long i = (long)blockIdx.x * blockDim.x + threadIdx.x;
    if (i < n) stg_any(dst, dst_off + (size_t)i, cvt(src[i]), bf);
}

// 1x1 conv: NHWC padded (C=128) -> flat NCHW bf16 (8 ch)
__global__ __launch_bounds__(256) void conv1x1_nhwc(const bf16* __restrict__ in,
                                                    const void* __restrict__ w,
                                                    const int* __restrict__ flags,
                                                    bf16* __restrict__ out,
                                                    int H, int W, int Wq, int PIX)
{
    const bool fw = flags[0] != 0;
    __shared__ float sw[8 * 128];
    for (int i = threadIdx.x; i < 1024; i += 256) sw[i] = ldg_any(w, i, fw);
    __syncthreads();
    const int HW = H * W;
    int idx = blockIdx.x * 256 + threadIdx.x;
    if (idx >= 2 * HW) return;
    int pix = idx % HW, n = idx / HW;
    int y = pix / W, x = pix - y * W;
    const bf16* ip = in + ((size_t)n * PIX + (size_t)(y + 1) * Wq + (x + 1)) * 128;
    float a[8];
#pragma unroll
    for (int o = 0; o < 8; ++o) a[o] = 0.f;
    for (int oc = 0; oc < 16; ++oc) {
        U16x8 q; q.u = *(const uint4*)(ip + oc * 8);
#pragma unroll
        for (int e = 0; e < 8; ++e) {
            float f = __uint_as_float((unsigned)q.s[e] << 16);
#pragma unroll
            for (int o = 0; o < 8; ++o) a[o] = fmaf(sw[o * 128 + oc * 8 + e], f, a[o]);
        }
    }
#pragma unroll
    for (int o = 0; o < 8; ++o)
        out[((size_t)n * 8 + o) * HW + pix] = __float2bfloat16(a[o]);
}

// GroupNorm stats/apply on FLAT planar bf16 (mfeat)
__global__ __launch_bounds__(256) void gn_stats_v(const bf16* __restrict__ x,
                                                  float* __restrict__ stats, int per_group)
{
    const int g = blockIdx.x;
    const uint4* xp = (const uint4*)(x + (size_t)g * per_group);
    const int nvec = per_group >> 3;
    float s = 0.f, ss = 0.f;
    const int stride = 256 * gridDim.y;
    for (int i = blockIdx.y * 256 + threadIdx.x; i < nvec; i += stride) {
        uint4 u = xp[i];
        float f0,f1,f2,f3,f4,f5,f6,f7;
        b2f2(u.x, f0, f1); b2f2(u.y, f2, f3); b2f2(u.z, f4, f5); b2f2(u.w, f6, f7);
        s += ((f0+f1)+(f2+f3)) + ((f4+f5)+(f6+f7));
        ss = fmaf(f0,f0,ss); ss = fmaf(f1,f1,ss); ss = fmaf(f2,f2,ss); ss = fmaf(f3,f3,ss);
        ss = fmaf(f4,f4,ss); ss = fmaf(f5,f5,ss); ss = fmaf(f6,f6,ss); ss = fmaf(f7,f7,ss);
    }
#pragma unroll
    for (int off = 32; off > 0; off >>= 1) {
        s  += __shfl_down(s,  off, 64);
        ss += __shfl_down(ss, off, 64);
    }
    __shared__ float sh[8];
    const int wv = threadIdx.x >> 6;
    if ((threadIdx.x & 63) == 0) { sh[wv * 2] = s; sh[wv * 2 + 1] = ss; }
    __syncthreads();
    if (threadIdx.x == 0) {
        s  = sh[0] + sh[2] + sh[4] + sh[6];
        ss = sh[1] + sh[3] + sh[5] + sh[7];
        atomicAdd(&stats[2 * g],     s);
        atomicAdd(&stats[2 * g + 1], ss);
    }
}

__global__ void gn_apply_v(bf16* __restrict__ x, const float* __restrict__ stats,
                           const void* __restrict__ gamma, const void* __restrict__ beta,
                           size_t gb_off, const int* __restrict__ flags,
                           int HW, int C, int per_group, float inv_len, long nvec)
{
    const bool fw = flags[0] != 0;
    long v = (long)blockIdx.x * blockDim.x + threadIdx.x;
    if (v >= nvec) return;
    long i0 = v * 8;
    int gl = (int)(i0 / per_group);
    float mu  = stats[2 * gl] * inv_len;
    float var = fmaxf(stats[2 * gl + 1] * inv_len - mu * mu, 0.f);
    float iv  = rsqrtf(var + 1e-5f);
    int cc = (int)((i0 / HW) % C);
    float ga = ldg_any(gamma, gb_off + cc, fw);
    float be = ldg_any(beta,  gb_off + cc, fw);
    float sc = iv * ga, sf = be - mu * iv * ga;
    uint4 u = *(const uint4*)(x + i0);
    float f[8];
    b2f2(u.x, f[0], f[1]); b2f2(u.y, f[2], f[3]);
    b2f2(u.z, f[4], f[5]); b2f2(u.w, f[6], f[7]);
#pragma unroll
    for (int j = 0; j < 8; ++j) f[j] = fmaxf(fmaf(f[j], sc, sf), 0.f);
    uint4 o;
    o.x = f2b(f[0]) | ((unsigned)f2b(f[1]) << 16);
    o.y = f2b(f[2]) | ((unsigned)f2b(f[3]) << 16);
    o.z = f2b(f[4]) | ((unsigned)f2b(f[5]) << 16);
    o.w = f2b(f[6]) | ((unsigned)f2b(f[7]) << 16);
    *(uint4*)(x + i0) = o;
}

__global__ __launch_bounds__(256) void dyn_conv_k(const bf16* __restrict__ mf,
                                                  const float* __restrict__ prm,
                                                  float* __restrict__ out, int H, int W)
{
    const int inst = blockIdx.y;
    __shared__ float p[169];
    if (threadIdx.x < 169) p[threadIdx.x] = prm[inst * 169 + threadIdx.x];
    __syncthreads();
    const int HW = H * W;
    const int pix = blockIdx.x * 256 + threadIdx.x;
    if (pix >= HW) return;
    const int b = inst / 100;
    float xin[10];
#pragma unroll
    for (int c = 0; c < 8; ++c) xin[c] = cvt(mf[((size_t)(b * 8 + c)) * HW + pix]);
    int yy = pix / W, xx = pix - yy * W;
    xin[8] = -1.f + 2.f * xx / (W - 1);
    xin[9] = -1.f + 2.f * yy / (H - 1);
    float h1[8];
#pragma unroll
    for (int o = 0; o < 8; ++o) {
        float s = p[152 + o];
#pragma unroll
        for (int c = 0; c < 10; ++c) s = fmaf(p[o * 10 + c], xin[c], s);
        h1[o] = fmaxf(s, 0.f);
    }
    float h2[8];
#pragma unroll
    for (int o = 0; o < 8; ++o) {
        float s = p[160 + o];
#pragma unroll
        for (int c = 0; c < 8; ++c) s = fmaf(p[80 + o * 8 + c], h1[c], s);
        h2[o] = fmaxf(s, 0.f);
    }
    float s = p[168];
#pragma unroll
    for (int c = 0; c < 8; ++c) s = fmaf(p[144 + c], h2[c], s);
    out[(size_t)inst * HW + pix] = s;
}

// ---------------------------------------------------------------------------
// host helpers
// ---------------------------------------------------------------------------
struct Norm { const float* st; const void* g; const void* b; size_t off; int cpg; int Gn; float inv; };
struct Geo  { int H, W, Wq, Hp, PIX; };

static inline Geo mkgeo(int H, int W) {
    int xb = (W + 31) / 32, yb = (H + 3) / 4;
    Geo g; g.H = H; g.W = W; g.Wq = (xb - 1) * 32 + 34; g.Hp = (yb - 1) * 4 + 6;
    g.PIX = g.Hp * g.Wq;
    return g;
}

static inline void mconv(const bf16* in, const bf16* wrep, const Norm* nm,
                         const void* bias, const void* scale, int sidx,
                         void* out, int outm, size_t out_off, int out_C,
                         const int* flags, int N, int Cin, Geo g, int Cout, hipStream_t s)
{
    int cob = (Cout + 127) / 128, Cpad = cob * 128;
    dim3 gr((g.W + 31) / 32, (g.H + 3) / 4, N * cob);
    conv3x3_mfma_k<<<gr, 256, 0, s>>>(
        in, wrep,
        nm ? nm->st : nullptr, nm ? nm->g : nullptr, nm ? nm->b : nullptr,
        nm ? nm->off : 0, nm ? nm->cpg : 1, nm ? nm->Gn : 1, nm ? nm->inv : 1.f,
        bias, scale, sidx, out, outm, out_off, out_C,
        flags, Cin, g.H, g.W, g.Wq, g.PIX, Cout, Cpad, cob);
}

static inline void run_padT(const void* src, const int* flags, bf16* dst,
                            int N, int C, Geo g, hipStream_t s)
{
    long total = (long)N * g.PIX * (C >> 3);
    padT_k<<<(int)((total + 255) / 256), 256, 0, s>>>(src, flags, dst, C, g.H, g.W,
                                                      g.Wq, g.Hp, g.PIX, total);
}

static inline void run_stats_nhwc(const bf16* x, float* st, int N, int C, int cpg, int Gn,
                                  Geo g, hipStream_t s)
{
    int C8 = C >> 3;
    long nvec = (long)g.PIX * C8;
    int chunks = (int)((nvec + 16383) / 16384);
    if (chunks > 32) chunks = 32; if (chunks < 1) chunks = 1;
    gn_stats_nhwc<<<dim3(chunks, 1, N), 256, 0, s>>>(x, st, C8, cpg >> 3, Gn,
                                                     nvec, g.PIX * C);
}

static inline void run_apply_nhwc(bf16* x, const float* st, const void* gm, const void* bt,
                                  size_t off, const int* flags, int N, int C, int cpg, int Gn,
                                  Geo g, hipStream_t s)
{
    long total = (long)N * g.H * g.W * (C >> 3);
    gn_apply_nhwc<<<(int)((total + 255) / 256), 256, 0, s>>>(
        x, st, gm, bt, off, flags, C, cpg, Gn, g.H, g.W, g.Wq, g.PIX,
        1.f / ((float)cpg * g.H * g.W), total);
}

extern "C" void kernel_launch(void* const* d_in, const int* in_sizes, int n_in,
                              void* d_out, int out_size, void* d_ws, size_t ws_size,
                              hipStream_t stream)
{
    const void* f[5] = {d_in[0], d_in[1], d_in[2], d_in[3], d_in[4]};
    static const int Hs[5] = {96, 48, 24, 12, 6};
    static const int Wd[5] = {160, 80, 40, 20, 10};
    const void* head_w     = d_in[5];
    const void* head_gn_g  = d_in[6];
    const void* head_gn_b  = d_in[7];
    const void* head_out_w = d_in[8];
    const void* head_out_b = d_in[9];
    const void* scales     = d_in[10];
    const void* ref_w      = d_in[11];
    const void* ref_gn_g   = d_in[12];
    const void* ref_gn_b   = d_in[13];
    const void* tow_w      = d_in[14];
    const void* tow_gn_g   = d_in[15];
    const void* tow_gn_b   = d_in[16];
    const void* out_w      = d_in[17];
    const void* out_gn_g   = d_in[18];
    const void* out_gn_b   = d_in[19];

    Geo G[5];
    for (int l = 0; l < 5; ++l) G[l] = mkgeo(Hs[l], Wd[l]);

    size_t po[5]; size_t off = 0;
    for (int l = 0; l < 5; ++l) { po[l] = off; off += (size_t)2 * 254 * Hs[l] * Wd[l]; }
    size_t mf_off = off; off += 245760;
    size_t ml_off = off;

    // ---- workspace (~42 MB) ----
    const size_t ACAP = (size_t)2 * 256 * G[0].PIX;       // 8,128,512 elems
    bf16*  A     = (bf16*)d_ws;
    bf16*  B     = A + ACAP;
    bf16*  B2    = B + ACAP;                              // 2*128*4900 = 1,254,400
    bf16*  mfeat = B2 + 1254400;
    float* prm   = (float*)(mfeat + 245760);              // 33,800 f32
    float* stats = prm + 33800;                           // 4,096 f32
    int*   flags = (int*)(stats + 4096);                  // 16 int
    bf16*  wrep  = (bf16*)(flags + 16);                   // 2,949,120 bf16
    float* dyn   = (float*)A;                             // aliases A after last read

    bf16* wrepH  = wrep;                        // 4 x 589824 (head layers)
    bf16* wrepHO = wrep + 4 * 589824;           // 589824 (head_out, Cpad 256)
    bf16* wrepR  = wrep;                        // mask phase reuses region
    bf16* wrepT  = wrep + 3 * 294912;

    hipMemsetAsync(stats, 0, 4096 * sizeof(float), stream);
    detect_k<<<1, 64, 0, stream>>>((const unsigned int*)d_in[0], flags);

    float* sp = stats;

    // repack head weights
    for (int l = 0; l < 4; ++l) {
        int total = 9 * 256 * 256;
        repack_off_k<<<(total + 255) / 256, 256, 0, stream>>>(
            head_w, (size_t)l * 589824, flags, wrepH + (size_t)l * 589824, 256, 256, 256, total);
    }
    {
        int total = 9 * 256 * 256;
        repack_off_k<<<(total + 255) / 256, 256, 0, stream>>>(
            head_out_w, 0, flags, wrepHO, 254, 256, 256, total);
    }

    // ---------------- head branches ----------------
    for (int lvl = 0; lvl < 5; ++lvl) {
        Geo g = G[lvl];
        int HW = g.H * g.W;
        float inv_pg = 1.f / (8 * HW);
        run_padT(f[lvl], flags, B, 2, 256, g, stream);
        hipMemsetAsync(A, 0, (size_t)2 * 256 * g.PIX * sizeof(bf16), stream);
        mconv(B, wrepH, nullptr, nullptr, nullptr, 0, A, 0, 0, 256,
              flags, 2, 256, g, 256, stream);
        float* s_prev = sp; sp += 128;
        run_stats_nhwc(A, s_prev, 2, 256, 8, 32, g, stream);
        bf16* a = A; bf16* bb = B;
        for (int l = 1; l < 4; ++l) {
            Norm nm{s_prev, head_gn_g, head_gn_b, (size_t)(l - 1) * 256, 8, 32, inv_pg};
            mconv(a, wrepH + (size_t)l * 589824, &nm, nullptr, nullptr, 0,
                  bb, 0, 0, 256, flags, 2, 256, g, 256, stream);
            s_prev = sp; sp += 128;
            run_stats_nhwc(bb, s_prev, 2, 256, 8, 32, g, stream);
            bf16* tmp = a; a = bb; bb = tmp;
        }
        Norm nm{s_prev, head_gn_g, head_gn_b, (size_t)3 * 256, 8, 32, inv_pg};
        mconv(a, wrepHO, &nm, head_out_b, scales, lvl, d_out, 2, po[lvl], 0,
              flags, 2, 256, g, 254, stream);
        if (lvl == 0)
            extract_params_k<<<(200 * 169 + 255) / 256, 256, 0, stream>>>(d_out, flags, prm, HW);
    }

    // repack mask weights (enqueued after all head convs; stream order protects)
    for (int i = 0; i < 3; ++i) {
        int total = 9 * 128 * 256;
        repack_off_k<<<(total + 255) / 256, 256, 0, stream>>>(
            ref_w, (size_t)i * 294912, flags, wrepR + (size_t)i * 294912, 128, 128, 256, total);
    }
    for (int l = 0; l < 4; ++l) {
        int total = 9 * 128 * 128;
        repack_off_k<<<(total + 255) / 256, 256, 0, stream>>>(
            tow_w, (size_t)l * 147456, flags, wrepT + (size_t)l * 147456, 128, 128, 128, total);
    }

    // ---------------- mask branch ----------------
    {
        Geo g0 = G[0];
        const int HW = 96 * 160;

        // refine 0
        run_padT(f[0], flags, B, 2, 256, g0, stream);
        hipMemsetAsync(A, 0, (size_t)2 * 128 * g0.PIX * sizeof(bf16), stream);
        mconv(B, wrepR, nullptr, nullptr, nullptr, 0, A, 0, 0, 128,
              flags, 2, 256, g0, 128, stream);
        float* s0 = sp; sp += 4;
        run_stats_nhwc(A, s0, 2, 128, 128, 1, g0, stream);
        run_apply_nhwc(A, s0, ref_gn_g, ref_gn_b, 0, flags, 2, 128, 128, 1, g0, stream);

        // refines 1,2 + upsample-add into A
        for (int i = 1; i < 3; ++i) {
            Geo gi = G[i];
            run_padT(f[i], flags, B, 2, 256, gi, stream);
            hipMemsetAsync(B2, 0, (size_t)2 * 128 * gi.PIX * sizeof(bf16), stream);
            mconv(B, wrepR + (size_t)i * 294912, nullptr, nullptr, nullptr, 0,
                  B2, 0, 0, 128, flags, 2, 256, gi, 128, stream);
            float* si = sp; sp += 4;
            run_stats_nhwc(B2, si, 2, 128, 128, 1, gi, stream);
            run_apply_nhwc(B2, si, ref_gn_g, ref_gn_b, (size_t)i * 128, flags,
                           2, 128, 128, 1, gi, stream);
            long tot = (long)2 * 96 * 160 * 16;
            upsample_add_nhwc<<<(int)((tot + 255) / 256), 256, 0, stream>>>(
                B2, A, gi.H, gi.W, gi.Wq, gi.PIX, 96, 160, g0.Wq, g0.PIX, tot);
        }

        // tower
        float inv_pg = 1.f / (128 * HW);
        hipMemsetAsync(B, 0, (size_t)2 * 128 * g0.PIX * sizeof(bf16), stream);
        mconv(A, wrepT, nullptr, nullptr, nullptr, 0, B, 0, 0, 128,
              flags, 2, 128, g0, 128, stream);
        float* sT = sp; sp += 4;
        run_stats_nhwc(B, sT, 2, 128, 128, 1, g0, stream);
        bf16* a = B; bf16* bb = A;
        for (int l = 1; l < 4; ++l) {
            Norm nm{sT, tow_gn_g, tow_gn_b, (size_t)(l - 1) * 128, 128, 1, inv_pg};
            mconv(a, wrepT + (size_t)l * 147456, &nm, nullptr, nullptr, 0,
                  bb, 0, 0, 128, flags, 2, 128, g0, 128, stream);
            sT = sp; sp += 4;
            run_stats_nhwc(bb, sT, 2, 128, 128, 1, g0, stream);
            bf16* tmp = a; a = bb; bb = tmp;
        }
        // final tower raw in a (= A), stats sT
        run_apply_nhwc(a, sT, tow_gn_g, tow_gn_b, (size_t)3 * 128, flags, 2, 128, 128, 1, g0, stream);
        conv1x1_nhwc<<<(2 * HW + 255) / 256, 256, 0, stream>>>(
            a, out_w, flags, mfeat, 96, 160, g0.Wq, g0.PIX);
        float* sM = sp; sp += 4;
        {
            int chunks = (8 * HW) / 8192; if (chunks < 1) chunks = 1;
            gn_stats_v<<<dim3(2, chunks), 256, 0, stream>>>(mfeat, sM, 8 * HW);
            long nvec = ((long)2 * 8 * HW) >> 3;
            gn_apply_v<<<(int)((nvec + 255) / 256), 256, 0, stream>>>(
                mfeat, sM, out_gn_g, out_gn_b, 0, flags, HW, 8, 8 * HW, 1.f / (8 * HW), nvec);
        }
        cast_out_k<<<(2 * 8 * HW + 255) / 256, 256, 0, stream>>>(
            mfeat, d_out, mf_off, flags, (long)2 * 8 * HW);
        dyn_conv_k<<<dim3((HW + 255) / 256, 200), 256, 0, stream>>>(mfeat, prm, dyn, 96, 160);
        long nt = (long)200 * 192 * 320;
        resize_out_k<<<(int)((nt + 255) / 256), 256, 0, stream>>>(
            dyn, d_out, ml_off, flags, 96, 160, 192, 320, nt);
    }
}

// Round 8
// 2435.018 us; speedup vs baseline: 2.8534x; 1.1384x over previous
//
#include <hip/hip_runtime.h>
#include <hip/hip_bf16.h>

typedef __hip_bfloat16 bf16;
typedef short v8s __attribute__((ext_vector_type(8)));
typedef float v4f __attribute__((ext_vector_type(4)));

__device__ __forceinline__ float cvt(bf16 v) { return __bfloat162float(v); }

__device__ __forceinline__ float ldg_any(const void* p, size_t i, bool bf) {
    return bf ? cvt(((const bf16*)p)[i]) : ((const float*)p)[i];
}
__device__ __forceinline__ void stg_any(void* p, size_t i, float v, bool bf) {
    if (bf) ((bf16*)p)[i] = __float2bfloat16(v);
    else    ((float*)p)[i] = v;
}
__device__ __forceinline__ bool bfmode(int mode, const int* flags) {
    return mode == 2 ? (flags[0] != 0) : (mode != 0);
}
__device__ __forceinline__ unsigned short f2b(float f) {
    bf16 h = __float2bfloat16(f); return *(unsigned short*)&h;
}
__device__ __forceinline__ void b2f2(unsigned u, float& a, float& b) {
    a = __uint_as_float(u << 16);
    b = __uint_as_float(u & 0xffff0000u);
}

union U16x8 { uint4 u; unsigned short s[8]; };

// lgkm-only barrier: publishes LDS without draining the global-load queue
// (__syncthreads emits s_waitcnt vmcnt(0) which kills cross-phase prefetch).
// Safe here: all LDS traffic is explicit ds_write/ds_read (no global_load_lds),
// and register uses of prefetched global loads get compiler-counted vmcnt.
#define BARLDS() asm volatile("s_waitcnt lgkmcnt(0)\n\ts_barrier" ::: "memory")

// ---------------------------------------------------------------------------
// dtype probe on f3 (N(0,1) data): fp32 never has exponent >= 200.
// ---------------------------------------------------------------------------
__global__ void detect_k(const unsigned int* __restrict__ x, int* __restrict__ flags)
{
    unsigned int u = x[threadIdx.x];
    int e = (u >> 23) & 0xFF;
    unsigned long long m = __ballot(e >= 200);
    if (threadIdx.x == 0) flags[0] = (m != 0ULL) ? 1 : 0;
}

// ---------------------------------------------------------------------------
// weight repack: OIHW (+element offset) -> [tap][co(pad)][ci] bf16
// ---------------------------------------------------------------------------
__global__ void repack_off_k(const void* __restrict__ w, size_t w_off,
                             const int* __restrict__ flags, bf16* __restrict__ dst,
                             int Cout, int Cpad, int Cin, int total)
{
    const bool fw = flags[0] != 0;
    int i = blockIdx.x * 256 + threadIdx.x;
    if (i >= total) return;
    int ci = i % Cin; int r = i / Cin; int co = r % Cpad; int tap = r / Cpad;
    float v = 0.f;
    if (co < Cout) v = ldg_any(w, w_off + ((size_t)co * Cin + ci) * 9 + tap, fw);
    dst[i] = __float2bfloat16(v);
}

// ---------------------------------------------------------------------------
// pad + transpose: NCHW (fp32/bf16) -> NHWC padded bf16 [n][Hp][Wq][C].
// ---------------------------------------------------------------------------
__global__ void padT_k(const void* __restrict__ src, const int* __restrict__ flags,
                       bf16* __restrict__ dst, int C, int H, int W, int Wq, int Hp,
                       int PIX, long total)
{
    const bool fb = flags[0] != 0;
    long v = (long)blockIdx.x * 256 + threadIdx.x;
    if (v >= total) return;
    const int C8 = C >> 3;
    int oct = (int)(v & (C8 - 1));
    long rest = v >> (C == 256 ? 5 : 4);
    int px = (int)(rest % Wq);
    long r2 = rest / Wq;
    int py = (int)(r2 % Hp);
    int n  = (int)(r2 / Hp);
    U16x8 o;
    if (py == 0 || py > H || px == 0 || px > W) {
        o.u = uint4{0, 0, 0, 0};
    } else {
        const int HW = H * W;
        size_t sb = ((size_t)n * C + oct * 8) * HW + (size_t)(py - 1) * W + (px - 1);
#pragma unroll
        for (int e = 0; e < 8; ++e) o.s[e] = f2b(ldg_any(src, sb + (size_t)e * HW, fb));
    }
    *(uint4*)(dst + v * 8) = o.u;
}

// ---------------------------------------------------------------------------
// MFMA implicit-GEMM 3x3 SAME conv, NHWC padded input, LDS-staged WEIGHTS.
// Block: 128 co x (4 rows x 32 cols); 4 waves tiled 2(co-slice) x 2(row-pair).
// Per phase (kernel row): cooperative 24KB weight stage (dbuf) + MFMA on
// previous slab. lgkm-only barriers keep prefetch loads in flight across
// phases. Weight LDS XOR-swizzled (conflict-free af reads). NHWC epilogue
// goes through an LDS transpose -> 16B/lane coalesced global writes.
// ---------------------------------------------------------------------------
__global__ __launch_bounds__(256, 2) void conv3x3_mfma_k(
    const bf16* __restrict__ in,      // NHWC padded
    const bf16* __restrict__ wrep,    // [tap][co pad][ci]
    const float* __restrict__ gstat, const void* __restrict__ gamma,
    const void* __restrict__ beta, size_t gb_off, int cpg, int Gn, float inv_pg,
    const void* __restrict__ bias, const void* __restrict__ scale, int sidx,
    void* __restrict__ out, int outm, size_t out_off, int out_C,
    const int* __restrict__ flags,
    int Cin, int H, int W, int Wq, int PIX, int Cout, int Cpad, int co_blocks)
{
    const bool fw   = flags[0] != 0;
    const bool fout = bfmode(outm, flags);

    const int t    = threadIdx.x;
    const int lane = t & 63;
    const int wv   = t >> 6;
    const int c    = lane & 15;
    const int quad = lane >> 4;
    const int wr   = wv >> 1;     // wave row-pair (0,1)
    const int wc   = wv & 1;      // wave co-slice (0,1)
    const int x0   = blockIdx.x * 32;
    const int y0   = blockIdx.y * 4;
    const int n    = blockIdx.z / co_blocks;
    const int cb   = blockIdx.z % co_blocks;

    // LDS arena: img 2x13056 | w 2x24576 | scale 1024 | shift 1024 = 77312 B
    __shared__ __align__(16) char s_arena[77312];
    float* s_scale = (float*)(s_arena + 75264);
    float* s_shift = (float*)(s_arena + 76288);

    const bool donorm = (gstat != nullptr);

    v4f acc[4][4];
#pragma unroll
    for (int i = 0; i < 4; ++i)
#pragma unroll
        for (int j = 0; j < 4; ++j) acc[i][j] = v4f{0.f, 0.f, 0.f, 0.f};

    const bf16* inb = in + (size_t)n * PIX * Cin;

    // static image staging map: flat = t + 256*it over 816 = 204 pos x 4 octets
    int goff[4], loff[4], okm[4], octv[4];
#pragma unroll
    for (int it = 0; it < 4; ++it) {
        int flat = t + 256 * it;
        int pos = flat >> 2, oct = flat & 3;
        int r = (pos * 241) >> 13;          // pos / 34 (exact for pos < 204)
        int cc = pos - r * 34;
        int py = y0 + r, px = x0 + cc;
        bool valid = flat < 816;
        goff[it] = (py * Wq + px) * Cin + oct * 8;
        loff[it] = valid ? (pos * 64 + (((oct + (pos >> 1)) & 3) << 4)) : -1;
        okm[it]  = (py >= 1 && py <= H && px >= 1 && px <= W) ? 1 : 0;
        octv[it] = oct * 8;
    }

    uint4 L[4];
    uint4 wrg[6];

#define STAGE_LOAD(ci0_) { \
    _Pragma("unroll") for (int it = 0; it < 4; ++it) \
        if (loff[it] >= 0) L[it] = *(const uint4*)(inb + goff[it] + (ci0_)); }

#define STAGE_WRITE(ci0_, b_) { \
    char* db = s_arena + (b_) * 13056; \
    _Pragma("unroll") for (int it = 0; it < 4; ++it) { \
        if (loff[it] < 0) continue; \
        uint4 q = L[it]; \
        if (donorm) { \
            U16x8 u_; u_.u = q; U16x8 o_; \
            if (okm[it]) { \
                int cib = (ci0_) + octv[it]; \
                _Pragma("unroll") for (int e = 0; e < 8; ++e) { \
                    float v_ = __uint_as_float((unsigned)u_.s[e] << 16); \
                    v_ = fmaxf(fmaf(v_, s_scale[cib + e], s_shift[cib + e]), 0.f); \
                    o_.s[e] = f2b(v_); } \
            } else { o_.u = uint4{0, 0, 0, 0}; } \
            q = o_.u; } \
        *(uint4*)(db + loff[it]) = q; } }

// cooperative coalesced weight stage: phase (ky=g_) of chunk ci0_, 24KB
#define WLOAD(ci0_, g_) { \
    _Pragma("unroll") for (int j = 0; j < 6; ++j) { \
        int f_ = t + 256 * j; int tapl_ = f_ >> 9; int rem_ = f_ & 511; \
        wrg[j] = *(const uint4*)(wrep + ((size_t)(3 * (g_) + tapl_) * Cpad \
                 + cb * 128 + (rem_ >> 2)) * (size_t)Cin + (ci0_) + (rem_ & 3) * 8); } }

// XOR-swizzled store: oct' = (oct + co + (co>>2)) & 3  (spreads af-read banks)
#define WSTORE(b_) { \
    bf16* sw = (bf16*)(s_arena + 26112 + (b_) * 24576); \
    _Pragma("unroll") for (int j = 0; j < 6; ++j) { \
        int f_ = t + 256 * j; int tapl_ = f_ >> 9; int rem_ = f_ & 511; \
        int co_ = rem_ >> 2; int oc_ = (rem_ + co_ + (co_ >> 2)) & 3; \
        *(uint4*)(&sw[tapl_ * 4096 + co_ * 32 + oc_ * 8]) = wrg[j]; } }

// MFMA phase: kernel row g_, 3 kx taps, 48 MFMAs/wave
#define MPHASE(ib_, wb_, g_) { \
    const char* sb_ = s_arena + (ib_) * 13056; \
    const bf16* wp_ = (const bf16*)(s_arena + 26112 + (wb_) * 24576); \
    _Pragma("unroll") for (int kx = 0; kx < 3; ++kx) { \
        v8s bfr[4]; \
        _Pragma("unroll") for (int nf = 0; nf < 4; ++nf) { \
            int pos = (2 * wr + (nf >> 1) + (g_)) * 34 + kx + c + (nf & 1) * 16; \
            bfr[nf] = *(const v8s*)(sb_ + pos * 64 + (((quad + (pos >> 1)) & 3) << 4)); } \
        _Pragma("unroll") for (int mf = 0; mf < 4; ++mf) { \
            int col_ = wc * 64 + mf * 16 + c; \
            int os_ = (quad + col_ + (col_ >> 2)) & 3; \
            v8s af = *(const v8s*)(wp_ + kx * 4096 + col_ * 32 + os_ * 8); \
            _Pragma("unroll") for (int nf = 0; nf < 4; ++nf) \
                acc[mf][nf] = __builtin_amdgcn_mfma_f32_16x16x32_bf16( \
                    af, bfr[nf], acc[mf][nf], 0, 0, 0); } } }

    // prologue: stage img chunk 0 and weight phase (0, ky=0)
    STAGE_LOAD(0);
    WLOAD(0, 0);
    if (donorm) {
        for (int ch = t; ch < Cin; ch += 256) {
            int gl = n * Gn + ch / cpg;
            float mu  = gstat[2 * gl] * inv_pg;
            float var = fmaxf(gstat[2 * gl + 1] * inv_pg - mu * mu, 0.f);
            float iv  = rsqrtf(var + 1e-5f);
            float ga  = ldg_any(gamma, gb_off + ch, fw);
            float be  = ldg_any(beta,  gb_off + ch, fw);
            s_scale[ch] = iv * ga;
            s_shift[ch] = be - mu * iv * ga;
        }
    }
    BARLDS();
    STAGE_WRITE(0, 0);
    WSTORE(0);
    BARLDS();

    // main loop: two 32-ci chunks per iteration (6 phases), static buffers.
    for (int ci0 = 0; ci0 < Cin; ci0 += 64) {
        const bool moreB = (ci0 + 64 < Cin);
        // P0: chunk A, ky=0, img0, w0
        STAGE_LOAD(ci0 + 32);
        WLOAD(ci0, 1);
        MPHASE(0, 0, 0);
        WSTORE(1);
        BARLDS();
        // P1: A, ky=1, w1
        WLOAD(ci0, 2);
        MPHASE(0, 1, 1);
        WSTORE(0);
        BARLDS();
        // P2: A, ky=2, w0; write img chunk B
        WLOAD(ci0 + 32, 0);
        MPHASE(0, 0, 2);
        STAGE_WRITE(ci0 + 32, 1);
        WSTORE(1);
        BARLDS();
        // P3: chunk B, ky=0, img1, w1
        if (moreB) STAGE_LOAD(ci0 + 64);
        WLOAD(ci0 + 32, 1);
        MPHASE(1, 1, 0);
        WSTORE(0);
        BARLDS();
        // P4: B, ky=1, w0
        WLOAD(ci0 + 32, 2);
        MPHASE(1, 0, 1);
        WSTORE(1);
        BARLDS();
        // P5: B, ky=2, w1; prefetch next iteration
        if (moreB) { WLOAD(ci0 + 64, 0); }
        MPHASE(1, 1, 2);
        if (moreB) { STAGE_WRITE(ci0 + 64, 0); WSTORE(0); }
        BARLDS();
    }
#undef MPHASE
#undef WSTORE
#undef WLOAD
#undef STAGE_WRITE
#undef STAGE_LOAD

    if (outm == 0) {
        // ---- coalesced NHWC epilogue via LDS transpose (32KB of arena) ----
        // acc -> [pix 128][co 128] bf16; 16B-slot XOR swizzle by (pix&7).
        // octet of co = (wc*64 + mf*16 + quad*4) >> 3 = wc*8 + mf*2 + (quad>>1)
        char* tb = s_arena;
#pragma unroll
        for (int mf = 0; mf < 4; ++mf) {
            int s0 = wc * 8 + mf * 2 + (quad >> 1);
#pragma unroll
            for (int nf = 0; nf < 4; ++nf) {
                int lp = (2 * wr + (nf >> 1)) * 32 + (nf & 1) * 16 + c;
                uint2 o;
                o.x = f2b(acc[mf][nf][0]) | ((unsigned)f2b(acc[mf][nf][1]) << 16);
                o.y = f2b(acc[mf][nf][2]) | ((unsigned)f2b(acc[mf][nf][3]) << 16);
                *(uint2*)(tb + lp * 256 + ((s0 ^ (lp & 7)) << 4) + (quad & 1) * 8) = o;
            }
        }
        BARLDS();
        bf16* ob = (bf16*)out + (size_t)n * PIX * out_C + cb * 128;
        const int o8 = t & 15;          // co octet
#pragma unroll
        for (int pass = 0; pass < 8; ++pass) {
            int lp = pass * 16 + (t >> 4);
            uint4 q = *(const uint4*)(tb + lp * 256 + ((o8 ^ (lp & 7)) << 4));
            int y = y0 + (lp >> 5);
            int x = x0 + (lp & 31);
            if (y < H && x < W)
                *(uint4*)(ob + ((size_t)(y + 1) * Wq + (x + 1)) * out_C + o8 * 8) = q;
        }
    } else {
        // planar output (f32/bf16)
        const float al = scale ? ldg_any(scale, sidx, fw) : 1.f;
        const int HW = H * W;
        const int ybase = y0 + 2 * wr;
#pragma unroll
        for (int mf = 0; mf < 4; ++mf) {
            int cobase = cb * 128 + wc * 64 + mf * 16 + quad * 4;
#pragma unroll
            for (int reg = 0; reg < 4; ++reg) {
                int co = cobase + reg;
                if (co >= Cout) continue;
                float bv = bias ? ldg_any(bias, co, fw) : 0.f;
                size_t obase = out_off + ((size_t)n * Cout + co) * HW;
#pragma unroll
                for (int nf = 0; nf < 4; ++nf) {
                    int y = ybase + (nf >> 1);
                    int x = x0 + (nf & 1) * 16 + c;
                    if (y < H && x < W)
                        stg_any(out, obase + (size_t)y * W + x,
                                fmaf(al, acc[mf][nf][reg], bv), fout);
                }
            }
        }
    }
}

// ---------------------------------------------------------------------------
// GroupNorm stats over NHWC padded buffer (borders zero -> harmless).
// ---------------------------------------------------------------------------
__global__ __launch_bounds__(256) void gn_stats_nhwc(const bf16* __restrict__ x,
                                                     float* __restrict__ stats,
                                                     int C8, int cpg8, int Gn,
                                                     long nvec, int planeC)
{
    const int n = blockIdx.z;
    const bf16* xp = x + (size_t)n * planeC;
    const int t = threadIdx.x;
    const int oct = t & (C8 - 1);
    float s = 0.f, ss = 0.f;
    const long stride = 256L * gridDim.x;
    for (long v = (long)blockIdx.x * 256 + t; v < nvec; v += stride) {
        uint4 u = *(const uint4*)(xp + v * 8);
        float f0,f1,f2,f3,f4,f5,f6,f7;
        b2f2(u.x, f0, f1); b2f2(u.y, f2, f3); b2f2(u.z, f4, f5); b2f2(u.w, f6, f7);
        s += ((f0+f1)+(f2+f3)) + ((f4+f5)+(f6+f7));
        ss = fmaf(f0,f0,ss); ss = fmaf(f1,f1,ss); ss = fmaf(f2,f2,ss); ss = fmaf(f3,f3,ss);
        ss = fmaf(f4,f4,ss); ss = fmaf(f5,f5,ss); ss = fmaf(f6,f6,ss); ss = fmaf(f7,f7,ss);
    }
    for (int off = C8; off < 64; off <<= 1) {
        s  += __shfl_xor(s,  off, 64);
        ss += __shfl_xor(ss, off, 64);
    }
    __shared__ float red[4][32][2];
    const int wvi = t >> 6;
    if ((t & 63) < C8) { red[wvi][oct][0] = s; red[wvi][oct][1] = ss; }
    __syncthreads();
    if (t < C8) {
        s  = red[0][t][0] + red[1][t][0] + red[2][t][0] + red[3][t][0];
        ss = red[0][t][1] + red[1][t][1] + red[2][t][1] + red[3][t][1];
        for (int off = cpg8 >> 1; off >= 1; off >>= 1) {
            s  += __shfl_down(s,  off, 64);
            ss += __shfl_down(ss, off, 64);
        }
        if ((t & (cpg8 - 1)) == 0) {
            int gl = n * Gn + t / cpg8;
            atomicAdd(&stats[2 * gl],     s);
            atomicAdd(&stats[2 * gl + 1], ss);
        }
    }
}

// GroupNorm apply + relu on NHWC padded interior (borders stay zero).
__global__ void gn_apply_nhwc(bf16* __restrict__ x, const float* __restrict__ stats,
                              const void* __restrict__ gamma, const void* __restrict__ beta,
                              size_t gb_off, const int* __restrict__ flags,
                              int C, int cpg, int Gn, int H, int W, int Wq, int PIX,
                              float inv_len, long total)
{
    const bool fw = flags[0] != 0;
    long v = (long)blockIdx.x * 256 + threadIdx.x;
    if (v >= total) return;
    const int C8 = C >> 3;
    int oct = (int)(v & (C8 - 1));
    long rest = v / C8;
    int x2 = (int)(rest % W);
    long r2 = rest / W;
    int y = (int)(r2 % H);
    int n = (int)(r2 / H);
    int ch0 = oct * 8;
    int gl = n * Gn + ch0 / cpg;
    float mu  = stats[2 * gl] * inv_len;
    float var = fmaxf(stats[2 * gl + 1] * inv_len - mu * mu, 0.f);
    float iv  = rsqrtf(var + 1e-5f);
    size_t base = ((size_t)n * PIX + (size_t)(y + 1) * Wq + (x2 + 1)) * C + ch0;
    U16x8 u; u.u = *(const uint4*)(x + base);
    U16x8 o;
#pragma unroll
    for (int e = 0; e < 8; ++e) {
        float ga = ldg_any(gamma, gb_off + ch0 + e, fw);
        float be = ldg_any(beta,  gb_off + ch0 + e, fw);
        float f = __uint_as_float((unsigned)u.s[e] << 16);
        f = fmaxf(fmaf(f, iv * ga, be - mu * iv * ga), 0.f);
        o.s[e] = f2b(f);
    }
    *(uint4*)(x + base) = o.u;
}

// ---------------------------------------------------------------------------
__global__ void extract_params_k(const void* __restrict__ pred3, const int* __restrict__ flags,
                                 float* __restrict__ prm, int HW)
{
    const bool bf = flags[0] != 0;
    int tid = blockIdx.x * blockDim.x + threadIdx.x;
    if (tid >= 200 * 169) return;
    int p = tid / 169, c = tid - p * 169;
    int b = p / 100, i = p - b * 100;
    prm[tid] = ldg_any(pred3, ((size_t)b * 254 + 85 + c) * HW + i, bf);
}

// bilinear upsample (align corners), NHWC padded src -> add into NHWC padded dst
__global__ void upsample_add_nhwc(const bf16* __restrict__ src, bf16* __restrict__ dst,
                                  int h, int w, int sWq, int sPIX,
                                  int OH, int OW, int dWq, int dPIX, long total)
{
    long i = (long)blockIdx.x * 256 + threadIdx.x;
    if (i >= total) return;
    const int C = 128, C8 = 16;
    int oct = (int)(i & (C8 - 1));
    long rest = i >> 4;
    int ox = (int)(rest % OW);
    long r = rest / OW;
    int oy = (int)(r % OH);
    int n  = (int)(r / OH);
    float sy = oy * ((h - 1.f) / (OH - 1.f));
    float sx = ox * ((w - 1.f) / (OW - 1.f));
    int y0 = (int)sy; int y1 = min(y0 + 1, h - 1); float wy = sy - y0;
    int x0 = (int)sx; int x1 = min(x0 + 1, w - 1); float wx = sx - x0;
    const bf16* sp = src + (size_t)n * sPIX * C + oct * 8;
    U16x8 q00, q01, q10, q11;
    q00.u = *(const uint4*)(sp + ((size_t)(y0 + 1) * sWq + (x0 + 1)) * C);
    q01.u = *(const uint4*)(sp + ((size_t)(y0 + 1) * sWq + (x1 + 1)) * C);
    q10.u = *(const uint4*)(sp + ((size_t)(y1 + 1) * sWq + (x0 + 1)) * C);
    q11.u = *(const uint4*)(sp + ((size_t)(y1 + 1) * sWq + (x1 + 1)) * C);
    bf16* dp = dst + ((size_t)n * dPIX + (size_t)(oy + 1) * dWq + (ox + 1)) * C + oct * 8;
    U16x8 d; d.u = *(const uint4*)dp;
    U16x8 o;
#pragma unroll
    for (int e = 0; e < 8; ++e) {
        float a00 = __uint_as_float((unsigned)q00.s[e] << 16);
        float a01 = __uint_as_float((unsigned)q01.s[e] << 16);
        float a10 = __uint_as_float((unsigned)q10.s[e] << 16);
        float a11 = __uint_as_float((unsigned)q11.s[e] << 16);
        float t0 = a00 * (1.f - wy) + a10 * wy;
        float t1 = a01 * (1.f - wy) + a11 * wy;
        float dv = __uint_as_float((unsigned)d.s[e] << 16);
        o.s[e] = f2b(dv + t0 * (1.f - wx) + t1 * wx);
    }
    *(uint4*)dp = o.u;
}

__global__ void resize_out_k(const float* __restrict__ src, void* __restrict__ dst,
                             size_t dst_off, const int* __restrict__ flags,
                             int h, int w, int OH, int OW, long total)
{
    const bool bf = flags[0] != 0;
    long i = (long)blockIdx.x * blockDim.x + threadIdx.x;
    if (i >= total) return;
    int ox = (int)(i % OW);
    long r = i / OW;
    int oy = (int)(r % OH);
    int nc = (int)(r / OH);
    float sy = oy * ((h - 1.f) / (OH - 1.f));
    float sx = ox * ((w - 1.f) / (OW - 1.f));
    int y0 = (int)sy; int y1 = min(y0 + 1, h - 1); float wy = sy - y0;
    int x0 = (int)sx; int x1 = min(x0 + 1, w - 1); float wx = sx - x0;
    const float* sp = src + (size_t)nc * h * w;
    float t0 = sp[y0 * w + x0] * (1.f - wy) + sp[y1 * w + x0] * wy;
    float t1 = sp[y0 * w + x1] * (1.f - wy) + sp[y1 * w + x1] * wy;
    stg_any(dst, dst_off + (size_t)i, t0 * (1.f - wx) + t1 * wx, bf);
}

__global__ void cast_out_k(const bf16* __restrict__ src, void* __restrict__ dst,
                           size_t dst_off, const int* __restrict__ flags, long n)
{
    const bool bf = flags[0] != 0;
    long i = (long)blockIdx.x * blockDim.x + threadIdx.x;
    if (i < n) stg_any(dst, dst_off + (size_t)i, cvt(src[i]), bf);
}

// 1x1 conv: NHWC padded (C=128) -> flat NCHW bf16 (8 ch)
__global__ __launch_bounds__(256) void conv1x1_nhwc(const bf16* __restrict__ in,
                                                    const void* __restrict__ w,
                                                    const int* __restrict__ flags,
                                                    bf16* __restrict__ out,
                                                    int H, int W, int Wq, int PIX)
{
    const bool fw = flags[0] != 0;
    __shared__ float sw[8 * 128];
    for (int i = threadIdx.x; i < 1024; i += 256) sw[i] = ldg_any(w, i, fw);
    __syncthreads();
    const int HW = H * W;
    int idx = blockIdx.x * 256 + threadIdx.x;
    if (idx >= 2 * HW) return;
    int pix = idx % HW, n = idx / HW;
    int y = pix / W, x = pix - y * W;
    const bf16* ip = in + ((size_t)n * PIX + (size_t)(y + 1) * Wq + (x + 1)) * 128;
    float a[8];
#pragma unroll
    for (int o = 0; o < 8; ++o) a[o] = 0.f;
    for (int oc = 0; oc < 16; ++oc) {
        U16x8 q; q.u = *(const uint4*)(ip + oc * 8);
#pragma unroll
        for (int e = 0; e < 8; ++e) {
            float f = __uint_as_float((unsigned)q.s[e] << 16);
#pragma unroll
            for (int o = 0; o < 8; ++o) a[o] = fmaf(sw[o * 128 + oc * 8 + e], f, a[o]);
        }
    }
#pragma unroll
    for (int o = 0; o < 8; ++o)
        out[((size_t)n * 8 + o) * HW + pix] = __float2bfloat16(a[o]);
}

// GroupNorm stats/apply on FLAT planar bf16 (mfeat)
__global__ __launch_bounds__(256) void gn_stats_v(const bf16* __restrict__ x,
                                                  float* __restrict__ stats, int per_group)
{
    const int g = blockIdx.x;
    const uint4* xp = (const uint4*)(x + (size_t)g * per_group);
    const int nvec = per_group >> 3;
    float s = 0.f, ss = 0.f;
    const int stride = 256 * gridDim.y;
    for (int i = blockIdx.y * 256 + threadIdx.x; i < nvec; i += stride) {
        uint4 u = xp[i];
        float f0,f1,f2,f3,f4,f5,f6,f7;
        b2f2(u.x, f0, f1); b2f2(u.y, f2, f3); b2f2(u.z, f4, f5); b2f2(u.w, f6, f7);
        s += ((f0+f1)+(f2+f3)) + ((f4+f5)+(f6+f7));
        ss = fmaf(f0,f0,ss); ss = fmaf(f1,f1,ss); ss = fmaf(f2,f2,ss); ss = fmaf(f3,f3,ss);
        ss = fmaf(f4,f4,ss); ss = fmaf(f5,f5,ss); ss = fmaf(f6,f6,ss); ss = fmaf(f7,f7,ss);
    }
#pragma unroll
    for (int off = 32; off > 0; off >>= 1) {
        s  += __shfl_down(s,  off, 64);
        ss += __shfl_down(ss, off, 64);
    }
    __shared__ float sh[8];
    const int wv = threadIdx.x >> 6;
    if ((threadIdx.x & 63) == 0) { sh[wv * 2] = s; sh[wv * 2 + 1] = ss; }
    __syncthreads();
    if (threadIdx.x == 0) {
        s  = sh[0] + sh[2] + sh[4] + sh[6];
        ss = sh[1] + sh[3] + sh[5] + sh[7];
        atomicAdd(&stats[2 * g],     s);
        atomicAdd(&stats[2 * g + 1], ss);
    }
}

__global__ void gn_apply_v(bf16* __restrict__ x, const float* __restrict__ stats,
                           const void* __restrict__ gamma, const void* __restrict__ beta,
                           size_t gb_off, const int* __restrict__ flags,
                           int HW, int C, int per_group, float inv_len, long nvec)
{
    const bool fw = flags[0] != 0;
    long v = (long)blockIdx.x * blockDim.x + threadIdx.x;
    if (v >= nvec) return;
    long i0 = v * 8;
    int gl = (int)(i0 / per_group);
    float mu  = stats[2 * gl] * inv_len;
    float var = fmaxf(stats[2 * gl + 1] * inv_len - mu * mu, 0.f);
    float iv  = rsqrtf(var + 1e-5f);
    int cc = (int)((i0 / HW) % C);
    float ga = ldg_any(gamma, gb_off + cc, fw);
    float be = ldg_any(beta,  gb_off + cc, fw);
    float sc = iv * ga, sf = be - mu * iv * ga;
    uint4 u = *(const uint4*)(x + i0);
    float f[8];
    b2f2(u.x, f[0], f[1]); b2f2(u.y, f[2], f[3]);
    b2f2(u.z, f[4], f[5]); b2f2(u.w, f[6], f[7]);
#pragma unroll
    for (int j = 0; j < 8; ++j) f[j] = fmaxf(fmaf(f[j], sc, sf), 0.f);
    uint4 o;
    o.x = f2b(f[0]) | ((unsigned)f2b(f[1]) << 16);
    o.y = f2b(f[2]) | ((unsigned)f2b(f[3]) << 16);
    o.z = f2b(f[4]) | ((unsigned)f2b(f[5]) << 16);
    o.w = f2b(f[6]) | ((unsigned)f2b(f[7]) << 16);
    *(uint4*)(x + i0) = o;
}

__global__ __launch_bounds__(256) void dyn_conv_k(const bf16* __restrict__ mf,
                                                  const float* __restrict__ prm,
                                                  float* __restrict__ out, int H, int W)
{
    const int inst = blockIdx.y;
    __shared__ float p[169];
    if (threadIdx.x < 169) p[threadIdx.x] = prm[inst * 169 + threadIdx.x];
    __syncthreads();
    const int HW = H * W;
    const int pix = blockIdx.x * 256 + threadIdx.x;
    if (pix >= HW) return;
    const int b = inst / 100;
    float xin[10];
#pragma unroll
    for (int c = 0; c < 8; ++c) xin[c] = cvt(mf[((size_t)(b * 8 + c)) * HW + pix]);
    int yy = pix / W, xx = pix - yy * W;
    xin[8] = -1.f + 2.f * xx / (W - 1);
    xin[9] = -1.f + 2.f * yy / (H - 1);
    float h1[8];
#pragma unroll
    for (int o = 0; o < 8; ++o) {
        float s = p[152 + o];
#pragma unroll
        for (int c = 0; c < 10; ++c) s = fmaf(p[o * 10 + c], xin[c], s);
        h1[o] = fmaxf(s, 0.f);
    }
    float h2[8];
#pragma unroll
    for (int o = 0; o < 8; ++o) {
        float s = p[160 + o];
#pragma unroll
        for (int c = 0; c < 8; ++c) s = fmaf(p[80 + o * 8 + c], h1[c], s);
        h2[o] = fmaxf(s, 0.f);
    }
    float s = p[168];
#pragma unroll
    for (int c = 0; c < 8; ++c) s = fmaf(p[144 + c], h2[c], s);
    out[(size_t)inst * HW + pix] = s;
}

// ---------------------------------------------------------------------------
// host helpers
// ---------------------------------------------------------------------------
struct Norm { const float* st; const void* g; const void* b; size_t off; int cpg; int Gn; float inv; };
struct Geo  { int H, W, Wq, Hp, PIX; };

static inline Geo mkgeo(int H, int W) {
    int xb = (W + 31) / 32, yb = (H + 3) / 4;
    Geo g; g.H = H; g.W = W; g.Wq = (xb - 1) * 32 + 34; g.Hp = (yb - 1) * 4 + 6;
    g.PIX = g.Hp * g.Wq;
    return g;
}

static inline void mconv(const bf16* in, const bf16* wrep, const Norm* nm,
                         const void* bias, const void* scale, int sidx,
                         void* out, int outm, size_t out_off, int out_C,
                         const int* flags, int N, int Cin, Geo g, int Cout, hipStream_t s)
{
    int cob = (Cout + 127) / 128, Cpad = cob * 128;
    dim3 gr((g.W + 31) / 32, (g.H + 3) / 4, N * cob);
    conv3x3_mfma_k<<<gr, 256, 0, s>>>(
        in, wrep,
        nm ? nm->st : nullptr, nm ? nm->g : nullptr, nm ? nm->b : nullptr,
        nm ? nm->off : 0, nm ? nm->cpg : 1, nm ? nm->Gn : 1, nm ? nm->inv : 1.f,
        bias, scale, sidx, out, outm, out_off, out_C,
        flags, Cin, g.H, g.W, g.Wq, g.PIX, Cout, Cpad, cob);
}

static inline void run_padT(const void* src, const int* flags, bf16* dst,
                            int N, int C, Geo g, hipStream_t s)
{
    long total = (long)N * g.PIX * (C >> 3);
    padT_k<<<(int)((total + 255) / 256), 256, 0, s>>>(src, flags, dst, C, g.H, g.W,
                                                      g.Wq, g.Hp, g.PIX, total);
}

static inline void run_stats_nhwc(const bf16* x, float* st, int N, int C, int cpg, int Gn,
                                  Geo g, hipStream_t s)
{
    int C8 = C >> 3;
    long nvec = (long)g.PIX * C8;
    int chunks = (int)((nvec + 16383) / 16384);
    if (chunks > 32) chunks = 32; if (chunks < 1) chunks = 1;
    gn_stats_nhwc<<<dim3(chunks, 1, N), 256, 0, s>>>(x, st, C8, cpg >> 3, Gn,
                                                     nvec, g.PIX * C);
}

static inline void run_apply_nhwc(bf16* x, const float* st, const void* gm, const void* bt,
                                  size_t off, const int* flags, int N, int C, int cpg, int Gn,
                                  Geo g, hipStream_t s)
{
    long total = (long)N * g.H * g.W * (C >> 3);
    gn_apply_nhwc<<<(int)((total + 255) / 256), 256, 0, s>>>(
        x, st, gm, bt, off, flags, C, cpg, Gn, g.H, g.W, g.Wq, g.PIX,
        1.f / ((float)cpg * g.H * g.W), total);
}

extern "C" void kernel_launch(void* const* d_in, const int* in_sizes, int n_in,
                              void* d_out, int out_size, void* d_ws, size_t ws_size,
                              hipStream_t stream)
{
    const void* f[5] = {d_in[0], d_in[1], d_in[2], d_in[3], d_in[4]};
    static const int Hs[5] = {96, 48, 24, 12, 6};
    static const int Wd[5] = {160, 80, 40, 20, 10};
    const void* head_w     = d_in[5];
    const void* head_gn_g  = d_in[6];
    const void* head_gn_b  = d_in[7];
    const void* head_out_w = d_in[8];
    const void* head_out_b = d_in[9];
    const void* scales     = d_in[10];
    const void* ref_w      = d_in[11];
    const void* ref_gn_g   = d_in[12];
    const void* ref_gn_b   = d_in[13];
    const void* tow_w      = d_in[14];
    const void* tow_gn_g   = d_in[15];
    const void* tow_gn_b   = d_in[16];
    const void* out_w      = d_in[17];
    const void* out_gn_g   = d_in[18];
    const void* out_gn_b   = d_in[19];

    Geo G[5];
    for (int l = 0; l < 5; ++l) G[l] = mkgeo(Hs[l], Wd[l]);

    size_t po[5]; size_t off = 0;
    for (int l = 0; l < 5; ++l) { po[l] = off; off += (size_t)2 * 254 * Hs[l] * Wd[l]; }
    size_t mf_off = off; off += 245760;
    size_t ml_off = off;

    // ---- workspace (~42 MB) ----
    const size_t ACAP = (size_t)2 * 256 * G[0].PIX;       // 8,128,512 elems
    bf16*  A     = (bf16*)d_ws;
    bf16*  B     = A + ACAP;
    bf16*  B2    = B + ACAP;                              // 2*128*4900 = 1,254,400
    bf16*  mfeat = B2 + 1254400;
    float* prm   = (float*)(mfeat + 245760);              // 33,800 f32
    float* stats = prm + 33800;                           // 4,096 f32
    int*   flags = (int*)(stats + 4096);                  // 16 int
    bf16*  wrep  = (bf16*)(flags + 16);                   // 2,949,120 bf16
    float* dyn   = (float*)A;                             // aliases A after last read

    bf16* wrepH  = wrep;                        // 4 x 589824 (head layers)
    bf16* wrepHO = wrep + 4 * 589824;           // 589824 (head_out, Cpad 256)
    bf16* wrepR  = wrep;                        // mask phase reuses region
    bf16* wrepT  = wrep + 3 * 294912;

    hipMemsetAsync(stats, 0, 4096 * sizeof(float), stream);
    detect_k<<<1, 64, 0, stream>>>((const unsigned int*)d_in[0], flags);

    float* sp = stats;

    // repack head weights
    for (int l = 0; l < 4; ++l) {
        int total = 9 * 256 * 256;
        repack_off_k<<<(total + 255) / 256, 256, 0, stream>>>(
            head_w, (size_t)l * 589824, flags, wrepH + (size_t)l * 589824, 256, 256, 256, total);
    }
    {
        int total = 9 * 256 * 256;
        repack_off_k<<<(total + 255) / 256, 256, 0, stream>>>(
            head_out_w, 0, flags, wrepHO, 254, 256, 256, total);
    }

    // ---------------- head branches ----------------
    for (int lvl = 0; lvl < 5; ++lvl) {
        Geo g = G[lvl];
        int HW = g.H * g.W;
        float inv_pg = 1.f / (8 * HW);
        run_padT(f[lvl], flags, B, 2, 256, g, stream);
        hipMemsetAsync(A, 0, (size_t)2 * 256 * g.PIX * sizeof(bf16), stream);
        mconv(B, wrepH, nullptr, nullptr, nullptr, 0, A, 0, 0, 256,
              flags, 2, 256, g, 256, stream);
        float* s_prev = sp; sp += 128;
        run_stats_nhwc(A, s_prev, 2, 256, 8, 32, g, stream);
        bf16* a = A; bf16* bb = B;
        for (int l = 1; l < 4; ++l) {
            Norm nm{s_prev, head_gn_g, head_gn_b, (size_t)(l - 1) * 256, 8, 32, inv_pg};
            mconv(a, wrepH + (size_t)l * 589824, &nm, nullptr, nullptr, 0,
                  bb, 0, 0, 256, flags, 2, 256, g, 256, stream);
            s_prev = sp; sp += 128;
            run_stats_nhwc(bb, s_prev, 2, 256, 8, 32, g, stream);
            bf16* tmp = a; a = bb; bb = tmp;
        }
        Norm nm{s_prev, head_gn_g, head_gn_b, (size_t)3 * 256, 8, 32, inv_pg};
        mconv(a, wrepHO, &nm, head_out_b, scales, lvl, d_out, 2, po[lvl], 0,
              flags, 2, 256, g, 254, stream);
        if (lvl == 0)
            extract_params_k<<<(200 * 169 + 255) / 256, 256, 0, stream>>>(d_out, flags, prm, HW);
    }

    // repack mask weights (enqueued after all head convs; stream order protects)
    for (int i = 0; i < 3; ++i) {
        int total = 9 * 128 * 256;
        repack_off_k<<<(total + 255) / 256, 256, 0, stream>>>(
            ref_w, (size_t)i * 294912, flags, wrepR + (size_t)i * 294912, 128, 128, 256, total);
    }
    for (int l = 0; l < 4; ++l) {
        int total = 9 * 128 * 128;
        repack_off_k<<<(total + 255) / 256, 256, 0, stream>>>(
            tow_w, (size_t)l * 147456, flags, wrepT + (size_t)l * 147456, 128, 128, 128, total);
    }

    // ---------------- mask branch ----------------
    {
        Geo g0 = G[0];
        const int HW = 96 * 160;

        // refine 0
        run_padT(f[0], flags, B, 2, 256, g0, stream);
        hipMemsetAsync(A, 0, (size_t)2 * 128 * g0.PIX * sizeof(bf16), stream);
        mconv(B, wrepR, nullptr, nullptr, nullptr, 0, A, 0, 0, 128,
              flags, 2, 256, g0, 128, stream);
        float* s0 = sp; sp += 4;
        run_stats_nhwc(A, s0, 2, 128, 128, 1, g0, stream);
        run_apply_nhwc(A, s0, ref_gn_g, ref_gn_b, 0, flags, 2, 128, 128, 1, g0, stream);

        // refines 1,2 + upsample-add into A
        for (int i = 1; i < 3; ++i) {
            Geo gi = G[i];
            run_padT(f[i], flags, B, 2, 256, gi, stream);
            hipMemsetAsync(B2, 0, (size_t)2 * 128 * gi.PIX * sizeof(bf16), stream);
            mconv(B, wrepR + (size_t)i * 294912, nullptr, nullptr, nullptr, 0,
                  B2, 0, 0, 128, flags, 2, 256, gi, 128, stream);
            float* si = sp; sp += 4;
            run_stats_nhwc(B2, si, 2, 128, 128, 1, gi, stream);
            run_apply_nhwc(B2, si, ref_gn_g, ref_gn_b, (size_t)i * 128, flags,
                           2, 128, 128, 1, gi, stream);
            long tot = (long)2 * 96 * 160 * 16;
            upsample_add_nhwc<<<(int)((tot + 255) / 256), 256, 0, stream>>>(
                B2, A, gi.H, gi.W, gi.Wq, gi.PIX, 96, 160, g0.Wq, g0.PIX, tot);
        }

        // tower
        float inv_pg = 1.f / (128 * HW);
        hipMemsetAsync(B, 0, (size_t)2 * 128 * g0.PIX * sizeof(bf16), stream);
        mconv(A, wrepT, nullptr, nullptr, nullptr, 0, B, 0, 0, 128,
              flags, 2, 128, g0, 128, stream);
        float* sT = sp; sp += 4;
        run_stats_nhwc(B, sT, 2, 128, 128, 1, g0, stream);
        bf16* a = B; bf16* bb = A;
        for (int l = 1; l < 4; ++l) {
            Norm nm{sT, tow_gn_g, tow_gn_b, (size_t)(l - 1) * 128, 128, 1, inv_pg};
            mconv(a, wrepT + (size_t)l * 147456, &nm, nullptr, nullptr, 0,
                  bb, 0, 0, 128, flags, 2, 128, g0, 128, stream);
            sT = sp; sp += 4;
            run_stats_nhwc(bb, sT, 2, 128, 128, 1, g0, stream);
            bf16* tmp = a; a = bb; bb = tmp;
        }
        // final tower raw in a (= A), stats sT
        run_apply_nhwc(a, sT, tow_gn_g, tow_gn_b, (size_t)3 * 128, flags, 2, 128, 128, 1, g0, stream);
        conv1x1_nhwc<<<(2 * HW + 255) / 256, 256, 0, stream>>>(
            a, out_w, flags, mfeat, 96, 160, g0.Wq, g0.PIX);
        float* sM = sp; sp += 4;
        {
            int chunks = (8 * HW) / 8192; if (chunks < 1) chunks = 1;
            gn_stats_v<<<dim3(2, chunks), 256, 0, stream>>>(mfeat, sM, 8 * HW);
            long nvec = ((long)2 * 8 * HW) >> 3;
            gn_apply_v<<<(int)((nvec + 255) / 256), 256, 0, stream>>>(
                mfeat, sM, out_gn_g, out_gn_b, 0, flags, HW, 8, 8 * HW, 1.f / (8 * HW), nvec);
        }
        cast_out_k<<<(2 * 8 * HW + 255) / 256, 256, 0, stream>>>(
            mfeat, d_out, mf_off, flags, (long)2 * 8 * HW);
        dyn_conv_k<<<dim3((HW + 255) / 256, 200), 256, 0, stream>>>(mfeat, prm, dyn, 96, 160);
        long nt = (long)200 * 192 * 320;
        resize_out_k<<<(int)((nt + 255) / 256), 256, 0, stream>>>(
            dyn, d_out, ml_off, flags, 96, 160, 192, 320, nt);
    }
}

// Round 9
// 2075.650 us; speedup vs baseline: 3.3474x; 1.1731x over previous
//
#include <hip/hip_runtime.h>
#include <hip/hip_bf16.h>

typedef __hip_bfloat16 bf16;
typedef short v8s __attribute__((ext_vector_type(8)));
typedef float v4f __attribute__((ext_vector_type(4)));

__device__ __forceinline__ float cvt(bf16 v) { return __bfloat162float(v); }

__device__ __forceinline__ float ldg_any(const void* p, size_t i, bool bf) {
    return bf ? cvt(((const bf16*)p)[i]) : ((const float*)p)[i];
}
__device__ __forceinline__ void stg_any(void* p, size_t i, float v, bool bf) {
    if (bf) ((bf16*)p)[i] = __float2bfloat16(v);
    else    ((float*)p)[i] = v;
}
__device__ __forceinline__ bool bfmode(int mode, const int* flags) {
    return mode == 2 ? (flags[0] != 0) : (mode != 0);
}
__device__ __forceinline__ unsigned short f2b(float f) {
    bf16 h = __float2bfloat16(f); return *(unsigned short*)&h;
}
__device__ __forceinline__ void b2f2(unsigned u, float& a, float& b) {
    a = __uint_as_float(u << 16);
    b = __uint_as_float(u & 0xffff0000u);
}

union U16x8 { uint4 u; unsigned short s[8]; };

// lgkm-only barrier: publishes LDS without draining the global-load queue
// (__syncthreads emits s_waitcnt vmcnt(0) which kills cross-phase prefetch).
// Safe here: all LDS traffic is explicit ds_write/ds_read (no global_load_lds),
// and register uses of prefetched global loads get compiler-counted vmcnt.
#define BARLDS() asm volatile("s_waitcnt lgkmcnt(0)\n\ts_barrier" ::: "memory")

// ---------------------------------------------------------------------------
// dtype probe on f3 (N(0,1) data): fp32 never has exponent >= 200.
// ---------------------------------------------------------------------------
__global__ void detect_k(const unsigned int* __restrict__ x, int* __restrict__ flags)
{
    unsigned int u = x[threadIdx.x];
    int e = (u >> 23) & 0xFF;
    unsigned long long m = __ballot(e >= 200);
    if (threadIdx.x == 0) flags[0] = (m != 0ULL) ? 1 : 0;
}

// ---------------------------------------------------------------------------
// weight repack: OIHW (+element offset) -> [tap][co(pad)][ci] bf16
// ---------------------------------------------------------------------------
__global__ void repack_off_k(const void* __restrict__ w, size_t w_off,
                             const int* __restrict__ flags, bf16* __restrict__ dst,
                             int Cout, int Cpad, int Cin, int total)
{
    const bool fw = flags[0] != 0;
    int i = blockIdx.x * 256 + threadIdx.x;
    if (i >= total) return;
    int ci = i % Cin; int r = i / Cin; int co = r % Cpad; int tap = r / Cpad;
    float v = 0.f;
    if (co < Cout) v = ldg_any(w, w_off + ((size_t)co * Cin + ci) * 9 + tap, fw);
    dst[i] = __float2bfloat16(v);
}

// ---------------------------------------------------------------------------
// pad + transpose: NCHW (fp32/bf16) -> NHWC padded bf16 [n][Hp][Wq][C].
// ---------------------------------------------------------------------------
__global__ void padT_k(const void* __restrict__ src, const int* __restrict__ flags,
                       bf16* __restrict__ dst, int C, int H, int W, int Wq, int Hp,
                       int PIX, long total)
{
    const bool fb = flags[0] != 0;
    long v = (long)blockIdx.x * 256 + threadIdx.x;
    if (v >= total) return;
    const int C8 = C >> 3;
    int oct = (int)(v & (C8 - 1));
    long rest = v >> (C == 256 ? 5 : 4);
    int px = (int)(rest % Wq);
    long r2 = rest / Wq;
    int py = (int)(r2 % Hp);
    int n  = (int)(r2 / Hp);
    U16x8 o;
    if (py == 0 || py > H || px == 0 || px > W) {
        o.u = uint4{0, 0, 0, 0};
    } else {
        const int HW = H * W;
        size_t sb = ((size_t)n * C + oct * 8) * HW + (size_t)(py - 1) * W + (px - 1);
#pragma unroll
        for (int e = 0; e < 8; ++e) o.s[e] = f2b(ldg_any(src, sb + (size_t)e * HW, fb));
    }
    *(uint4*)(dst + v * 8) = o.u;
}

// ---------------------------------------------------------------------------
// MFMA implicit-GEMM 3x3 SAME conv, NHWC padded input, LDS-staged WEIGHTS.
// Block: 128 co x (4 rows x 32 cols); 4 waves tiled 2(co-slice) x 2(row-pair).
// Per phase (kernel row): cooperative 24KB weight stage (dbuf) + MFMA on
// previous slab. lgkm-only barriers keep prefetch loads in flight across
// phases. Weight LDS XOR-swizzled. NHWC epilogue via LDS transpose.
// NEW: optional fused GroupNorm STATS of the output (ostat != nullptr):
// per-block reduction of acc (valid pixels) -> per-octet (sum, sumsq) ->
// hierarchical shuffle/LDS reduce -> <=16 atomics per block.
// ---------------------------------------------------------------------------
__global__ __launch_bounds__(256, 2) void conv3x3_mfma_k(
    const bf16* __restrict__ in,      // NHWC padded
    const bf16* __restrict__ wrep,    // [tap][co pad][ci]
    const float* __restrict__ gstat, const void* __restrict__ gamma,
    const void* __restrict__ beta, size_t gb_off, int cpg, int Gn, float inv_pg,
    const void* __restrict__ bias, const void* __restrict__ scale, int sidx,
    void* __restrict__ out, int outm, size_t out_off, int out_C,
    const int* __restrict__ flags,
    int Cin, int H, int W, int Wq, int PIX, int Cout, int Cpad, int co_blocks,
    float* __restrict__ ostat, int ocpg8, int oGn)
{
    const bool fw   = flags[0] != 0;
    const bool fout = bfmode(outm, flags);

    const int t    = threadIdx.x;
    const int lane = t & 63;
    const int wv   = t >> 6;
    const int c    = lane & 15;
    const int quad = lane >> 4;
    const int wr   = wv >> 1;     // wave row-pair (0,1)
    const int wc   = wv & 1;      // wave co-slice (0,1)
    const int x0   = blockIdx.x * 32;
    const int y0   = blockIdx.y * 4;
    const int n    = blockIdx.z / co_blocks;
    const int cb   = blockIdx.z % co_blocks;

    // LDS arena: img 2x13056 | w 2x24576 | scale 1024 | shift 1024 = 77312 B
    __shared__ __align__(16) char s_arena[77312];
    __shared__ float s_srd[4][8][2];     // fused-stats cross-wave combine
    float* s_scale = (float*)(s_arena + 75264);
    float* s_shift = (float*)(s_arena + 76288);

    const bool donorm = (gstat != nullptr);

    v4f acc[4][4];
#pragma unroll
    for (int i = 0; i < 4; ++i)
#pragma unroll
        for (int j = 0; j < 4; ++j) acc[i][j] = v4f{0.f, 0.f, 0.f, 0.f};

    const bf16* inb = in + (size_t)n * PIX * Cin;

    // static image staging map: flat = t + 256*it over 816 = 204 pos x 4 octets
    int goff[4], loff[4], okm[4], octv[4];
#pragma unroll
    for (int it = 0; it < 4; ++it) {
        int flat = t + 256 * it;
        int pos = flat >> 2, oct = flat & 3;
        int r = (pos * 241) >> 13;          // pos / 34 (exact for pos < 204)
        int cc = pos - r * 34;
        int py = y0 + r, px = x0 + cc;
        bool valid = flat < 816;
        goff[it] = (py * Wq + px) * Cin + oct * 8;
        loff[it] = valid ? (pos * 64 + (((oct + (pos >> 1)) & 3) << 4)) : -1;
        okm[it]  = (py >= 1 && py <= H && px >= 1 && px <= W) ? 1 : 0;
        octv[it] = oct * 8;
    }

    uint4 L[4];
    uint4 wrg[6];

#define STAGE_LOAD(ci0_) { \
    _Pragma("unroll") for (int it = 0; it < 4; ++it) \
        if (loff[it] >= 0) L[it] = *(const uint4*)(inb + goff[it] + (ci0_)); }

#define STAGE_WRITE(ci0_, b_) { \
    char* db = s_arena + (b_) * 13056; \
    _Pragma("unroll") for (int it = 0; it < 4; ++it) { \
        if (loff[it] < 0) continue; \
        uint4 q = L[it]; \
        if (donorm) { \
            U16x8 u_; u_.u = q; U16x8 o_; \
            if (okm[it]) { \
                int cib = (ci0_) + octv[it]; \
                _Pragma("unroll") for (int e = 0; e < 8; ++e) { \
                    float v_ = __uint_as_float((unsigned)u_.s[e] << 16); \
                    v_ = fmaxf(fmaf(v_, s_scale[cib + e], s_shift[cib + e]), 0.f); \
                    o_.s[e] = f2b(v_); } \
            } else { o_.u = uint4{0, 0, 0, 0}; } \
            q = o_.u; } \
        *(uint4*)(db + loff[it]) = q; } }

// cooperative coalesced weight stage: phase (ky=g_) of chunk ci0_, 24KB
#define WLOAD(ci0_, g_) { \
    _Pragma("unroll") for (int j = 0; j < 6; ++j) { \
        int f_ = t + 256 * j; int tapl_ = f_ >> 9; int rem_ = f_ & 511; \
        wrg[j] = *(const uint4*)(wrep + ((size_t)(3 * (g_) + tapl_) * Cpad \
                 + cb * 128 + (rem_ >> 2)) * (size_t)Cin + (ci0_) + (rem_ & 3) * 8); } }

// XOR-swizzled store: oct' = (oct + co + (co>>2)) & 3
#define WSTORE(b_) { \
    bf16* sw = (bf16*)(s_arena + 26112 + (b_) * 24576); \
    _Pragma("unroll") for (int j = 0; j < 6; ++j) { \
        int f_ = t + 256 * j; int tapl_ = f_ >> 9; int rem_ = f_ & 511; \
        int co_ = rem_ >> 2; int oc_ = (rem_ + co_ + (co_ >> 2)) & 3; \
        *(uint4*)(&sw[tapl_ * 4096 + co_ * 32 + oc_ * 8]) = wrg[j]; } }

// MFMA phase: kernel row g_, 3 kx taps, 48 MFMAs/wave
#define MPHASE(ib_, wb_, g_) { \
    const char* sb_ = s_arena + (ib_) * 13056; \
    const bf16* wp_ = (const bf16*)(s_arena + 26112 + (wb_) * 24576); \
    _Pragma("unroll") for (int kx = 0; kx < 3; ++kx) { \
        v8s bfr[4]; \
        _Pragma("unroll") for (int nf = 0; nf < 4; ++nf) { \
            int pos = (2 * wr + (nf >> 1) + (g_)) * 34 + kx + c + (nf & 1) * 16; \
            bfr[nf] = *(const v8s*)(sb_ + pos * 64 + (((quad + (pos >> 1)) & 3) << 4)); } \
        _Pragma("unroll") for (int mf = 0; mf < 4; ++mf) { \
            int col_ = wc * 64 + mf * 16 + c; \
            int os_ = (quad + col_ + (col_ >> 2)) & 3; \
            v8s af = *(const v8s*)(wp_ + kx * 4096 + col_ * 32 + os_ * 8); \
            _Pragma("unroll") for (int nf = 0; nf < 4; ++nf) \
                acc[mf][nf] = __builtin_amdgcn_mfma_f32_16x16x32_bf16( \
                    af, bfr[nf], acc[mf][nf], 0, 0, 0); } } }

    // prologue: stage img chunk 0 and weight phase (0, ky=0)
    STAGE_LOAD(0);
    WLOAD(0, 0);
    if (donorm) {
        for (int ch = t; ch < Cin; ch += 256) {
            int gl = n * Gn + ch / cpg;
            float mu  = gstat[2 * gl] * inv_pg;
            float var = fmaxf(gstat[2 * gl + 1] * inv_pg - mu * mu, 0.f);
            float iv  = rsqrtf(var + 1e-5f);
            float ga  = ldg_any(gamma, gb_off + ch, fw);
            float be  = ldg_any(beta,  gb_off + ch, fw);
            s_scale[ch] = iv * ga;
            s_shift[ch] = be - mu * iv * ga;
        }
    }
    BARLDS();
    STAGE_WRITE(0, 0);
    WSTORE(0);
    BARLDS();

    // main loop: two 32-ci chunks per iteration (6 phases), static buffers.
    for (int ci0 = 0; ci0 < Cin; ci0 += 64) {
        const bool moreB = (ci0 + 64 < Cin);
        // P0: chunk A, ky=0, img0, w0
        STAGE_LOAD(ci0 + 32);
        WLOAD(ci0, 1);
        MPHASE(0, 0, 0);
        WSTORE(1);
        BARLDS();
        // P1: A, ky=1, w1
        WLOAD(ci0, 2);
        MPHASE(0, 1, 1);
        WSTORE(0);
        BARLDS();
        // P2: A, ky=2, w0; write img chunk B
        WLOAD(ci0 + 32, 0);
        MPHASE(0, 0, 2);
        STAGE_WRITE(ci0 + 32, 1);
        WSTORE(1);
        BARLDS();
        // P3: chunk B, ky=0, img1, w1
        if (moreB) STAGE_LOAD(ci0 + 64);
        WLOAD(ci0 + 32, 1);
        MPHASE(1, 1, 0);
        WSTORE(0);
        BARLDS();
        // P4: B, ky=1, w0
        WLOAD(ci0 + 32, 2);
        MPHASE(1, 0, 1);
        WSTORE(1);
        BARLDS();
        // P5: B, ky=2, w1; prefetch next iteration
        if (moreB) { WLOAD(ci0 + 64, 0); }
        MPHASE(1, 1, 2);
        if (moreB) { STAGE_WRITE(ci0 + 64, 0); WSTORE(0); }
        BARLDS();
    }
#undef MPHASE
#undef WSTORE
#undef WLOAD
#undef STAGE_WRITE
#undef STAGE_LOAD

    // ---- fused GroupNorm stats of the output tile (before any LDS reuse) ----
    // Per-thread: all 4 regs of acc[mf][*] share one co-octet
    // (co = wc*64+mf*16+quad*4+reg). Butterfly over c (x-positions) and the
    // quad-pair (octet halves); cross-wave via 256B LDS; <=16 atomics/block.
    if (ostat) {
        float ps[4], pq[4];
#pragma unroll
        for (int mf = 0; mf < 4; ++mf) { ps[mf] = 0.f; pq[mf] = 0.f; }
#pragma unroll
        for (int nf = 0; nf < 4; ++nf) {
            int y = y0 + 2 * wr + (nf >> 1);
            int x = x0 + (nf & 1) * 16 + c;
            bool ok = (y < H) && (x < W);
#pragma unroll
            for (int mf = 0; mf < 4; ++mf)
#pragma unroll
                for (int reg = 0; reg < 4; ++reg) {
                    float v = ok ? acc[mf][nf][reg] : 0.f;
                    ps[mf] += v;
                    pq[mf] = fmaf(v, v, pq[mf]);
                }
        }
#pragma unroll
        for (int off = 1; off <= 16; off <<= 1)
#pragma unroll
            for (int mf = 0; mf < 4; ++mf) {
                ps[mf] += __shfl_xor(ps[mf], off, 64);
                pq[mf] += __shfl_xor(pq[mf], off, 64);
            }
        if (c == 0 && ((quad & 1) == 0)) {
            int qh = quad >> 1;
#pragma unroll
            for (int mf = 0; mf < 4; ++mf) {
                s_srd[wv][mf * 2 + qh][0] = ps[mf];
                s_srd[wv][mf * 2 + qh][1] = pq[mf];
            }
        }
        BARLDS();
        if (t < 16) {
            int wcl = t >> 3, idx = t & 7;
            float s  = s_srd[wcl][idx][0] + s_srd[wcl + 2][idx][0];
            float ss = s_srd[wcl][idx][1] + s_srd[wcl + 2][idx][1];
            for (int off = ocpg8 >> 1; off >= 1; off >>= 1) {
                s  += __shfl_down(s,  off, 64);
                ss += __shfl_down(ss, off, 64);
            }
            if ((t & (ocpg8 - 1)) == 0) {
                int gl = n * oGn + (cb * 16 + t) / ocpg8;
                atomicAdd(&ostat[2 * gl],     s);
                atomicAdd(&ostat[2 * gl + 1], ss);
            }
        }
    }

    if (outm == 0) {
        // ---- coalesced NHWC epilogue via LDS transpose (32KB of arena) ----
        // acc -> [pix 128][co 128] bf16; 16B-slot XOR swizzle by (pix&7).
        // octet of co = (wc*64 + mf*16 + quad*4) >> 3 = wc*8 + mf*2 + (quad>>1)
        char* tb = s_arena;
#pragma unroll
        for (int mf = 0; mf < 4; ++mf) {
            int s0 = wc * 8 + mf * 2 + (quad >> 1);
#pragma unroll
            for (int nf = 0; nf < 4; ++nf) {
                int lp = (2 * wr + (nf >> 1)) * 32 + (nf & 1) * 16 + c;
                uint2 o;
                o.x = f2b(acc[mf][nf][0]) | ((unsigned)f2b(acc[mf][nf][1]) << 16);
                o.y = f2b(acc[mf][nf][2]) | ((unsigned)f2b(acc[mf][nf][3]) << 16);
                *(uint2*)(tb + lp * 256 + ((s0 ^ (lp & 7)) << 4) + (quad & 1) * 8) = o;
            }
        }
        BARLDS();
        bf16* ob = (bf16*)out + (size_t)n * PIX * out_C + cb * 128;
        const int o8 = t & 15;          // co octet
#pragma unroll
        for (int pass = 0; pass < 8; ++pass) {
            int lp = pass * 16 + (t >> 4);
            uint4 q = *(const uint4*)(tb + lp * 256 + ((o8 ^ (lp & 7)) << 4));
            int y = y0 + (lp >> 5);
            int x = x0 + (lp & 31);
            if (y < H && x < W)
                *(uint4*)(ob + ((size_t)(y + 1) * Wq + (x + 1)) * out_C + o8 * 8) = q;
        }
    } else {
        // planar output (f32/bf16)
        const float al = scale ? ldg_any(scale, sidx, fw) : 1.f;
        const int HW = H * W;
        const int ybase = y0 + 2 * wr;
#pragma unroll
        for (int mf = 0; mf < 4; ++mf) {
            int cobase = cb * 128 + wc * 64 + mf * 16 + quad * 4;
#pragma unroll
            for (int reg = 0; reg < 4; ++reg) {
                int co = cobase + reg;
                if (co >= Cout) continue;
                float bv = bias ? ldg_any(bias, co, fw) : 0.f;
                size_t obase = out_off + ((size_t)n * Cout + co) * HW;
#pragma unroll
                for (int nf = 0; nf < 4; ++nf) {
                    int y = ybase + (nf >> 1);
                    int x = x0 + (nf & 1) * 16 + c;
                    if (y < H && x < W)
                        stg_any(out, obase + (size_t)y * W + x,
                                fmaf(al, acc[mf][nf][reg], bv), fout);
                }
            }
        }
    }
}

// GroupNorm apply + relu on NHWC padded interior (borders stay zero).
__global__ void gn_apply_nhwc(bf16* __restrict__ x, const float* __restrict__ stats,
                              const void* __restrict__ gamma, const void* __restrict__ beta,
                              size_t gb_off, const int* __restrict__ flags,
                              int C, int cpg, int Gn, int H, int W, int Wq, int PIX,
                              float inv_len, long total)
{
    const bool fw = flags[0] != 0;
    long v = (long)blockIdx.x * 256 + threadIdx.x;
    if (v >= total) return;
    const int C8 = C >> 3;
    int oct = (int)(v & (C8 - 1));
    long rest = v / C8;
    int x2 = (int)(rest % W);
    long r2 = rest / W;
    int y = (int)(r2 % H);
    int n = (int)(r2 / H);
    int ch0 = oct * 8;
    int gl = n * Gn + ch0 / cpg;
    float mu  = stats[2 * gl] * inv_len;
    float var = fmaxf(stats[2 * gl + 1] * inv_len - mu * mu, 0.f);
    float iv  = rsqrtf(var + 1e-5f);
    size_t base = ((size_t)n * PIX + (size_t)(y + 1) * Wq + (x2 + 1)) * C + ch0;
    U16x8 u; u.u = *(const uint4*)(x + base);
    U16x8 o;
#pragma unroll
    for (int e = 0; e < 8; ++e) {
        float ga = ldg_any(gamma, gb_off + ch0 + e, fw);
        float be = ldg_any(beta,  gb_off + ch0 + e, fw);
        float f = __uint_as_float((unsigned)u.s[e] << 16);
        f = fmaxf(fmaf(f, iv * ga, be - mu * iv * ga), 0.f);
        o.s[e] = f2b(f);
    }
    *(uint4*)(x + base) = o.u;
}

// ---------------------------------------------------------------------------
__global__ void extract_params_k(const void* __restrict__ pred3, const int* __restrict__ flags,
                                 float* __restrict__ prm, int HW)
{
    const bool bf = flags[0] != 0;
    int tid = blockIdx.x * blockDim.x + threadIdx.x;
    if (tid >= 200 * 169) return;
    int p = tid / 169, c = tid - p * 169;
    int b = p / 100, i = p - b * 100;
    prm[tid] = ldg_any(pred3, ((size_t)b * 254 + 85 + c) * HW + i, bf);
}

// bilinear upsample (align corners), NHWC padded src -> add into NHWC padded dst
__global__ void upsample_add_nhwc(const bf16* __restrict__ src, bf16* __restrict__ dst,
                                  int h, int w, int sWq, int sPIX,
                                  int OH, int OW, int dWq, int dPIX, long total)
{
    long i = (long)blockIdx.x * 256 + threadIdx.x;
    if (i >= total) return;
    const int C = 128, C8 = 16;
    int oct = (int)(i & (C8 - 1));
    long rest = i >> 4;
    int ox = (int)(rest % OW);
    long r = rest / OW;
    int oy = (int)(r % OH);
    int n  = (int)(r / OH);
    float sy = oy * ((h - 1.f) / (OH - 1.f));
    float sx = ox * ((w - 1.f) / (OW - 1.f));
    int y0 = (int)sy; int y1 = min(y0 + 1, h - 1); float wy = sy - y0;
    int x0 = (int)sx; int x1 = min(x0 + 1, w - 1); float wx = sx - x0;
    const bf16* sp = src + (size_t)n * sPIX * C + oct * 8;
    U16x8 q00, q01, q10, q11;
    q00.u = *(const uint4*)(sp + ((size_t)(y0 + 1) * sWq + (x0 + 1)) * C);
    q01.u = *(const uint4*)(sp + ((size_t)(y0 + 1) * sWq + (x1 + 1)) * C);
    q10.u = *(const uint4*)(sp + ((size_t)(y1 + 1) * sWq + (x0 + 1)) * C);
    q11.u = *(const uint4*)(sp + ((size_t)(y1 + 1) * sWq + (x1 + 1)) * C);
    bf16* dp = dst + ((size_t)n * dPIX + (size_t)(oy + 1) * dWq + (ox + 1)) * C + oct * 8;
    U16x8 d; d.u = *(const uint4*)dp;
    U16x8 o;
#pragma unroll
    for (int e = 0; e < 8; ++e) {
        float a00 = __uint_as_float((unsigned)q00.s[e] << 16);
        float a01 = __uint_as_float((unsigned)q01.s[e] << 16);
        float a10 = __uint_as_float((unsigned)q10.s[e] << 16);
        float a11 = __uint_as_float((unsigned)q11.s[e] << 16);
        float t0 = a00 * (1.f - wy) + a10 * wy;
        float t1 = a01 * (1.f - wy) + a11 * wy;
        float dv = __uint_as_float((unsigned)d.s[e] << 16);
        o.s[e] = f2b(dv + t0 * (1.f - wx) + t1 * wx);
    }
    *(uint4*)dp = o.u;
}

__global__ void resize_out_k(const float* __restrict__ src, void* __restrict__ dst,
                             size_t dst_off, const int* __restrict__ flags,
                             int h, int w, int OH, int OW, long total)
{
    const bool bf = flags[0] != 0;
    long i = (long)blockIdx.x * blockDim.x + threadIdx.x;
    if (i >= total) return;
    int ox = (int)(i % OW);
    long r = i / OW;
    int oy = (int)(r % OH);
    int nc = (int)(r / OH);
    float sy = oy * ((h - 1.f) / (OH - 1.f));
    float sx = ox * ((w - 1.f) / (OW - 1.f));
    int y0 = (int)sy; int y1 = min(y0 + 1, h - 1); float wy = sy - y0;
    int x0 = (int)sx; int x1 = min(x0 + 1, w - 1); float wx = sx - x0;
    const float* sp = src + (size_t)nc * h * w;
    float t0 = sp[y0 * w + x0] * (1.f - wy) + sp[y1 * w + x0] * wy;
    float t1 = sp[y0 * w + x1] * (1.f - wy) + sp[y1 * w + x1] * wy;
    stg_any(dst, dst_off + (size_t)i, t0 * (1.f - wx) + t1 * wx, bf);
}

__global__ void cast_out_k(const bf16* __restrict__ src, void* __restrict__ dst,
                           size_t dst_off, const int* __restrict__ flags, long n)
{
    const bool bf = flags[0] != 0;
    long i = (long)blockIdx.x * blockDim.x + threadIdx.x;
    if (i < n) stg_any(dst, dst_off + (size_t)i, cvt(src[i]), bf);
}

// 1x1 conv: NHWC padded (C=128) -> flat NCHW bf16 (8 ch)
__global__ __launch_bounds__(256) void conv1x1_nhwc(const bf16* __restrict__ in,
                                                    const void* __restrict__ w,
                                                    const int* __restrict__ flags,
                                                    bf16* __restrict__ out,
                                                    int H, int W, int Wq, int PIX)
{
    const bool fw = flags[0] != 0;
    __shared__ float sw[8 * 128];
    for (int i = threadIdx.x; i < 1024; i += 256) sw[i] = ldg_any(w, i, fw);
    __syncthreads();
    const int HW = H * W;
    int idx = blockIdx.x * 256 + threadIdx.x;
    if (idx >= 2 * HW) return;
    int pix = idx % HW, n = idx / HW;
    int y = pix / W, x = pix - y * W;
    const bf16* ip = in + ((size_t)n * PIX + (size_t)(y + 1) * Wq + (x + 1)) * 128;
    float a[8];
#pragma unroll
    for (int o = 0; o < 8; ++o) a[o] = 0.f;
    for (int oc = 0; oc < 16; ++oc) {
        U16x8 q; q.u = *(const uint4*)(ip + oc * 8);
#pragma unroll
        for (int e = 0; e < 8; ++e) {
            float f = __uint_as_float((unsigned)q.s[e] << 16);
#pragma unroll
            for (int o = 0; o < 8; ++o) a[o] = fmaf(sw[o * 128 + oc * 8 + e], f, a[o]);
        }
    }
#pragma unroll
    for (int o = 0; o < 8; ++o)
        out[((size_t)n * 8 + o) * HW + pix] = __float2bfloat16(a[o]);
}

// GroupNorm stats/apply on FLAT planar bf16 (mfeat)
__global__ __launch_bounds__(256) void gn_stats_v(const bf16* __restrict__ x,
                                                  float* __restrict__ stats, int per_group)
{
    const int g = blockIdx.x;
    const uint4* xp = (const uint4*)(x + (size_t)g * per_group);
    const int nvec = per_group >> 3;
    float s = 0.f, ss = 0.f;
    const int stride = 256 * gridDim.y;
    for (int i = blockIdx.y * 256 + threadIdx.x; i < nvec; i += stride) {
        uint4 u = xp[i];
        float f0,f1,f2,f3,f4,f5,f6,f7;
        b2f2(u.x, f0, f1); b2f2(u.y, f2, f3); b2f2(u.z, f4, f5); b2f2(u.w, f6, f7);
        s += ((f0+f1)+(f2+f3)) + ((f4+f5)+(f6+f7));
        ss = fmaf(f0,f0,ss); ss = fmaf(f1,f1,ss); ss = fmaf(f2,f2,ss); ss = fmaf(f3,f3,ss);
        ss = fmaf(f4,f4,ss); ss = fmaf(f5,f5,ss); ss = fmaf(f6,f6,ss); ss = fmaf(f7,f7,ss);
    }
#pragma unroll
    for (int off = 32; off > 0; off >>= 1) {
        s  += __shfl_down(s,  off, 64);
        ss += __shfl_down(ss, off, 64);
    }
    __shared__ float sh[8];
    const int wv = threadIdx.x >> 6;
    if ((threadIdx.x & 63) == 0) { sh[wv * 2] = s; sh[wv * 2 + 1] = ss; }
    __syncthreads();
    if (threadIdx.x == 0) {
        s  = sh[0] + sh[2] + sh[4] + sh[6];
        ss = sh[1] + sh[3] + sh[5] + sh[7];
        atomicAdd(&stats[2 * g],     s);
        atomicAdd(&stats[2 * g + 1], ss);
    }
}

__global__ void gn_apply_v(bf16* __restrict__ x, const float* __restrict__ stats,
                           const void* __restrict__ gamma, const void* __restrict__ beta,
                           size_t gb_off, const int* __restrict__ flags,
                           int HW, int C, int per_group, float inv_len, long nvec)
{
    const bool fw = flags[0] != 0;
    long v = (long)blockIdx.x * blockDim.x + threadIdx.x;
    if (v >= nvec) return;
    long i0 = v * 8;
    int gl = (int)(i0 / per_group);
    float mu  = stats[2 * gl] * inv_len;
    float var = fmaxf(stats[2 * gl + 1] * inv_len - mu * mu, 0.f);
    float iv  = rsqrtf(var + 1e-5f);
    int cc = (int)((i0 / HW) % C);
    float ga = ldg_any(gamma, gb_off + cc, fw);
    float be = ldg_any(beta,  gb_off + cc, fw);
    float sc = iv * ga, sf = be - mu * iv * ga;
    uint4 u = *(const uint4*)(x + i0);
    float f[8];
    b2f2(u.x, f[0], f[1]); b2f2(u.y, f[2], f[3]);
    b2f2(u.z, f[4], f[5]); b2f2(u.w, f[6], f[7]);
#pragma unroll
    for (int j = 0; j < 8; ++j) f[j] = fmaxf(fmaf(f[j], sc, sf), 0.f);
    uint4 o;
    o.x = f2b(f[0]) | ((unsigned)f2b(f[1]) << 16);
    o.y = f2b(f[2]) | ((unsigned)f2b(f[3]) << 16);
    o.z = f2b(f[4]) | ((unsigned)f2b(f[5]) << 16);
    o.w = f2b(f[6]) | ((unsigned)f2b(f[7]) << 16);
    *(uint4*)(x + i0) = o;
}

__global__ __launch_bounds__(256) void dyn_conv_k(const bf16* __restrict__ mf,
                                                  const float* __restrict__ prm,
                                                  float* __restrict__ out, int H, int W)
{
    const int inst = blockIdx.y;
    __shared__ float p[169];
    if (threadIdx.x < 169) p[threadIdx.x] = prm[inst * 169 + threadIdx.x];
    __syncthreads();
    const int HW = H * W;
    const int pix = blockIdx.x * 256 + threadIdx.x;
    if (pix >= HW) return;
    const int b = inst / 100;
    float xin[10];
#pragma unroll
    for (int c = 0; c < 8; ++c) xin[c] = cvt(mf[((size_t)(b * 8 + c)) * HW + pix]);
    int yy = pix / W, xx = pix - yy * W;
    xin[8] = -1.f + 2.f * xx / (W - 1);
    xin[9] = -1.f + 2.f * yy / (H - 1);
    float h1[8];
#pragma unroll
    for (int o = 0; o < 8; ++o) {
        float s = p[152 + o];
#pragma unroll
        for (int c = 0; c < 10; ++c) s = fmaf(p[o * 10 + c], xin[c], s);
        h1[o] = fmaxf(s, 0.f);
    }
    float h2[8];
#pragma unroll
    for (int o = 0; o < 8; ++o) {
        float s = p[160 + o];
#pragma unroll
        for (int c = 0; c < 8; ++c) s = fmaf(p[80 + o * 8 + c], h1[c], s);
        h2[o] = fmaxf(s, 0.f);
    }
    float s = p[168];
#pragma unroll
    for (int c = 0; c < 8; ++c) s = fmaf(p[144 + c], h2[c], s);
    out[(size_t)inst * HW + pix] = s;
}

// ---------------------------------------------------------------------------
// host helpers
// ---------------------------------------------------------------------------
struct Norm { const float* st; const void* g; const void* b; size_t off; int cpg; int Gn; float inv; };
struct Geo  { int H, W, Wq, Hp, PIX; };

static inline Geo mkgeo(int H, int W) {
    int xb = (W + 31) / 32, yb = (H + 3) / 4;
    Geo g; g.H = H; g.W = W; g.Wq = (xb - 1) * 32 + 34; g.Hp = (yb - 1) * 4 + 6;
    g.PIX = g.Hp * g.Wq;
    return g;
}

static inline void mconv(const bf16* in, const bf16* wrep, const Norm* nm,
                         const void* bias, const void* scale, int sidx,
                         void* out, int outm, size_t out_off, int out_C,
                         const int* flags, int N, int Cin, Geo g, int Cout,
                         float* ostat, int ocpg8, int oGn, hipStream_t s)
{
    int cob = (Cout + 127) / 128, Cpad = cob * 128;
    dim3 gr((g.W + 31) / 32, (g.H + 3) / 4, N * cob);
    conv3x3_mfma_k<<<gr, 256, 0, s>>>(
        in, wrep,
        nm ? nm->st : nullptr, nm ? nm->g : nullptr, nm ? nm->b : nullptr,
        nm ? nm->off : 0, nm ? nm->cpg : 1, nm ? nm->Gn : 1, nm ? nm->inv : 1.f,
        bias, scale, sidx, out, outm, out_off, out_C,
        flags, Cin, g.H, g.W, g.Wq, g.PIX, Cout, Cpad, cob,
        ostat, ocpg8, oGn);
}

static inline void run_padT(const void* src, const int* flags, bf16* dst,
                            int N, int C, Geo g, hipStream_t s)
{
    long total = (long)N * g.PIX * (C >> 3);
    padT_k<<<(int)((total + 255) / 256), 256, 0, s>>>(src, flags, dst, C, g.H, g.W,
                                                      g.Wq, g.Hp, g.PIX, total);
}

static inline void run_apply_nhwc(bf16* x, const float* st, const void* gm, const void* bt,
                                  size_t off, const int* flags, int N, int C, int cpg, int Gn,
                                  Geo g, hipStream_t s)
{
    long total = (long)N * g.H * g.W * (C >> 3);
    gn_apply_nhwc<<<(int)((total + 255) / 256), 256, 0, s>>>(
        x, st, gm, bt, off, flags, C, cpg, Gn, g.H, g.W, g.Wq, g.PIX,
        1.f / ((float)cpg * g.H * g.W), total);
}

extern "C" void kernel_launch(void* const* d_in, const int* in_sizes, int n_in,
                              void* d_out, int out_size, void* d_ws, size_t ws_size,
                              hipStream_t stream)
{
    const void* f[5] = {d_in[0], d_in[1], d_in[2], d_in[3], d_in[4]};
    static const int Hs[5] = {96, 48, 24, 12, 6};
    static const int Wd[5] = {160, 80, 40, 20, 10};
    const void* head_w     = d_in[5];
    const void* head_gn_g  = d_in[6];
    const void* head_gn_b  = d_in[7];
    const void* head_out_w = d_in[8];
    const void* head_out_b = d_in[9];
    const void* scales     = d_in[10];
    const void* ref_w      = d_in[11];
    const void* ref_gn_g   = d_in[12];
    const void* ref_gn_b   = d_in[13];
    const void* tow_w      = d_in[14];
    const void* tow_gn_g   = d_in[15];
    const void* tow_gn_b   = d_in[16];
    const void* out_w      = d_in[17];
    const void* out_gn_g   = d_in[18];
    const void* out_gn_b   = d_in[19];

    Geo G[5];
    for (int l = 0; l < 5; ++l) G[l] = mkgeo(Hs[l], Wd[l]);

    size_t po[5]; size_t off = 0;
    for (int l = 0; l < 5; ++l) { po[l] = off; off += (size_t)2 * 254 * Hs[l] * Wd[l]; }
    size_t mf_off = off; off += 245760;
    size_t ml_off = off;

    // ---- workspace (~42 MB) ----
    const size_t ACAP = (size_t)2 * 256 * G[0].PIX;       // 8,128,512 elems
    bf16*  A     = (bf16*)d_ws;
    bf16*  B     = A + ACAP;
    bf16*  B2    = B + ACAP;                              // 2*128*4900 = 1,254,400
    bf16*  mfeat = B2 + 1254400;
    float* prm   = (float*)(mfeat + 245760);              // 33,800 f32
    float* stats = prm + 33800;                           // 4,096 f32
    int*   flags = (int*)(stats + 4096);                  // 16 int
    bf16*  wrep  = (bf16*)(flags + 16);                   // 2,949,120 bf16
    float* dyn   = (float*)A;                             // aliases A after last read

    bf16* wrepH  = wrep;                        // 4 x 589824 (head layers)
    bf16* wrepHO = wrep + 4 * 589824;           // 589824 (head_out, Cpad 256)
    bf16* wrepR  = wrep;                        // mask phase reuses region
    bf16* wrepT  = wrep + 3 * 294912;

    hipMemsetAsync(stats, 0, 4096 * sizeof(float), stream);
    detect_k<<<1, 64, 0, stream>>>((const unsigned int*)d_in[0], flags);

    float* sp = stats;

    // repack head weights
    for (int l = 0; l < 4; ++l) {
        int total = 9 * 256 * 256;
        repack_off_k<<<(total + 255) / 256, 256, 0, stream>>>(
            head_w, (size_t)l * 589824, flags, wrepH + (size_t)l * 589824, 256, 256, 256, total);
    }
    {
        int total = 9 * 256 * 256;
        repack_off_k<<<(total + 255) / 256, 256, 0, stream>>>(
            head_out_w, 0, flags, wrepHO, 254, 256, 256, total);
    }

    // ---------------- head branches ----------------
    for (int lvl = 0; lvl < 5; ++lvl) {
        Geo g = G[lvl];
        int HW = g.H * g.W;
        float inv_pg = 1.f / (8 * HW);
        run_padT(f[lvl], flags, B, 2, 256, g, stream);
        hipMemsetAsync(A, 0, (size_t)2 * 256 * g.PIX * sizeof(bf16), stream);
        float* s_prev = sp; sp += 128;
        mconv(B, wrepH, nullptr, nullptr, nullptr, 0, A, 0, 0, 256,
              flags, 2, 256, g, 256, s_prev, 1, 32, stream);
        bf16* a = A; bf16* bb = B;
        for (int l = 1; l < 4; ++l) {
            Norm nm{s_prev, head_gn_g, head_gn_b, (size_t)(l - 1) * 256, 8, 32, inv_pg};
            float* s_cur = sp; sp += 128;
            mconv(a, wrepH + (size_t)l * 589824, &nm, nullptr, nullptr, 0,
                  bb, 0, 0, 256, flags, 2, 256, g, 256, s_cur, 1, 32, stream);
            s_prev = s_cur;
            bf16* tmp = a; a = bb; bb = tmp;
        }
        Norm nm{s_prev, head_gn_g, head_gn_b, (size_t)3 * 256, 8, 32, inv_pg};
        mconv(a, wrepHO, &nm, head_out_b, scales, lvl, d_out, 2, po[lvl], 0,
              flags, 2, 256, g, 254, nullptr, 1, 1, stream);
        if (lvl == 0)
            extract_params_k<<<(200 * 169 + 255) / 256, 256, 0, stream>>>(d_out, flags, prm, HW);
    }

    // repack mask weights (enqueued after all head convs; stream order protects)
    for (int i = 0; i < 3; ++i) {
        int total = 9 * 128 * 256;
        repack_off_k<<<(total + 255) / 256, 256, 0, stream>>>(
            ref_w, (size_t)i * 294912, flags, wrepR + (size_t)i * 294912, 128, 128, 256, total);
    }
    for (int l = 0; l < 4; ++l) {
        int total = 9 * 128 * 128;
        repack_off_k<<<(total + 255) / 256, 256, 0, stream>>>(
            tow_w, (size_t)l * 147456, flags, wrepT + (size_t)l * 147456, 128, 128, 128, total);
    }

    // ---------------- mask branch ----------------
    {
        Geo g0 = G[0];
        const int HW = 96 * 160;

        // refine 0
        run_padT(f[0], flags, B, 2, 256, g0, stream);
        hipMemsetAsync(A, 0, (size_t)2 * 128 * g0.PIX * sizeof(bf16), stream);
        float* s0 = sp; sp += 4;
        mconv(B, wrepR, nullptr, nullptr, nullptr, 0, A, 0, 0, 128,
              flags, 2, 256, g0, 128, s0, 16, 1, stream);
        run_apply_nhwc(A, s0, ref_gn_g, ref_gn_b, 0, flags, 2, 128, 128, 1, g0, stream);

        // refines 1,2 + upsample-add into A
        for (int i = 1; i < 3; ++i) {
            Geo gi = G[i];
            run_padT(f[i], flags, B, 2, 256, gi, stream);
            hipMemsetAsync(B2, 0, (size_t)2 * 128 * gi.PIX * sizeof(bf16), stream);
            float* si = sp; sp += 4;
            mconv(B, wrepR + (size_t)i * 294912, nullptr, nullptr, nullptr, 0,
                  B2, 0, 0, 128, flags, 2, 256, gi, 128, si, 16, 1, stream);
            run_apply_nhwc(B2, si, ref_gn_g, ref_gn_b, (size_t)i * 128, flags,
                           2, 128, 128, 1, gi, stream);
            long tot = (long)2 * 96 * 160 * 16;
            upsample_add_nhwc<<<(int)((tot + 255) / 256), 256, 0, stream>>>(
                B2, A, gi.H, gi.W, gi.Wq, gi.PIX, 96, 160, g0.Wq, g0.PIX, tot);
        }

        // tower
        float inv_pg = 1.f / (128 * HW);
        hipMemsetAsync(B, 0, (size_t)2 * 128 * g0.PIX * sizeof(bf16), stream);
        float* sT = sp; sp += 4;
        mconv(A, wrepT, nullptr, nullptr, nullptr, 0, B, 0, 0, 128,
              flags, 2, 128, g0, 128, sT, 16, 1, stream);
        bf16* a = B; bf16* bb = A;
        for (int l = 1; l < 4; ++l) {
            Norm nm{sT, tow_gn_g, tow_gn_b, (size_t)(l - 1) * 128, 128, 1, inv_pg};
            float* sN = sp; sp += 4;
            mconv(a, wrepT + (size_t)l * 147456, &nm, nullptr, nullptr, 0,
                  bb, 0, 0, 128, flags, 2, 128, g0, 128, sN, 16, 1, stream);
            sT = sN;
            bf16* tmp = a; a = bb; bb = tmp;
        }
        // final tower raw in a (= A), stats sT (fused)
        run_apply_nhwc(a, sT, tow_gn_g, tow_gn_b, (size_t)3 * 128, flags, 2, 128, 128, 1, g0, stream);
        conv1x1_nhwc<<<(2 * HW + 255) / 256, 256, 0, stream>>>(
            a, out_w, flags, mfeat, 96, 160, g0.Wq, g0.PIX);
        float* sM = sp; sp += 4;
        {
            int chunks = (8 * HW) / 8192; if (chunks < 1) chunks = 1;
            gn_stats_v<<<dim3(2, chunks), 256, 0, stream>>>(mfeat, sM, 8 * HW);
            long nvec = ((long)2 * 8 * HW) >> 3;
            gn_apply_v<<<(int)((nvec + 255) / 256), 256, 0, stream>>>(
                mfeat, sM, out_gn_g, out_gn_b, 0, flags, HW, 8, 8 * HW, 1.f / (8 * HW), nvec);
        }
        cast_out_k<<<(2 * 8 * HW + 255) / 256, 256, 0, stream>>>(
            mfeat, d_out, mf_off, flags, (long)2 * 8 * HW);
        dyn_conv_k<<<dim3((HW + 255) / 256, 200), 256, 0, stream>>>(mfeat, prm, dyn, 96, 160);
        long nt = (long)200 * 192 * 320;
        resize_out_k<<<(int)((nt + 255) / 256), 256, 0, stream>>>(
            dyn, d_out, ml_off, flags, 96, 160, 192, 320, nt);
    }
}